// Round 1
// baseline (17277.341 us; speedup 1.0000x reference)
//
#include <hip/hip_runtime.h>
#include <math.h>

#define E 512
#define H 1024
#define B 64
#define S 32
#define SRC 256
#define L4 4      // NLEV-1 levels actually processed
#define T 31      // S-1 timesteps
#define R 256     // L4*B rows (effective batch)

// ---------------------------------------------------------------------------
// Gather embeddings for the recurrent inputs: xs[t][l*B+b][e] = emb_W[inputs[l+1,b,t]][e]
__global__ __launch_bounds__(128) void k_embed(const int* __restrict__ inputs,
                                               const float* __restrict__ embW,
                                               float* __restrict__ xs) {
    int blk = blockIdx.x;              // l*T*B + t*B + b
    int b = blk % B;
    int t = (blk / B) % T;
    int l = blk / (B * T);
    int tok = inputs[(l + 1) * B * S + b * S + t];
    const float4* src = (const float4*)(embW + (long long)tok * E);
    float4* dst = (float4*)(xs + ((size_t)t * R + (size_t)l * B + b) * E);
    dst[threadIdx.x] = src[threadIdx.x];   // 128 threads * float4 = 512
}

// ---------------------------------------------------------------------------
// pe[r][e] = (1/32) * sum_{s=1}^{min(plen-1,32)-1} emb_W[inputs[l,b,s]][e],  r = l*64+b
__global__ __launch_bounds__(128) void k_pe(const int* __restrict__ inputs,
                                            const int* __restrict__ lens,
                                            const float* __restrict__ embW,
                                            float* __restrict__ pe) {
    int r = blockIdx.x;
    int l = r >> 6, b = r & 63;
    int plen = lens[l * B + b];
    int send = plen - 1;
    if (send > S) send = S;
    const int* toks = inputs + l * B * S + b * S;
    float4 acc = {0.f, 0.f, 0.f, 0.f};
    for (int s = 1; s < send; ++s) {
        int tok = toks[s];
        float4 v = ((const float4*)(embW + (long long)tok * E))[threadIdx.x];
        acc.x += v.x; acc.y += v.y; acc.z += v.z; acc.w += v.w;
    }
    const float inv = 1.f / 32.f;
    acc.x *= inv; acc.y *= inv; acc.z *= inv; acc.w *= inv;
    ((float4*)(pe + (size_t)r * E))[threadIdx.x] = acc;
}

// ---------------------------------------------------------------------------
// cm[b][h] = mean over SRC of contexts[b][s][h]
__global__ __launch_bounds__(256) void k_cm(const float* __restrict__ ctx,
                                            float* __restrict__ cm) {
    int b = blockIdx.x;
    int j = threadIdx.x;                       // 256 float4 = 1024 floats
    const float4* c4 = (const float4*)(ctx + (size_t)b * SRC * H);
    float4 acc = {0.f, 0.f, 0.f, 0.f};
    for (int s = 0; s < SRC; ++s) {
        float4 v = c4[(size_t)s * (H / 4) + j];
        acc.x += v.x; acc.y += v.y; acc.z += v.z; acc.w += v.w;
    }
    const float inv = 1.f / (float)SRC;
    acc.x *= inv; acc.y *= inv; acc.z *= inv; acc.w *= inv;
    ((float4*)(cm + (size_t)b * H))[j] = acc;
}

// ---------------------------------------------------------------------------
// Generic C[m] = act( A1[m]@W1[n]^T + A2[m2]@W2[n]^T + bias1[n] (+bias2[n]) )
// A row-major (256 x K), W row-major (N x ldw) accessed at W[n*ldw + k].
// Output row offset = (m>>6)*strideL + (m&63)*strideB  (handles outs scatter).
// a2mod = 64 -> A2 row index is m%64 (broadcast over levels). act=1 -> tanh.
__global__ __launch_bounds__(256) void k_gemm2(
    const float* __restrict__ A1, const float* __restrict__ W1, int ldw1, int K1,
    const float* __restrict__ A2, const float* __restrict__ W2, int ldw2, int K2,
    const float* __restrict__ bias1, const float* __restrict__ bias2,
    float* __restrict__ C, long long strideL, long long strideB,
    int act, int a2mod) {
    __shared__ float As[16][64];
    __shared__ float Ws[16][64];
    const int tid = threadIdx.x;
    const int tx = tid & 15, ty = tid >> 4;
    const int n0 = blockIdx.x * 64;
    const int m0 = blockIdx.y * 64;
    float acc[4][4] = {};

    for (int pass = 0; pass < 2; ++pass) {
        const float* A = pass ? A2 : A1;
        const float* W = pass ? W2 : W1;
        const int K = pass ? K2 : K1;
        const int ldw = pass ? ldw2 : ldw1;
        const int mod = pass ? a2mod : 0;
        if (K == 0 || A == nullptr) continue;
        for (int k0 = 0; k0 < K; k0 += 16) {
            __syncthreads();
            {
                int i = tid;
#pragma unroll
                for (int it = 0; it < 4; ++it, i += 256) {
                    int m = i >> 4, k = i & 15;
                    int rr = m0 + m;
                    if (mod) rr = rr & (mod - 1);      // mod is 64 (pow2)
                    As[k][m] = A[(long long)rr * K + k0 + k];
                }
            }
            {
                int i = tid;
#pragma unroll
                for (int it = 0; it < 4; ++it, i += 256) {
                    int n = i >> 4, k = i & 15;
                    Ws[k][n] = W[(long long)(n0 + n) * ldw + k0 + k];
                }
            }
            __syncthreads();
#pragma unroll
            for (int k = 0; k < 16; ++k) {
                float4 av = *(const float4*)&As[k][ty * 4];
                float4 bv = *(const float4*)&Ws[k][tx * 4];
                float a[4] = {av.x, av.y, av.z, av.w};
                float bb[4] = {bv.x, bv.y, bv.z, bv.w};
#pragma unroll
                for (int i = 0; i < 4; ++i)
#pragma unroll
                    for (int j = 0; j < 4; ++j) acc[i][j] += a[i] * bb[j];
            }
        }
    }

#pragma unroll
    for (int i = 0; i < 4; ++i) {
        int m = m0 + ty * 4 + i;
        long long rowoff = (long long)(m >> 6) * strideL + (long long)(m & 63) * strideB;
#pragma unroll
        for (int j = 0; j < 4; ++j) {
            int n = n0 + tx * 4 + j;
            float v = acc[i][j] + bias1[n];
            if (bias2) v += bias2[n];
            if (act) v = tanhf(v);
            C[rowoff + n] = v;
        }
    }
}

// ---------------------------------------------------------------------------
// LSTM pointwise: g (R x 4H) gates [i|f|g|o]; updates hbuf, cbuf in place.
__global__ __launch_bounds__(256) void k_lstm(const float* __restrict__ g,
                                              float* __restrict__ hbuf,
                                              float* __restrict__ cbuf) {
    int idx = blockIdx.x * 256 + threadIdx.x;      // R*H = 262144
    int r = idx >> 10, h = idx & 1023;
    const float* gr = g + (long long)r * 4096;
    float gi = gr[h], gf = gr[1024 + h], gg = gr[2048 + h], go = gr[3072 + h];
    float cp = cbuf[idx];
    float si = 1.f / (1.f + expf(-gi));
    float sf = 1.f / (1.f + expf(-gf));
    float so = 1.f / (1.f + expf(-go));
    float c = sf * cp + si * tanhf(gg);
    float hn = so * tanhf(c);
    cbuf[idx] = c;
    hbuf[idx] = hn;
}

// ---------------------------------------------------------------------------
// Attention: per b, for all 4 levels: scores = ctx[b] @ gamma[l*64+b],
// softmax over SRC, ct = sum_s w[s]*ctx[b,s,:]
__global__ __launch_bounds__(256) void k_attn(const float* __restrict__ ctx,
                                              const float* __restrict__ gamma,
                                              float* __restrict__ ct) {
    __shared__ float gam[L4][H];
    __shared__ float wsm[L4][SRC];
    const int b = blockIdx.x;
    const int tid = threadIdx.x;
    const int wave = tid >> 6, lane = tid & 63;

#pragma unroll
    for (int l = 0; l < L4; ++l) {
        const float4* src = (const float4*)(gamma + (size_t)(l * B + b) * H);
        ((float4*)gam[l])[tid] = src[tid];
    }
    __syncthreads();

    const float* ctxb = ctx + (size_t)b * SRC * H;
    for (int s8 = 0; s8 < 64; ++s8) {
        int s = wave * 64 + s8;
        const float* cs = ctxb + (size_t)s * H;
        float a0 = 0.f, a1 = 0.f, a2 = 0.f, a3 = 0.f;
#pragma unroll
        for (int j = 0; j < 16; ++j) {
            int h = lane + 64 * j;
            float cv = cs[h];
            a0 += cv * gam[0][h];
            a1 += cv * gam[1][h];
            a2 += cv * gam[2][h];
            a3 += cv * gam[3][h];
        }
#pragma unroll
        for (int off = 32; off >= 1; off >>= 1) {
            a0 += __shfl_xor(a0, off);
            a1 += __shfl_xor(a1, off);
            a2 += __shfl_xor(a2, off);
            a3 += __shfl_xor(a3, off);
        }
        if (lane == 0) {
            wsm[0][s] = a0; wsm[1][s] = a1; wsm[2][s] = a2; wsm[3][s] = a3;
        }
    }
    __syncthreads();

    // softmax: wave w handles level w; 4 scores per lane
    {
        int l = wave;
        float v0 = wsm[l][lane], v1 = wsm[l][lane + 64];
        float v2 = wsm[l][lane + 128], v3 = wsm[l][lane + 192];
        float m = fmaxf(fmaxf(v0, v1), fmaxf(v2, v3));
#pragma unroll
        for (int off = 32; off >= 1; off >>= 1) m = fmaxf(m, __shfl_xor(m, off));
        float e0 = expf(v0 - m), e1 = expf(v1 - m), e2 = expf(v2 - m), e3 = expf(v3 - m);
        float sum = e0 + e1 + e2 + e3;
#pragma unroll
        for (int off = 32; off >= 1; off >>= 1) sum += __shfl_xor(sum, off);
        float inv = 1.f / sum;
        wsm[l][lane] = e0 * inv;
        wsm[l][lane + 64] = e1 * inv;
        wsm[l][lane + 128] = e2 * inv;
        wsm[l][lane + 192] = e3 * inv;
    }
    __syncthreads();

    // ct: each thread one float4 of H for all 4 levels
    float4 acc[L4];
#pragma unroll
    for (int l = 0; l < L4; ++l) acc[l] = make_float4(0.f, 0.f, 0.f, 0.f);
    const float4* ctx4 = (const float4*)ctxb;
    for (int s = 0; s < SRC; ++s) {
        float4 cv = ctx4[(size_t)s * (H / 4) + tid];
        float w0 = wsm[0][s], w1 = wsm[1][s], w2 = wsm[2][s], w3 = wsm[3][s];
        acc[0].x += w0 * cv.x; acc[0].y += w0 * cv.y; acc[0].z += w0 * cv.z; acc[0].w += w0 * cv.w;
        acc[1].x += w1 * cv.x; acc[1].y += w1 * cv.y; acc[1].z += w1 * cv.z; acc[1].w += w1 * cv.w;
        acc[2].x += w2 * cv.x; acc[2].y += w2 * cv.y; acc[2].z += w2 * cv.z; acc[2].w += w2 * cv.w;
        acc[3].x += w3 * cv.x; acc[3].y += w3 * cv.y; acc[3].z += w3 * cv.z; acc[3].w += w3 * cv.w;
    }
#pragma unroll
    for (int l = 0; l < L4; ++l)
        ((float4*)(ct + (size_t)(l * B + b) * H))[tid] = acc[l];
}

// ---------------------------------------------------------------------------
extern "C" void kernel_launch(void* const* d_in, const int* in_sizes, int n_in,
                              void* d_out, int out_size, void* d_ws, size_t ws_size,
                              hipStream_t stream) {
    const int*   inputs     = (const int*)d_in[0];
    const int*   input_lens = (const int*)d_in[1];
    const float* contexts   = (const float*)d_in[2];
    const float* emb_W      = (const float*)d_in[3];
    const float* W_ih0      = (const float*)d_in[4];
    const float* W_hh0      = (const float*)d_in[5];
    const float* b_ih0      = (const float*)d_in[6];
    const float* b_hh0      = (const float*)d_in[7];
    const float* W_ih1      = (const float*)d_in[8];
    const float* W_hh1      = (const float*)d_in[9];
    const float* b_ih1      = (const float*)d_in[10];
    const float* b_hh1      = (const float*)d_in[11];
    const float* att_in_W   = (const float*)d_in[12];
    const float* att_in_b   = (const float*)d_in[13];
    const float* att_out_W  = (const float*)d_in[14];
    const float* att_out_b  = (const float*)d_in[15];
    const float* isl_in_W   = (const float*)d_in[16];
    const float* isl_in_b   = (const float*)d_in[17];
    const float* isl_out_W  = (const float*)d_in[18];
    const float* isl_out_b  = (const float*)d_in[19];

    float* out = (float*)d_out;
    float* ws  = (float*)d_ws;

    // workspace carve (floats)
    float* xs  = ws;                                   // T*R*E = 4,063,232
    float* pe  = xs + (size_t)T * R * E;               // R*E
    float* cm  = pe + (size_t)R * E;                   // B*H
    float* h0b = cm + (size_t)B * H;                   // R*H  (layer0 h)
    float* h1b = h0b + (size_t)R * H;                  // R*H  (layer1 h)
    float* c0b = h1b + (size_t)R * H;
    float* c1b = c0b + (size_t)R * H;
    float* g   = c1b + (size_t)R * H;                  // R*4H
    float* gam = g + (size_t)R * 4 * H;                // R*H
    float* ctb = gam + (size_t)R * H;                  // R*H

    // setup
    k_embed<<<L4 * T * B, 128, 0, stream>>>(inputs, emb_W, xs);
    k_pe<<<R, 128, 0, stream>>>(inputs, input_lens, emb_W, pe);
    k_cm<<<B, 256, 0, stream>>>(contexts, cm);

    // h0 = tanh([pe|cm] @ isl_in_W^T + b) ; c0 = tanh([cm|pe] @ isl_out_W^T + b)
    k_gemm2<<<dim3(16, 4), 256, 0, stream>>>(pe, isl_in_W, 1536, 512,
                                             cm, isl_in_W + 512, 1536, 1024,
                                             isl_in_b, nullptr,
                                             h0b, 64LL * H, (long long)H, 1, 64);
    k_gemm2<<<dim3(16, 4), 256, 0, stream>>>(pe, isl_out_W + 1024, 1536, 512,
                                             cm, isl_out_W, 1536, 1024,
                                             isl_out_b, nullptr,
                                             c0b, 64LL * H, (long long)H, 1, 64);
    hipMemcpyAsync(h1b, h0b, (size_t)R * H * 4, hipMemcpyDeviceToDevice, stream);
    hipMemcpyAsync(c1b, c0b, (size_t)R * H * 4, hipMemcpyDeviceToDevice, stream);

    for (int t = 0; t < T; ++t) {
        const float* xt = xs + (size_t)t * R * E;
        // layer0 gates
        k_gemm2<<<dim3(64, 4), 256, 0, stream>>>(xt, W_ih0, 512, 512,
                                                 h0b, W_hh0, 1024, 1024,
                                                 b_ih0, b_hh0,
                                                 g, 64LL * 4096, 4096LL, 0, 0);
        k_lstm<<<1024, 256, 0, stream>>>(g, h0b, c0b);
        // layer1 gates (input = new h0b)
        k_gemm2<<<dim3(64, 4), 256, 0, stream>>>(h0b, W_ih1, 1024, 1024,
                                                 h1b, W_hh1, 1024, 1024,
                                                 b_ih1, b_hh1,
                                                 g, 64LL * 4096, 4096LL, 0, 0);
        k_lstm<<<1024, 256, 0, stream>>>(g, h1b, c1b);
        // gamma = h2 @ att_in_W^T + b
        k_gemm2<<<dim3(16, 4), 256, 0, stream>>>(h1b, att_in_W, 1024, 1024,
                                                 nullptr, nullptr, 0, 0,
                                                 att_in_b, nullptr,
                                                 gam, 64LL * H, (long long)H, 0, 0);
        // attention
        k_attn<<<B, 256, 0, stream>>>(contexts, gam, ctb);
        // out = tanh([ct|h2] @ att_out_W^T + b) scattered into outs[l,t,b,:]
        k_gemm2<<<dim3(16, 4), 256, 0, stream>>>(ctb, att_out_W, 2048, 1024,
                                                 h1b, att_out_W + 1024, 2048, 1024,
                                                 att_out_b, nullptr,
                                                 out + (size_t)t * B * H,
                                                 (long long)T * B * H, (long long)H, 1, 0);
    }

    // finals: hT[-1] = [h0b rows 192..255, h1b rows 192..255]; cT likewise
    size_t OUTS = (size_t)L4 * T * B * H;
    size_t seg = (size_t)B * H;                         // 65536 floats
    hipMemcpyAsync(out + OUTS,           h0b + 192 * H, seg * 4, hipMemcpyDeviceToDevice, stream);
    hipMemcpyAsync(out + OUTS + seg,     h1b + 192 * H, seg * 4, hipMemcpyDeviceToDevice, stream);
    hipMemcpyAsync(out + OUTS + 2 * seg, c0b + 192 * H, seg * 4, hipMemcpyDeviceToDevice, stream);
    hipMemcpyAsync(out + OUTS + 3 * seg, c1b + 192 * H, seg * 4, hipMemcpyDeviceToDevice, stream);
}

// Round 2
// 13463.187 us; speedup vs baseline: 1.2833x; 1.2833x over previous
//
#include <hip/hip_runtime.h>
#include <math.h>

#define E 512
#define H 1024
#define B 64
#define S 32
#define SRC 256
#define L4 4      // NLEV-1 levels actually processed
#define T 31      // S-1 timesteps
#define R 256     // L4*B rows (effective batch)

typedef unsigned int uint_t;
typedef unsigned short ushort_t;
typedef float f32x4_v __attribute__((ext_vector_type(4)));
typedef short bf16x8_v __attribute__((ext_vector_type(8)));

// ---------------------------------------------------------------------------
// Gather embeddings: xs[t][l*B+b][e] = emb_W[inputs[l+1,b,t]][e]
__global__ __launch_bounds__(128) void k_embed(const int* __restrict__ inputs,
                                               const float* __restrict__ embW,
                                               float* __restrict__ xs) {
    int blk = blockIdx.x;              // l*T*B + t*B + b
    int b = blk % B;
    int t = (blk / B) % T;
    int l = blk / (B * T);
    int tok = inputs[(l + 1) * B * S + b * S + t];
    const float4* src = (const float4*)(embW + (long long)tok * E);
    float4* dst = (float4*)(xs + ((size_t)t * R + (size_t)l * B + b) * E);
    dst[threadIdx.x] = src[threadIdx.x];   // 128 threads * float4 = 512
}

// ---------------------------------------------------------------------------
__global__ __launch_bounds__(128) void k_pe(const int* __restrict__ inputs,
                                            const int* __restrict__ lens,
                                            const float* __restrict__ embW,
                                            float* __restrict__ pe) {
    int r = blockIdx.x;
    int l = r >> 6, b = r & 63;
    int plen = lens[l * B + b];
    int send = plen - 1;
    if (send > S) send = S;
    const int* toks = inputs + l * B * S + b * S;
    float4 acc = {0.f, 0.f, 0.f, 0.f};
    for (int s = 1; s < send; ++s) {
        int tok = toks[s];
        float4 v = ((const float4*)(embW + (long long)tok * E))[threadIdx.x];
        acc.x += v.x; acc.y += v.y; acc.z += v.z; acc.w += v.w;
    }
    const float inv = 1.f / 32.f;
    acc.x *= inv; acc.y *= inv; acc.z *= inv; acc.w *= inv;
    ((float4*)(pe + (size_t)r * E))[threadIdx.x] = acc;
}

// ---------------------------------------------------------------------------
__global__ __launch_bounds__(256) void k_cm(const float* __restrict__ ctx,
                                            float* __restrict__ cm) {
    int b = blockIdx.x;
    int j = threadIdx.x;
    const float4* c4 = (const float4*)(ctx + (size_t)b * SRC * H);
    float4 acc = {0.f, 0.f, 0.f, 0.f};
    for (int s = 0; s < SRC; ++s) {
        float4 v = c4[(size_t)s * (H / 4) + j];
        acc.x += v.x; acc.y += v.y; acc.z += v.z; acc.w += v.w;
    }
    const float inv = 1.f / (float)SRC;
    acc.x *= inv; acc.y *= inv; acc.z *= inv; acc.w *= inv;
    ((float4*)(cm + (size_t)b * H))[j] = acc;
}

// ---------------------------------------------------------------------------
// split f32 -> bf16 hi (truncate) + bf16 lo (truncated remainder)
__device__ __forceinline__ void split1(float x, uint_t& h, uint_t& l) {
    uint_t u = __float_as_uint(x);
    h = u >> 16;
    float hf = __uint_as_float(u & 0xFFFF0000u);
    l = __float_as_uint(x - hf) >> 16;
}

__device__ __forceinline__ void split_quad(float4 v, uint2& hi, uint2& lo) {
    uint_t h0, h1, h2, h3, l0, l1, l2, l3;
    split1(v.x, h0, l0); split1(v.y, h1, l1);
    split1(v.z, h2, l2); split1(v.w, h3, l3);
    hi.x = h0 | (h1 << 16); hi.y = h2 | (h3 << 16);
    lo.x = l0 | (l1 << 16); lo.y = l2 | (l3 << 16);
}

// ---------------------------------------------------------------------------
// MFMA split-bf16 GEMM: C = act( A1@W1^T + A2@W2^T + bias1 (+bias2) )
// A row-major (256 x K, ld = K), W row-major (N x ldw): W[n*ldw + k].
// Output row offset = (m>>6)*strideL + (m&63)*strideB. a2mod=64 -> A2 row = m%64.
// Block: 256 thr (4 waves, 2x2), tile 64m x 64n, BK=32.
// Fragment LDS layout: per 16-row subtile, lane-contiguous 16B fragments.
// A/B staged with identical (lane-group, elem)->k placement, so the result is
// invariant to the HW's internal k-ordering (bijection argument); C/D layout
// is the m89-verified col=lane&15, row=(lane>>4)*4+reg.
__global__ __launch_bounds__(256) void k_bgemm(
    const float* __restrict__ A1, const float* __restrict__ W1, int ldw1, int K1,
    const float* __restrict__ A2, const float* __restrict__ W2, int ldw2, int K2,
    const float* __restrict__ bias1, const float* __restrict__ bias2,
    float* __restrict__ C, long long strideL, long long strideB,
    int act, int a2mod) {
    __shared__ __align__(16) ushort_t Af[2][4][64][8];   // [hi/lo][msub][fraglane][8]
    __shared__ __align__(16) ushort_t Bf[2][4][64][8];
    const int tid = threadIdx.x;
    const int lane = tid & 63;
    const int wv = tid >> 6;
    const int wm = wv & 1, wn = wv >> 1;
    const int n0 = blockIdx.x * 64;
    const int m0 = blockIdx.y * 64;

    f32x4_v zero = {0.f, 0.f, 0.f, 0.f};
    f32x4_v acc[2][2] = {{zero, zero}, {zero, zero}};

    for (int pass = 0; pass < 2; ++pass) {
        const float* Aop = pass ? A2 : A1;
        const float* Wop = pass ? W2 : W1;
        const int K = pass ? K2 : K1;
        const int ldw = pass ? ldw2 : ldw1;
        const int mod = pass ? a2mod : 0;
        if (Aop == nullptr || K == 0) continue;
        for (int k0 = 0; k0 < K; k0 += 32) {
            __syncthreads();
#pragma unroll
            for (int q = tid; q < 512; q += 256) {   // stage A tile 64x32
                int kq = q & 7, row = q >> 3;
                int rr = m0 + row; if (mod) rr &= (mod - 1);
                float4 v = *(const float4*)(Aop + (long long)rr * K + k0 + kq * 4);
                uint2 hi, lo; split_quad(v, hi, lo);
                int ms = row >> 4;
                int fl = ((kq & 3) << 4) | (row & 15);
                int off = (kq >> 2) * 4;
                *(uint2*)&Af[0][ms][fl][off] = hi;
                *(uint2*)&Af[1][ms][fl][off] = lo;
            }
#pragma unroll
            for (int q = tid; q < 512; q += 256) {   // stage B tile 64x32
                int kq = q & 7, row = q >> 3;
                float4 v = *(const float4*)(Wop + (long long)(n0 + row) * ldw + k0 + kq * 4);
                uint2 hi, lo; split_quad(v, hi, lo);
                int ns = row >> 4;
                int fl = ((kq & 3) << 4) | (row & 15);
                int off = (kq >> 2) * 4;
                *(uint2*)&Bf[0][ns][fl][off] = hi;
                *(uint2*)&Bf[1][ns][fl][off] = lo;
            }
            __syncthreads();
            bf16x8_v ah[2], al[2], bh[2], bl[2];
#pragma unroll
            for (int i = 0; i < 2; ++i) {
                ah[i] = *(const bf16x8_v*)&Af[0][wm * 2 + i][lane][0];
                al[i] = *(const bf16x8_v*)&Af[1][wm * 2 + i][lane][0];
                bh[i] = *(const bf16x8_v*)&Bf[0][wn * 2 + i][lane][0];
                bl[i] = *(const bf16x8_v*)&Bf[1][wn * 2 + i][lane][0];
            }
#pragma unroll
            for (int i = 0; i < 2; ++i)
#pragma unroll
                for (int j = 0; j < 2; ++j) {
                    acc[i][j] = __builtin_amdgcn_mfma_f32_16x16x32_bf16(al[i], bh[j], acc[i][j], 0, 0, 0);
                    acc[i][j] = __builtin_amdgcn_mfma_f32_16x16x32_bf16(ah[i], bl[j], acc[i][j], 0, 0, 0);
                    acc[i][j] = __builtin_amdgcn_mfma_f32_16x16x32_bf16(ah[i], bh[j], acc[i][j], 0, 0, 0);
                }
        }
    }

    const int l16 = lane & 15, g4 = (lane >> 4) * 4;
#pragma unroll
    for (int i = 0; i < 2; ++i) {
#pragma unroll
        for (int r = 0; r < 4; ++r) {
            int m = m0 + wm * 32 + i * 16 + g4 + r;
            long long rowoff = (long long)(m >> 6) * strideL + (long long)(m & 63) * strideB;
#pragma unroll
            for (int j = 0; j < 2; ++j) {
                int n = n0 + wn * 32 + j * 16 + l16;
                float v = acc[i][j][r] + bias1[n];
                if (bias2) v += bias2[n];
                if (act) v = tanhf(v);
                C[rowoff + n] = v;
            }
        }
    }
}

// ---------------------------------------------------------------------------
// LSTM pointwise: g (R x 4H) gates [i|f|g|o]; updates hbuf, cbuf in place.
__global__ __launch_bounds__(256) void k_lstm(const float* __restrict__ g,
                                              float* __restrict__ hbuf,
                                              float* __restrict__ cbuf) {
    int idx = blockIdx.x * 256 + threadIdx.x;      // R*H = 262144
    int r = idx >> 10, h = idx & 1023;
    const float* gr = g + (long long)r * 4096;
    float gi = gr[h], gf = gr[1024 + h], gg = gr[2048 + h], go = gr[3072 + h];
    float cp = cbuf[idx];
    float si = 1.f / (1.f + expf(-gi));
    float sf = 1.f / (1.f + expf(-gf));
    float so = 1.f / (1.f + expf(-go));
    float c = sf * cp + si * tanhf(gg);
    float hn = so * tanhf(c);
    cbuf[idx] = c;
    hbuf[idx] = hn;
}

// ---------------------------------------------------------------------------
__global__ __launch_bounds__(256) void k_attn(const float* __restrict__ ctx,
                                              const float* __restrict__ gamma,
                                              float* __restrict__ ct) {
    __shared__ float gam[L4][H];
    __shared__ float wsm[L4][SRC];
    const int b = blockIdx.x;
    const int tid = threadIdx.x;
    const int wave = tid >> 6, lane = tid & 63;

#pragma unroll
    for (int l = 0; l < L4; ++l) {
        const float4* src = (const float4*)(gamma + (size_t)(l * B + b) * H);
        ((float4*)gam[l])[tid] = src[tid];
    }
    __syncthreads();

    const float* ctxb = ctx + (size_t)b * SRC * H;
    for (int s8 = 0; s8 < 64; ++s8) {
        int s = wave * 64 + s8;
        const float* cs = ctxb + (size_t)s * H;
        float a0 = 0.f, a1 = 0.f, a2 = 0.f, a3 = 0.f;
#pragma unroll
        for (int j = 0; j < 16; ++j) {
            int h = lane + 64 * j;
            float cv = cs[h];
            a0 += cv * gam[0][h];
            a1 += cv * gam[1][h];
            a2 += cv * gam[2][h];
            a3 += cv * gam[3][h];
        }
#pragma unroll
        for (int off = 32; off >= 1; off >>= 1) {
            a0 += __shfl_xor(a0, off);
            a1 += __shfl_xor(a1, off);
            a2 += __shfl_xor(a2, off);
            a3 += __shfl_xor(a3, off);
        }
        if (lane == 0) {
            wsm[0][s] = a0; wsm[1][s] = a1; wsm[2][s] = a2; wsm[3][s] = a3;
        }
    }
    __syncthreads();

    {
        int l = wave;
        float v0 = wsm[l][lane], v1 = wsm[l][lane + 64];
        float v2 = wsm[l][lane + 128], v3 = wsm[l][lane + 192];
        float m = fmaxf(fmaxf(v0, v1), fmaxf(v2, v3));
#pragma unroll
        for (int off = 32; off >= 1; off >>= 1) m = fmaxf(m, __shfl_xor(m, off));
        float e0 = expf(v0 - m), e1 = expf(v1 - m), e2 = expf(v2 - m), e3 = expf(v3 - m);
        float sum = e0 + e1 + e2 + e3;
#pragma unroll
        for (int off = 32; off >= 1; off >>= 1) sum += __shfl_xor(sum, off);
        float inv = 1.f / sum;
        wsm[l][lane] = e0 * inv;
        wsm[l][lane + 64] = e1 * inv;
        wsm[l][lane + 128] = e2 * inv;
        wsm[l][lane + 192] = e3 * inv;
    }
    __syncthreads();

    float4 acc[L4];
#pragma unroll
    for (int l = 0; l < L4; ++l) acc[l] = make_float4(0.f, 0.f, 0.f, 0.f);
    const float4* ctx4 = (const float4*)ctxb;
    for (int s = 0; s < SRC; ++s) {
        float4 cv = ctx4[(size_t)s * (H / 4) + tid];
        float w0 = wsm[0][s], w1 = wsm[1][s], w2 = wsm[2][s], w3 = wsm[3][s];
        acc[0].x += w0 * cv.x; acc[0].y += w0 * cv.y; acc[0].z += w0 * cv.z; acc[0].w += w0 * cv.w;
        acc[1].x += w1 * cv.x; acc[1].y += w1 * cv.y; acc[1].z += w1 * cv.z; acc[1].w += w1 * cv.w;
        acc[2].x += w2 * cv.x; acc[2].y += w2 * cv.y; acc[2].z += w2 * cv.z; acc[2].w += w2 * cv.w;
        acc[3].x += w3 * cv.x; acc[3].y += w3 * cv.y; acc[3].z += w3 * cv.z; acc[3].w += w3 * cv.w;
    }
#pragma unroll
    for (int l = 0; l < L4; ++l)
        ((float4*)(ct + (size_t)(l * B + b) * H))[tid] = acc[l];
}

// ---------------------------------------------------------------------------
extern "C" void kernel_launch(void* const* d_in, const int* in_sizes, int n_in,
                              void* d_out, int out_size, void* d_ws, size_t ws_size,
                              hipStream_t stream) {
    const int*   inputs     = (const int*)d_in[0];
    const int*   input_lens = (const int*)d_in[1];
    const float* contexts   = (const float*)d_in[2];
    const float* emb_W      = (const float*)d_in[3];
    const float* W_ih0      = (const float*)d_in[4];
    const float* W_hh0      = (const float*)d_in[5];
    const float* b_ih0      = (const float*)d_in[6];
    const float* b_hh0      = (const float*)d_in[7];
    const float* W_ih1      = (const float*)d_in[8];
    const float* W_hh1      = (const float*)d_in[9];
    const float* b_ih1      = (const float*)d_in[10];
    const float* b_hh1      = (const float*)d_in[11];
    const float* att_in_W   = (const float*)d_in[12];
    const float* att_in_b   = (const float*)d_in[13];
    const float* att_out_W  = (const float*)d_in[14];
    const float* att_out_b  = (const float*)d_in[15];
    const float* isl_in_W   = (const float*)d_in[16];
    const float* isl_in_b   = (const float*)d_in[17];
    const float* isl_out_W  = (const float*)d_in[18];
    const float* isl_out_b  = (const float*)d_in[19];

    float* out = (float*)d_out;
    float* ws  = (float*)d_ws;

    // workspace carve (floats)
    float* xs  = ws;                                   // T*R*E
    float* pe  = xs + (size_t)T * R * E;               // R*E
    float* cm  = pe + (size_t)R * E;                   // B*H
    float* h0b = cm + (size_t)B * H;                   // R*H
    float* h1b = h0b + (size_t)R * H;                  // R*H
    float* c0b = h1b + (size_t)R * H;
    float* c1b = c0b + (size_t)R * H;
    float* g   = c1b + (size_t)R * H;                  // R*4H
    float* gam = g + (size_t)R * 4 * H;                // R*H
    float* ctb = gam + (size_t)R * H;                  // R*H

    // setup
    k_embed<<<L4 * T * B, 128, 0, stream>>>(inputs, emb_W, xs);
    k_pe<<<R, 128, 0, stream>>>(inputs, input_lens, emb_W, pe);
    k_cm<<<B, 256, 0, stream>>>(contexts, cm);

    // h0 = tanh([pe|cm] @ isl_in_W^T + b) ; c0 = tanh([cm|pe] @ isl_out_W^T + b)
    k_bgemm<<<dim3(16, 4), 256, 0, stream>>>(pe, isl_in_W, 1536, 512,
                                             cm, isl_in_W + 512, 1536, 1024,
                                             isl_in_b, nullptr,
                                             h0b, 64LL * H, (long long)H, 1, 64);
    k_bgemm<<<dim3(16, 4), 256, 0, stream>>>(pe, isl_out_W + 1024, 1536, 512,
                                             cm, isl_out_W, 1536, 1024,
                                             isl_out_b, nullptr,
                                             c0b, 64LL * H, (long long)H, 1, 64);
    hipMemcpyAsync(h1b, h0b, (size_t)R * H * 4, hipMemcpyDeviceToDevice, stream);
    hipMemcpyAsync(c1b, c0b, (size_t)R * H * 4, hipMemcpyDeviceToDevice, stream);

    for (int t = 0; t < T; ++t) {
        const float* xt = xs + (size_t)t * R * E;
        // layer0 gates
        k_bgemm<<<dim3(64, 4), 256, 0, stream>>>(xt, W_ih0, 512, 512,
                                                 h0b, W_hh0, 1024, 1024,
                                                 b_ih0, b_hh0,
                                                 g, 64LL * 4096, 4096LL, 0, 0);
        k_lstm<<<1024, 256, 0, stream>>>(g, h0b, c0b);
        // layer1 gates
        k_bgemm<<<dim3(64, 4), 256, 0, stream>>>(h0b, W_ih1, 1024, 1024,
                                                 h1b, W_hh1, 1024, 1024,
                                                 b_ih1, b_hh1,
                                                 g, 64LL * 4096, 4096LL, 0, 0);
        k_lstm<<<1024, 256, 0, stream>>>(g, h1b, c1b);
        // gamma = h2 @ att_in_W^T + b
        k_bgemm<<<dim3(16, 4), 256, 0, stream>>>(h1b, att_in_W, 1024, 1024,
                                                 nullptr, nullptr, 0, 0,
                                                 att_in_b, nullptr,
                                                 gam, 64LL * H, (long long)H, 0, 0);
        // attention
        k_attn<<<B, 256, 0, stream>>>(contexts, gam, ctb);
        // out = tanh([ct|h2] @ att_out_W^T + b) scattered into outs[l,t,b,:]
        k_bgemm<<<dim3(16, 4), 256, 0, stream>>>(ctb, att_out_W, 2048, 1024,
                                                 h1b, att_out_W + 1024, 2048, 1024,
                                                 att_out_b, nullptr,
                                                 out + (size_t)t * B * H,
                                                 (long long)T * B * H, (long long)H, 1, 0);
    }

    // finals
    size_t OUTS = (size_t)L4 * T * B * H;
    size_t seg = (size_t)B * H;
    hipMemcpyAsync(out + OUTS,           h0b + 192 * H, seg * 4, hipMemcpyDeviceToDevice, stream);
    hipMemcpyAsync(out + OUTS + seg,     h1b + 192 * H, seg * 4, hipMemcpyDeviceToDevice, stream);
    hipMemcpyAsync(out + OUTS + 2 * seg, c0b + 192 * H, seg * 4, hipMemcpyDeviceToDevice, stream);
    hipMemcpyAsync(out + OUTS + 3 * seg, c1b + 192 * H, seg * 4, hipMemcpyDeviceToDevice, stream);
}

// Round 3
// 5760.127 us; speedup vs baseline: 2.9995x; 2.3373x over previous
//
#include <hip/hip_runtime.h>
#include <math.h>

#define E 512
#define H 1024
#define B 64
#define S 32
#define SRC 256
#define L4 4      // NLEV-1 levels actually processed
#define T 31      // S-1 timesteps
#define R 256     // L4*B rows (effective batch)

typedef unsigned int uint_t;
typedef unsigned short ushort_t;
typedef float f32x4_v __attribute__((ext_vector_type(4)));
typedef short bf16x8_v __attribute__((ext_vector_type(8)));

// ---------------------------------------------------------------------------
// split f32 -> bf16 hi (truncate) + bf16 lo (truncated remainder)
__device__ __forceinline__ void split1(float x, uint_t& h, uint_t& l) {
    uint_t u = __float_as_uint(x);
    h = u >> 16;
    float hf = __uint_as_float(u & 0xFFFF0000u);
    l = __float_as_uint(x - hf) >> 16;
}

__device__ __forceinline__ void split_quad(float4 v, uint2& hi, uint2& lo) {
    uint_t h0, h1, h2, h3, l0, l1, l2, l3;
    split1(v.x, h0, l0); split1(v.y, h1, l1);
    split1(v.z, h2, l2); split1(v.w, h3, l3);
    hi.x = h0 | (h1 << 16); hi.y = h2 | (h3 << 16);
    lo.x = l0 | (l1 << 16); lo.y = l2 | (l3 << 16);
}

__device__ __forceinline__ void gl_lds16(const void* g, void* l) {
    __builtin_amdgcn_global_load_lds(
        (const __attribute__((address_space(1))) void*)g,
        (__attribute__((address_space(3))) void*)l, 16, 0, 0);
}

// ---------------------------------------------------------------------------
// Embeddings -> bf16 hi/lo planes: xs[t*R + l*B+b][e]
__global__ __launch_bounds__(128) void k_embed(const int* __restrict__ inputs,
                                               const float* __restrict__ embW,
                                               ushort_t* __restrict__ xhi,
                                               ushort_t* __restrict__ xlo) {
    int blk = blockIdx.x;              // l*T*B + t*B + b
    int b = blk % B;
    int t = (blk / B) % T;
    int l = blk / (B * T);
    int tok = inputs[(l + 1) * B * S + b * S + t];
    const float4* src = (const float4*)(embW + (long long)tok * E);
    float4 v = src[threadIdx.x];
    uint2 hi, lo; split_quad(v, hi, lo);
    size_t base = ((size_t)t * R + (size_t)l * B + b) * E + threadIdx.x * 4;
    *(uint2*)(xhi + base) = hi;
    *(uint2*)(xlo + base) = lo;
}

// ---------------------------------------------------------------------------
__global__ __launch_bounds__(128) void k_pe(const int* __restrict__ inputs,
                                            const int* __restrict__ lens,
                                            const float* __restrict__ embW,
                                            float* __restrict__ pe) {
    int r = blockIdx.x;
    int l = r >> 6, b = r & 63;
    int plen = lens[l * B + b];
    int send = plen - 1;
    if (send > S) send = S;
    const int* toks = inputs + l * B * S + b * S;
    float4 acc = {0.f, 0.f, 0.f, 0.f};
    for (int s = 1; s < send; ++s) {
        int tok = toks[s];
        float4 v = ((const float4*)(embW + (long long)tok * E))[threadIdx.x];
        acc.x += v.x; acc.y += v.y; acc.z += v.z; acc.w += v.w;
    }
    const float inv = 1.f / 32.f;
    acc.x *= inv; acc.y *= inv; acc.z *= inv; acc.w *= inv;
    ((float4*)(pe + (size_t)r * E))[threadIdx.x] = acc;
}

// ---------------------------------------------------------------------------
__global__ __launch_bounds__(256) void k_cm(const float* __restrict__ ctx,
                                            float* __restrict__ cm) {
    int b = blockIdx.x;
    int j = threadIdx.x;
    const float4* c4 = (const float4*)(ctx + (size_t)b * SRC * H);
    float4 acc = {0.f, 0.f, 0.f, 0.f};
    for (int s = 0; s < SRC; ++s) {
        float4 v = c4[(size_t)s * (H / 4) + j];
        acc.x += v.x; acc.y += v.y; acc.z += v.z; acc.w += v.w;
    }
    const float inv = 1.f / (float)SRC;
    acc.x *= inv; acc.y *= inv; acc.z *= inv; acc.w *= inv;
    ((float4*)(cm + (size_t)b * H))[j] = acc;
}

// ---------------------------------------------------------------------------
// Old f32-staged split GEMM for the two init projections (runs once; OK slow).
__global__ __launch_bounds__(256) void k_bgemm(
    const float* __restrict__ A1, const float* __restrict__ W1, int ldw1, int K1,
    const float* __restrict__ A2, const float* __restrict__ W2, int ldw2, int K2,
    const float* __restrict__ bias1, const float* __restrict__ bias2,
    float* __restrict__ C, long long strideL, long long strideB,
    int act, int a2mod) {
    __shared__ __align__(16) ushort_t Af[2][4][64][8];
    __shared__ __align__(16) ushort_t Bf[2][4][64][8];
    const int tid = threadIdx.x;
    const int lane = tid & 63;
    const int wv = tid >> 6;
    const int wm = wv & 1, wn = wv >> 1;
    const int n0 = blockIdx.x * 64;
    const int m0 = blockIdx.y * 64;

    f32x4_v zero = {0.f, 0.f, 0.f, 0.f};
    f32x4_v acc[2][2] = {{zero, zero}, {zero, zero}};

    for (int pass = 0; pass < 2; ++pass) {
        const float* Aop = pass ? A2 : A1;
        const float* Wop = pass ? W2 : W1;
        const int K = pass ? K2 : K1;
        const int ldw = pass ? ldw2 : ldw1;
        const int mod = pass ? a2mod : 0;
        if (Aop == nullptr || K == 0) continue;
        for (int k0 = 0; k0 < K; k0 += 32) {
            __syncthreads();
#pragma unroll
            for (int q = tid; q < 512; q += 256) {
                int kq = q & 7, row = q >> 3;
                int rr = m0 + row; if (mod) rr &= (mod - 1);
                float4 v = *(const float4*)(Aop + (long long)rr * K + k0 + kq * 4);
                uint2 hi, lo; split_quad(v, hi, lo);
                int ms = row >> 4;
                int fl = ((kq & 3) << 4) | (row & 15);
                int off = (kq >> 2) * 4;
                *(uint2*)&Af[0][ms][fl][off] = hi;
                *(uint2*)&Af[1][ms][fl][off] = lo;
            }
#pragma unroll
            for (int q = tid; q < 512; q += 256) {
                int kq = q & 7, row = q >> 3;
                float4 v = *(const float4*)(Wop + (long long)(n0 + row) * ldw + k0 + kq * 4);
                uint2 hi, lo; split_quad(v, hi, lo);
                int ns = row >> 4;
                int fl = ((kq & 3) << 4) | (row & 15);
                int off = (kq >> 2) * 4;
                *(uint2*)&Bf[0][ns][fl][off] = hi;
                *(uint2*)&Bf[1][ns][fl][off] = lo;
            }
            __syncthreads();
            bf16x8_v ah[2], al[2], bh[2], bl[2];
#pragma unroll
            for (int i = 0; i < 2; ++i) {
                ah[i] = *(const bf16x8_v*)&Af[0][wm * 2 + i][lane][0];
                al[i] = *(const bf16x8_v*)&Af[1][wm * 2 + i][lane][0];
                bh[i] = *(const bf16x8_v*)&Bf[0][wn * 2 + i][lane][0];
                bl[i] = *(const bf16x8_v*)&Bf[1][wn * 2 + i][lane][0];
            }
#pragma unroll
            for (int i = 0; i < 2; ++i)
#pragma unroll
                for (int j = 0; j < 2; ++j) {
                    acc[i][j] = __builtin_amdgcn_mfma_f32_16x16x32_bf16(al[i], bh[j], acc[i][j], 0, 0, 0);
                    acc[i][j] = __builtin_amdgcn_mfma_f32_16x16x32_bf16(ah[i], bl[j], acc[i][j], 0, 0, 0);
                    acc[i][j] = __builtin_amdgcn_mfma_f32_16x16x32_bf16(ah[i], bh[j], acc[i][j], 0, 0, 0);
                }
        }
    }

    const int l16 = lane & 15, g4 = (lane >> 4) * 4;
#pragma unroll
    for (int i = 0; i < 2; ++i) {
#pragma unroll
        for (int r = 0; r < 4; ++r) {
            int m = m0 + wm * 32 + i * 16 + g4 + r;
            long long rowoff = (long long)(m >> 6) * strideL + (long long)(m & 63) * strideB;
#pragma unroll
            for (int j = 0; j < 2; ++j) {
                int n = n0 + wn * 32 + j * 16 + l16;
                float v = acc[i][j][r] + bias1[n];
                if (bias2) v += bias2[n];
                if (act) v = tanhf(v);
                C[rowoff + n] = v;
            }
        }
    }
}

// ---------------------------------------------------------------------------
// Fast in-loop GEMM: C = act( A1@W1^T + A2@W2^T + bias1 (+bias2) )
// A given as pre-split bf16 hi/lo planes (row-major, lda = Kp), staged via
// global_load_lds (linear LDS + inverse-XOR-swizzled source, rule 21).
// W is f32 (N x ldw), register-staged (T14), split to bf16 hi/lo on ds_write
// with the same XOR swizzle. BK=64, tile 64x64, 4 waves (2x2), A double-buffered,
// raw s_barrier (no vmcnt drain) so next-step loads fly under compute.
__global__ __launch_bounds__(256) void k_mgemm(
    const ushort_t* __restrict__ Ah1, const ushort_t* __restrict__ Al1, int K1,
    const ushort_t* __restrict__ Ah2, const ushort_t* __restrict__ Al2, int K2,
    const float* __restrict__ W1, int ldw1,
    const float* __restrict__ W2, int ldw2,
    const float* __restrict__ bias1, const float* __restrict__ bias2,
    float* __restrict__ C, long long strideL, long long strideB, int act) {
    // LDS: A dbuf 2 x (hi 8K + lo 8K) = 32K, B (hi 8K + lo 8K) = 16K
    __shared__ __align__(16) unsigned char lds[49152];
    const int tid = threadIdx.x;
    const int lane = tid & 63;
    const int wv = tid >> 6;
    const int wm = wv & 1, wn = wv >> 1;
    const int n0 = blockIdx.x * 64;
    const int m0 = blockIdx.y * 64;
    const int n1steps = K1 >> 6;
    const int NT = (K1 + K2) >> 6;

    f32x4_v zero = {0.f, 0.f, 0.f, 0.f};
    f32x4_v acc[2][2] = {{zero, zero}, {zero, zero}};
    float4 wreg[4];

    // --- stage helpers -----------------------------------------------------
    auto loadW = [&](int t) {
        const float* W; int ldw, k0;
        if (t < n1steps) { W = W1; ldw = ldw1; k0 = t << 6; }
        else             { W = W2; ldw = ldw2; k0 = (t - n1steps) << 6; }
        const float* src = W + (size_t)(n0 + (tid >> 2)) * ldw + k0 + (tid & 3) * 16;
#pragma unroll
        for (int i = 0; i < 4; ++i) wreg[i] = ((const float4*)src)[i];
    };
    auto stageA = [&](int t, int buf) {
        const ushort_t *Ah, *Al; int lda, k0;
        if (t < n1steps) { Ah = Ah1; Al = Al1; lda = K1; k0 = t << 6; }
        else             { Ah = Ah2; Al = Al2; lda = K2; k0 = (t - n1steps) << 6; }
        int xorc = ((lane & 7) * 16) ^ ((lane >> 3) << 4);
#pragma unroll
        for (int cc = 0; cc < 4; ++cc) {
            int c = wv * 4 + cc;           // 0..15
            int p = c >> 3, s = c & 7;
            const ushort_t* plane = p ? Al : Ah;
            const unsigned char* gsrc = (const unsigned char*)(plane
                + (size_t)(m0 + 8 * s + (lane >> 3)) * lda + k0) + xorc;
            unsigned char* ldst = &lds[buf * 16384 + p * 8192 + s * 1024];
            gl_lds16(gsrc, ldst);
        }
    };
    auto commitW = [&]() {
        int rB = tid >> 2;
        int cbase = (tid & 3) * 32;
        int rowbyte = 32768 + rB * 128;
        int sw = (rB & 7) << 4;
#pragma unroll
        for (int i = 0; i < 4; ++i) {
            uint2 hi, lo; split_quad(wreg[i], hi, lo);
            int cb = (cbase + i * 8) ^ sw;
            *(uint2*)&lds[rowbyte + cb] = hi;
            *(uint2*)&lds[rowbyte + 8192 + cb] = lo;
        }
    };
    auto compute = [&](int buf) {
        const unsigned char* Ab = &lds[buf * 16384];
        const unsigned char* Bb = &lds[32768];
#pragma unroll
        for (int kf = 0; kf < 2; ++kf) {
            int colA = (kf * 64 + ((lane >> 4) * 16)) ^ ((lane & 7) << 4);
            bf16x8_v ah[2], al[2], bh[2], bl[2];
#pragma unroll
            for (int i = 0; i < 2; ++i) {
                int rowm = (wm * 2 + i) * 16 + (lane & 15);
                ah[i] = *(const bf16x8_v*)(Ab + rowm * 128 + colA);
                al[i] = *(const bf16x8_v*)(Ab + 8192 + rowm * 128 + colA);
                int rown = (wn * 2 + i) * 16 + (lane & 15);
                bh[i] = *(const bf16x8_v*)(Bb + rown * 128 + colA);
                bl[i] = *(const bf16x8_v*)(Bb + 8192 + rown * 128 + colA);
            }
#pragma unroll
            for (int i = 0; i < 2; ++i)
#pragma unroll
                for (int j = 0; j < 2; ++j) {
                    acc[i][j] = __builtin_amdgcn_mfma_f32_16x16x32_bf16(al[i], bh[j], acc[i][j], 0, 0, 0);
                    acc[i][j] = __builtin_amdgcn_mfma_f32_16x16x32_bf16(ah[i], bl[j], acc[i][j], 0, 0, 0);
                    acc[i][j] = __builtin_amdgcn_mfma_f32_16x16x32_bf16(ah[i], bh[j], acc[i][j], 0, 0, 0);
                }
        }
    };

    // --- pipeline ----------------------------------------------------------
    loadW(0);
    stageA(0, 0);
    int cur = 0;
    for (int t = 0; t < NT; ++t) {
        asm volatile("s_waitcnt vmcnt(0)" ::: "memory");   // W(t) regs + A(t) LDS arrived
        commitW();                                          // split W(t) -> LDS B tile
        if (t + 1 < NT) {
            loadW(t + 1);                                   // f32 W prefetch (regs)
            stageA(t + 1, cur ^ 1);                         // A prefetch (LDS dbuf)
        }
        asm volatile("s_waitcnt lgkmcnt(0)" ::: "memory");  // my ds_writes done
        __builtin_amdgcn_s_barrier();                       // B + A[cur] visible to all
        __builtin_amdgcn_sched_barrier(0);
        compute(cur);
        __builtin_amdgcn_sched_barrier(0);
        __builtin_amdgcn_s_barrier();                       // all reads done before overwrite
        cur ^= 1;
    }

    // --- epilogue (C/D map per m89: col = lane&15, row = (lane>>4)*4 + r) ---
    const int l16 = lane & 15, g4 = (lane >> 4) * 4;
#pragma unroll
    for (int i = 0; i < 2; ++i) {
#pragma unroll
        for (int r = 0; r < 4; ++r) {
            int m = m0 + wm * 32 + i * 16 + g4 + r;
            long long rowoff = (long long)(m >> 6) * strideL + (long long)(m & 63) * strideB;
#pragma unroll
            for (int j = 0; j < 2; ++j) {
                int n = n0 + wn * 32 + j * 16 + l16;
                float v = acc[i][j][r] + bias1[n];
                if (bias2) v += bias2[n];
                if (act) v = tanhf(v);
                C[rowoff + n] = v;
            }
        }
    }
}

// ---------------------------------------------------------------------------
// LSTM pointwise; writes f32 h,c and bf16 hi/lo planes of h.
__global__ __launch_bounds__(256) void k_lstm(const float* __restrict__ g,
                                              float* __restrict__ hbuf,
                                              float* __restrict__ cbuf,
                                              ushort_t* __restrict__ hhi,
                                              ushort_t* __restrict__ hlo) {
    int idx = blockIdx.x * 256 + threadIdx.x;      // R*H = 262144
    int r = idx >> 10, h = idx & 1023;
    const float* gr = g + (long long)r * 4096;
    float gi = gr[h], gf = gr[1024 + h], gg = gr[2048 + h], go = gr[3072 + h];
    float cp = cbuf[idx];
    float si = 1.f / (1.f + expf(-gi));
    float sf = 1.f / (1.f + expf(-gf));
    float so = 1.f / (1.f + expf(-go));
    float c = sf * cp + si * tanhf(gg);
    float hn = so * tanhf(c);
    cbuf[idx] = c;
    hbuf[idx] = hn;
    uint_t hu, lu; split1(hn, hu, lu);
    hhi[idx] = (ushort_t)hu;
    hlo[idx] = (ushort_t)lu;
}

// ---------------------------------------------------------------------------
// Init: copy h/c level-1 state and emit bf16 planes for h0 and h1.
__global__ __launch_bounds__(256) void k_init_split(const float* __restrict__ h0f,
                                                    const float* __restrict__ c0f,
                                                    float* __restrict__ h1f,
                                                    float* __restrict__ c1f,
                                                    ushort_t* __restrict__ h0hi,
                                                    ushort_t* __restrict__ h0lo,
                                                    ushort_t* __restrict__ h1hi,
                                                    ushort_t* __restrict__ h1lo) {
    int idx = blockIdx.x * 256 + threadIdx.x;
    float h = h0f[idx], c = c0f[idx];
    h1f[idx] = h; c1f[idx] = c;
    uint_t hu, lu; split1(h, hu, lu);
    h0hi[idx] = (ushort_t)hu; h0lo[idx] = (ushort_t)lu;
    h1hi[idx] = (ushort_t)hu; h1lo[idx] = (ushort_t)lu;
}

// ---------------------------------------------------------------------------
// Attention; writes bf16 hi/lo planes of ct.
__global__ __launch_bounds__(256) void k_attn(const float* __restrict__ ctx,
                                              const float* __restrict__ gamma,
                                              ushort_t* __restrict__ cthi,
                                              ushort_t* __restrict__ ctlo) {
    __shared__ float gam[L4][H];
    __shared__ float wsm[L4][SRC];
    const int b = blockIdx.x;
    const int tid = threadIdx.x;
    const int wave = tid >> 6, lane = tid & 63;

#pragma unroll
    for (int l = 0; l < L4; ++l) {
        const float4* src = (const float4*)(gamma + (size_t)(l * B + b) * H);
        ((float4*)gam[l])[tid] = src[tid];
    }
    __syncthreads();

    const float* ctxb = ctx + (size_t)b * SRC * H;
    for (int s8 = 0; s8 < 64; ++s8) {
        int s = wave * 64 + s8;
        const float* cs = ctxb + (size_t)s * H;
        float a0 = 0.f, a1 = 0.f, a2 = 0.f, a3 = 0.f;
#pragma unroll
        for (int j = 0; j < 16; ++j) {
            int h = lane + 64 * j;
            float cv = cs[h];
            a0 += cv * gam[0][h];
            a1 += cv * gam[1][h];
            a2 += cv * gam[2][h];
            a3 += cv * gam[3][h];
        }
#pragma unroll
        for (int off = 32; off >= 1; off >>= 1) {
            a0 += __shfl_xor(a0, off);
            a1 += __shfl_xor(a1, off);
            a2 += __shfl_xor(a2, off);
            a3 += __shfl_xor(a3, off);
        }
        if (lane == 0) {
            wsm[0][s] = a0; wsm[1][s] = a1; wsm[2][s] = a2; wsm[3][s] = a3;
        }
    }
    __syncthreads();

    {
        int l = wave;
        float v0 = wsm[l][lane], v1 = wsm[l][lane + 64];
        float v2 = wsm[l][lane + 128], v3 = wsm[l][lane + 192];
        float m = fmaxf(fmaxf(v0, v1), fmaxf(v2, v3));
#pragma unroll
        for (int off = 32; off >= 1; off >>= 1) m = fmaxf(m, __shfl_xor(m, off));
        float e0 = expf(v0 - m), e1 = expf(v1 - m), e2 = expf(v2 - m), e3 = expf(v3 - m);
        float sum = e0 + e1 + e2 + e3;
#pragma unroll
        for (int off = 32; off >= 1; off >>= 1) sum += __shfl_xor(sum, off);
        float inv = 1.f / sum;
        wsm[l][lane] = e0 * inv;
        wsm[l][lane + 64] = e1 * inv;
        wsm[l][lane + 128] = e2 * inv;
        wsm[l][lane + 192] = e3 * inv;
    }
    __syncthreads();

    float4 acc[L4];
#pragma unroll
    for (int l = 0; l < L4; ++l) acc[l] = make_float4(0.f, 0.f, 0.f, 0.f);
    const float4* ctx4 = (const float4*)ctxb;
    for (int s = 0; s < SRC; ++s) {
        float4 cv = ctx4[(size_t)s * (H / 4) + tid];
        float w0 = wsm[0][s], w1 = wsm[1][s], w2 = wsm[2][s], w3 = wsm[3][s];
        acc[0].x += w0 * cv.x; acc[0].y += w0 * cv.y; acc[0].z += w0 * cv.z; acc[0].w += w0 * cv.w;
        acc[1].x += w1 * cv.x; acc[1].y += w1 * cv.y; acc[1].z += w1 * cv.z; acc[1].w += w1 * cv.w;
        acc[2].x += w2 * cv.x; acc[2].y += w2 * cv.y; acc[2].z += w2 * cv.z; acc[2].w += w2 * cv.w;
        acc[3].x += w3 * cv.x; acc[3].y += w3 * cv.y; acc[3].z += w3 * cv.z; acc[3].w += w3 * cv.w;
    }
#pragma unroll
    for (int l = 0; l < L4; ++l) {
        uint2 hi, lo; split_quad(acc[l], hi, lo);
        size_t base = (size_t)(l * B + b) * H + tid * 4;
        *(uint2*)(cthi + base) = hi;
        *(uint2*)(ctlo + base) = lo;
    }
}

// ---------------------------------------------------------------------------
extern "C" void kernel_launch(void* const* d_in, const int* in_sizes, int n_in,
                              void* d_out, int out_size, void* d_ws, size_t ws_size,
                              hipStream_t stream) {
    const int*   inputs     = (const int*)d_in[0];
    const int*   input_lens = (const int*)d_in[1];
    const float* contexts   = (const float*)d_in[2];
    const float* emb_W      = (const float*)d_in[3];
    const float* W_ih0      = (const float*)d_in[4];
    const float* W_hh0      = (const float*)d_in[5];
    const float* b_ih0      = (const float*)d_in[6];
    const float* b_hh0      = (const float*)d_in[7];
    const float* W_ih1      = (const float*)d_in[8];
    const float* W_hh1      = (const float*)d_in[9];
    const float* b_ih1      = (const float*)d_in[10];
    const float* b_hh1      = (const float*)d_in[11];
    const float* att_in_W   = (const float*)d_in[12];
    const float* att_in_b   = (const float*)d_in[13];
    const float* att_out_W  = (const float*)d_in[14];
    const float* att_out_b  = (const float*)d_in[15];
    const float* isl_in_W   = (const float*)d_in[16];
    const float* isl_in_b   = (const float*)d_in[17];
    const float* isl_out_W  = (const float*)d_in[18];
    const float* isl_out_b  = (const float*)d_in[19];

    float* out = (float*)d_out;

    // workspace carve (256B-aligned regions)
    char* p = (char*)d_ws;
    auto alloc = [&](size_t bytes) { char* r = p; p += (bytes + 255) & ~(size_t)255; return r; };
    ushort_t* xs_hi = (ushort_t*)alloc((size_t)T * R * E * 2);
    ushort_t* xs_lo = (ushort_t*)alloc((size_t)T * R * E * 2);
    ushort_t* h0hi  = (ushort_t*)alloc((size_t)R * H * 2);
    ushort_t* h0lo  = (ushort_t*)alloc((size_t)R * H * 2);
    ushort_t* h1hi  = (ushort_t*)alloc((size_t)R * H * 2);
    ushort_t* h1lo  = (ushort_t*)alloc((size_t)R * H * 2);
    ushort_t* cthi  = (ushort_t*)alloc((size_t)R * H * 2);
    ushort_t* ctlo  = (ushort_t*)alloc((size_t)R * H * 2);
    float* pe  = (float*)alloc((size_t)R * E * 4);
    float* cm  = (float*)alloc((size_t)B * H * 4);
    float* h0f = (float*)alloc((size_t)R * H * 4);
    float* h1f = (float*)alloc((size_t)R * H * 4);
    float* c0f = (float*)alloc((size_t)R * H * 4);
    float* c1f = (float*)alloc((size_t)R * H * 4);
    float* g   = (float*)alloc((size_t)R * 4 * H * 4);
    float* gam = (float*)alloc((size_t)R * H * 4);

    // ---- setup ----
    k_embed<<<L4 * T * B, 128, 0, stream>>>(inputs, emb_W, xs_hi, xs_lo);
    k_pe<<<R, 128, 0, stream>>>(inputs, input_lens, emb_W, pe);
    k_cm<<<B, 256, 0, stream>>>(contexts, cm);

    k_bgemm<<<dim3(16, 4), 256, 0, stream>>>(pe, isl_in_W, 1536, 512,
                                             cm, isl_in_W + 512, 1536, 1024,
                                             isl_in_b, nullptr,
                                             h0f, 64LL * H, (long long)H, 1, 64);
    k_bgemm<<<dim3(16, 4), 256, 0, stream>>>(pe, isl_out_W + 1024, 1536, 512,
                                             cm, isl_out_W, 1536, 1024,
                                             isl_out_b, nullptr,
                                             c0f, 64LL * H, (long long)H, 1, 64);
    k_init_split<<<R * H / 256, 256, 0, stream>>>(h0f, c0f, h1f, c1f,
                                                  h0hi, h0lo, h1hi, h1lo);

    // ---- recurrent loop ----
    for (int t = 0; t < T; ++t) {
        const ushort_t* xh = xs_hi + (size_t)t * R * E;
        const ushort_t* xl = xs_lo + (size_t)t * R * E;
        // layer0 gates: [x | h0] @ [W_ih0 | W_hh0]^T
        k_mgemm<<<dim3(64, 4), 256, 0, stream>>>(xh, xl, 512,
                                                 h0hi, h0lo, 1024,
                                                 W_ih0, 512, W_hh0, 1024,
                                                 b_ih0, b_hh0,
                                                 g, 64LL * 4096, 4096LL, 0);
        k_lstm<<<1024, 256, 0, stream>>>(g, h0f, c0f, h0hi, h0lo);
        // layer1 gates: [h0 | h1] @ [W_ih1 | W_hh1]^T
        k_mgemm<<<dim3(64, 4), 256, 0, stream>>>(h0hi, h0lo, 1024,
                                                 h1hi, h1lo, 1024,
                                                 W_ih1, 1024, W_hh1, 1024,
                                                 b_ih1, b_hh1,
                                                 g, 64LL * 4096, 4096LL, 0);
        k_lstm<<<1024, 256, 0, stream>>>(g, h1f, c1f, h1hi, h1lo);
        // gamma = h2 @ att_in_W^T + b
        k_mgemm<<<dim3(16, 4), 256, 0, stream>>>(h1hi, h1lo, 1024,
                                                 nullptr, nullptr, 0,
                                                 att_in_W, 1024, nullptr, 0,
                                                 att_in_b, nullptr,
                                                 gam, 64LL * H, (long long)H, 0);
        // attention
        k_attn<<<B, 256, 0, stream>>>(contexts, gam, cthi, ctlo);
        // out = tanh([ct | h2] @ att_out_W^T + b) scattered into outs[l,t,b,:]
        k_mgemm<<<dim3(16, 4), 256, 0, stream>>>(cthi, ctlo, 1024,
                                                 h1hi, h1lo, 1024,
                                                 att_out_W, 2048, att_out_W + 1024, 2048,
                                                 att_out_b, nullptr,
                                                 out + (size_t)t * B * H,
                                                 (long long)T * B * H, (long long)H, 1);
    }

    // ---- finals ----
    size_t OUTS = (size_t)L4 * T * B * H;
    size_t seg = (size_t)B * H;
    hipMemcpyAsync(out + OUTS,           h0f + 192 * H, seg * 4, hipMemcpyDeviceToDevice, stream);
    hipMemcpyAsync(out + OUTS + seg,     h1f + 192 * H, seg * 4, hipMemcpyDeviceToDevice, stream);
    hipMemcpyAsync(out + OUTS + 2 * seg, c0f + 192 * H, seg * 4, hipMemcpyDeviceToDevice, stream);
    hipMemcpyAsync(out + OUTS + 3 * seg, c1f + 192 * H, seg * 4, hipMemcpyDeviceToDevice, stream);
}

// Round 4
// 4134.117 us; speedup vs baseline: 4.1792x; 1.3933x over previous
//
#include <hip/hip_runtime.h>
#include <math.h>

#define E 512
#define H 1024
#define B 64
#define S 32
#define SRC 256
#define L4 4      // NLEV-1 levels actually processed
#define T 31      // S-1 timesteps
#define R 256     // L4*B rows (effective batch)

typedef unsigned int uint_t;
typedef unsigned short ushort_t;
typedef float f32x4_v __attribute__((ext_vector_type(4)));
typedef short bf16x8_v __attribute__((ext_vector_type(8)));

// ---------------------------------------------------------------------------
// split f32 -> bf16 hi (truncate) + bf16 lo (truncated remainder)
__device__ __forceinline__ void split1(float x, uint_t& h, uint_t& l) {
    uint_t u = __float_as_uint(x);
    h = u >> 16;
    float hf = __uint_as_float(u & 0xFFFF0000u);
    l = __float_as_uint(x - hf) >> 16;
}

__device__ __forceinline__ void split_quad(float4 v, uint2& hi, uint2& lo) {
    uint_t h0, h1, h2, h3, l0, l1, l2, l3;
    split1(v.x, h0, l0); split1(v.y, h1, l1);
    split1(v.z, h2, l2); split1(v.w, h3, l3);
    hi.x = h0 | (h1 << 16); hi.y = h2 | (h3 << 16);
    lo.x = l0 | (l1 << 16); lo.y = l2 | (l3 << 16);
}

__device__ __forceinline__ void gl_lds16(const void* g, void* l) {
    __builtin_amdgcn_global_load_lds(
        (const __attribute__((address_space(1))) void*)g,
        (__attribute__((address_space(3))) void*)l, 16, 0, 0);
}

// ---------------------------------------------------------------------------
// Embeddings -> bf16 hi/lo planes: xs[t*R + l*B+b][e]
__global__ __launch_bounds__(128) void k_embed(const int* __restrict__ inputs,
                                               const float* __restrict__ embW,
                                               ushort_t* __restrict__ xhi,
                                               ushort_t* __restrict__ xlo) {
    int blk = blockIdx.x;              // l*T*B + t*B + b
    int b = blk % B;
    int t = (blk / B) % T;
    int l = blk / (B * T);
    int tok = inputs[(l + 1) * B * S + b * S + t];
    const float4* src = (const float4*)(embW + (long long)tok * E);
    float4 v = src[threadIdx.x];
    uint2 hi, lo; split_quad(v, hi, lo);
    size_t base = ((size_t)t * R + (size_t)l * B + b) * E + threadIdx.x * 4;
    *(uint2*)(xhi + base) = hi;
    *(uint2*)(xlo + base) = lo;
}

// ---------------------------------------------------------------------------
// pe mean -> bf16 hi/lo planes
__global__ __launch_bounds__(128) void k_pe(const int* __restrict__ inputs,
                                            const int* __restrict__ lens,
                                            const float* __restrict__ embW,
                                            ushort_t* __restrict__ phi,
                                            ushort_t* __restrict__ plo) {
    int r = blockIdx.x;
    int l = r >> 6, b = r & 63;
    int plen = lens[l * B + b];
    int send = plen - 1;
    if (send > S) send = S;
    const int* toks = inputs + l * B * S + b * S;
    float4 acc = {0.f, 0.f, 0.f, 0.f};
    for (int s = 1; s < send; ++s) {
        int tok = toks[s];
        float4 v = ((const float4*)(embW + (long long)tok * E))[threadIdx.x];
        acc.x += v.x; acc.y += v.y; acc.z += v.z; acc.w += v.w;
    }
    const float inv = 1.f / 32.f;
    acc.x *= inv; acc.y *= inv; acc.z *= inv; acc.w *= inv;
    uint2 hi, lo; split_quad(acc, hi, lo);
    size_t base = (size_t)r * E + threadIdx.x * 4;
    *(uint2*)(phi + base) = hi;
    *(uint2*)(plo + base) = lo;
}

// ---------------------------------------------------------------------------
// cm mean -> bf16 hi/lo planes
__global__ __launch_bounds__(256) void k_cm(const float* __restrict__ ctx,
                                            ushort_t* __restrict__ chi,
                                            ushort_t* __restrict__ clo) {
    int b = blockIdx.x;
    int j = threadIdx.x;
    const float4* c4 = (const float4*)(ctx + (size_t)b * SRC * H);
    float4 acc = {0.f, 0.f, 0.f, 0.f};
    for (int s = 0; s < SRC; ++s) {
        float4 v = c4[(size_t)s * (H / 4) + j];
        acc.x += v.x; acc.y += v.y; acc.z += v.z; acc.w += v.w;
    }
    const float inv = 1.f / (float)SRC;
    acc.x *= inv; acc.y *= inv; acc.z *= inv; acc.w *= inv;
    uint2 hi, lo; split_quad(acc, hi, lo);
    size_t base = (size_t)b * H + j * 4;
    *(uint2*)(chi + base) = hi;
    *(uint2*)(clo + base) = lo;
}

// ---------------------------------------------------------------------------
// Unified split-bf16 MFMA GEMM, 512 threads = 2 k-split groups x 4 waves.
// A = concat([A1(K1) | A2(K2)]) as pre-split bf16 hi/lo planes, staged with
// global_load_lds + XOR swizzle (both-sides, rule 21). W f32 register-staged,
// split on ds_write. Tile 64m x 64cols, BK=64, A double-buffered, raw
// s_barrier in the K-loop (prefetch survives the barrier).
// wmap: 0 -> W row = n0 + j (plain N cols); 1 -> gate-interleaved: col j is
//       gate q=j>>4, h-col nh0+(j&15); W row = q*H + nh0 + (j&15).
// mode: 0 -> C = act(g + bias1 (+bias2)), scatter rows by strideL/strideB
//       1 -> fused LSTM pointwise: c,h update + h hi/lo planes
__global__ __launch_bounds__(512) void k_fgemm(
    const ushort_t* __restrict__ Ah1, const ushort_t* __restrict__ Al1, int K1,
    const ushort_t* __restrict__ Ah2, const ushort_t* __restrict__ Al2, int K2,
    const float* __restrict__ W1, int ldw1,
    const float* __restrict__ W2, int ldw2,
    const float* __restrict__ bias1, const float* __restrict__ bias2,
    int wmap, int a2mod, int mode,
    float* __restrict__ C, long long strideL, long long strideB, int act,
    float* __restrict__ cbuf, float* __restrict__ hf,
    ushort_t* __restrict__ hhi, ushort_t* __restrict__ hlo) {
    // LDS: A: gi*32K + buf*16K (64KB), B: 64K + gi*16K (32KB). gtile aliases 64K+.
    __shared__ __align__(16) unsigned char lds[98304];
    const int tid = threadIdx.x;
    const int gi = tid >> 8;           // k-split group 0/1
    const int gt = tid & 255;
    const int lane = tid & 63;
    const int gwv = (tid >> 6) & 3;    // wave within group
    const int wm = gwv & 1, wn = gwv >> 1;
    const int m0 = blockIdx.y * 64;
    const int NT = (K1 + K2) >> 6;
    const int NTg = NT >> 1;
    const int n1steps = K1 >> 6;
    unsigned char* Abase = lds + (gi << 15);
    unsigned char* Bbase = lds + 65536 + (gi << 14);
    float* gtile = (float*)(lds + 65536);     // [64][68] f32

    f32x4_v zero = {0.f, 0.f, 0.f, 0.f};
    f32x4_v acc[2][2] = {{zero, zero}, {zero, zero}};
    float4 wreg[4];

    auto wrow = [&](int j) -> long long {
        return wmap ? (long long)((j >> 4) * H + blockIdx.x * 16 + (j & 15))
                    : (long long)(blockIdx.x * 64 + j);
    };
    auto loadW = [&](int t) {
        const float* W; int ldw, k0;
        if (t < n1steps) { W = W1; ldw = ldw1; k0 = t << 6; }
        else             { W = W2; ldw = ldw2; k0 = (t - n1steps) << 6; }
        const float4* src = (const float4*)(W + wrow(gt >> 2) * ldw + k0 + (gt & 3) * 16);
#pragma unroll
        for (int i = 0; i < 4; ++i) wreg[i] = src[i];
    };
    auto stageA = [&](int t, int buf) {
        const ushort_t *Ph, *Pl; int lda, k0, mod;
        if (t < n1steps) { Ph = Ah1; Pl = Al1; lda = K1; k0 = t << 6; mod = 0; }
        else             { Ph = Ah2; Pl = Al2; lda = K2; k0 = (t - n1steps) << 6; mod = a2mod; }
        int xorc = ((lane & 7) * 16) ^ ((lane >> 3) << 4);
#pragma unroll
        for (int cc = 0; cc < 4; ++cc) {
            int c = gwv * 4 + cc;              // 0..15
            int p = c >> 3, s = c & 7;
            int rr = m0 + 8 * s + (lane >> 3);
            if (mod) rr &= (mod - 1);
            const ushort_t* plane = p ? Pl : Ph;
            const unsigned char* gsrc =
                (const unsigned char*)(plane + (size_t)rr * lda + k0) + xorc;
            gl_lds16(gsrc, Abase + buf * 16384 + p * 8192 + s * 1024);
        }
    };
    auto commitW = [&]() {
        int rB = gt >> 2;
        int cbase = (gt & 3) * 32;
        unsigned char* row = Bbase + rB * 128;
        int sw = (rB & 7) << 4;
        uint2 h0, h1, h2, h3, l0, l1, l2, l3;
        split_quad(wreg[0], h0, l0); split_quad(wreg[1], h1, l1);
        split_quad(wreg[2], h2, l2); split_quad(wreg[3], h3, l3);
        uint4 H01 = {h0.x, h0.y, h1.x, h1.y}, H23 = {h2.x, h2.y, h3.x, h3.y};
        uint4 L01 = {l0.x, l0.y, l1.x, l1.y}, L23 = {l2.x, l2.y, l3.x, l3.y};
        int c0 = cbase ^ sw, c1 = (cbase + 16) ^ sw;
        *(uint4*)(row + c0) = H01;
        *(uint4*)(row + c1) = H23;
        *(uint4*)(row + 8192 + c0) = L01;
        *(uint4*)(row + 8192 + c1) = L23;
    };
    auto compute = [&](int buf) {
        const unsigned char* Ab = Abase + buf * 16384;
        const unsigned char* Bb = Bbase;
#pragma unroll
        for (int kf = 0; kf < 2; ++kf) {
            int colA = (kf * 64 + ((lane >> 4) * 16)) ^ ((lane & 7) << 4);
            bf16x8_v ah[2], al[2], bh[2], bl[2];
#pragma unroll
            for (int i = 0; i < 2; ++i) {
                int rowm = (wm * 2 + i) * 16 + (lane & 15);
                ah[i] = *(const bf16x8_v*)(Ab + rowm * 128 + colA);
                al[i] = *(const bf16x8_v*)(Ab + 8192 + rowm * 128 + colA);
                int rj = (wn * 2 + i) * 16 + (lane & 15);
                bh[i] = *(const bf16x8_v*)(Bb + rj * 128 + colA);
                bl[i] = *(const bf16x8_v*)(Bb + 8192 + rj * 128 + colA);
            }
            __builtin_amdgcn_s_setprio(1);
#pragma unroll
            for (int i = 0; i < 2; ++i)
#pragma unroll
                for (int j = 0; j < 2; ++j) {
                    acc[i][j] = __builtin_amdgcn_mfma_f32_16x16x32_bf16(al[i], bh[j], acc[i][j], 0, 0, 0);
                    acc[i][j] = __builtin_amdgcn_mfma_f32_16x16x32_bf16(ah[i], bl[j], acc[i][j], 0, 0, 0);
                    acc[i][j] = __builtin_amdgcn_mfma_f32_16x16x32_bf16(ah[i], bh[j], acc[i][j], 0, 0, 0);
                }
            __builtin_amdgcn_s_setprio(0);
        }
    };

    // --- pipelined K-loop (each group covers its half of the K tiles) ------
    const int tbase = gi * NTg;
    loadW(tbase);
    stageA(tbase, 0);
    int cur = 0;
    for (int tt = 0; tt < NTg; ++tt) {
        asm volatile("s_waitcnt vmcnt(0)" ::: "memory");
        commitW();
        if (tt + 1 < NTg) {
            loadW(tbase + tt + 1);
            stageA(tbase + tt + 1, cur ^ 1);
        }
        asm volatile("s_waitcnt lgkmcnt(0)" ::: "memory");
        __builtin_amdgcn_s_barrier();
        __builtin_amdgcn_sched_barrier(0);
        compute(cur);
        __builtin_amdgcn_sched_barrier(0);
        __builtin_amdgcn_s_barrier();
        cur ^= 1;
    }

    // --- cross-group reduction + epilogue ---------------------------------
    const int l16 = lane & 15, g4 = (lane >> 4) * 4;
    if (gi == 1) {
#pragma unroll
        for (int i = 0; i < 2; ++i)
#pragma unroll
            for (int jj = 0; jj < 2; ++jj)
#pragma unroll
                for (int r = 0; r < 4; ++r)
                    gtile[(wm * 32 + i * 16 + g4 + r) * 68 + wn * 32 + jj * 16 + l16] = acc[i][jj][r];
    }
    __syncthreads();
    if (gi == 0) {
#pragma unroll
        for (int i = 0; i < 2; ++i)
#pragma unroll
            for (int jj = 0; jj < 2; ++jj)
#pragma unroll
                for (int r = 0; r < 4; ++r)
                    acc[i][jj][r] += gtile[(wm * 32 + i * 16 + g4 + r) * 68 + wn * 32 + jj * 16 + l16];
        if (mode == 0) {
#pragma unroll
            for (int i = 0; i < 2; ++i) {
#pragma unroll
                for (int r = 0; r < 4; ++r) {
                    int m = m0 + wm * 32 + i * 16 + g4 + r;
                    long long rowoff = (long long)(m >> 6) * strideL + (long long)(m & 63) * strideB;
#pragma unroll
                    for (int jj = 0; jj < 2; ++jj) {
                        int n = blockIdx.x * 64 + wn * 32 + jj * 16 + l16;
                        float v = acc[i][jj][r] + bias1[n];
                        if (bias2) v += bias2[n];
                        if (act) v = tanhf(v);
                        C[rowoff + n] = v;
                    }
                }
            }
        } else {
            // write summed gates back for the pointwise stage
#pragma unroll
            for (int i = 0; i < 2; ++i)
#pragma unroll
                for (int jj = 0; jj < 2; ++jj)
#pragma unroll
                    for (int r = 0; r < 4; ++r)
                        gtile[(wm * 32 + i * 16 + g4 + r) * 68 + wn * 32 + jj * 16 + l16] = acc[i][jj][r];
        }
    }
    if (mode == 1) {
        __syncthreads();
        // all 512 threads: LSTM pointwise on 64 rows x 16 h-cols
        int m = tid >> 3;
        int hcb = (tid & 7) * 2;
        int nh0 = blockIdx.x * 16;
#pragma unroll
        for (int e = 0; e < 2; ++e) {
            int hc = hcb + e;
            float gv[4];
#pragma unroll
            for (int q = 0; q < 4; ++q) {
                int bidx = q * H + nh0 + hc;
                gv[q] = gtile[m * 68 + q * 16 + hc] + bias1[bidx] + bias2[bidx];
            }
            size_t idx = (size_t)(m0 + m) * H + nh0 + hc;
            float cp = cbuf[idx];
            float si = 1.f / (1.f + __expf(-gv[0]));
            float sf = 1.f / (1.f + __expf(-gv[1]));
            float so = 1.f / (1.f + __expf(-gv[3]));
            float c = sf * cp + si * tanhf(gv[2]);
            float hn = so * tanhf(c);
            cbuf[idx] = c;
            hf[idx] = hn;
            uint_t hu, lu; split1(hn, hu, lu);
            hhi[idx] = (ushort_t)hu;
            hlo[idx] = (ushort_t)lu;
        }
    }
}

// ---------------------------------------------------------------------------
// Init: emit bf16 planes for h0/h1 (set 0) and copy h/c to layer-1 buffers.
__global__ __launch_bounds__(256) void k_init_split(const float* __restrict__ h0f,
                                                    const float* __restrict__ c0f,
                                                    float* __restrict__ h1f,
                                                    float* __restrict__ c1f,
                                                    ushort_t* __restrict__ h0hi,
                                                    ushort_t* __restrict__ h0lo,
                                                    ushort_t* __restrict__ h1hi,
                                                    ushort_t* __restrict__ h1lo) {
    int idx = blockIdx.x * 256 + threadIdx.x;
    float h = h0f[idx], c = c0f[idx];
    h1f[idx] = h; c1f[idx] = c;
    uint_t hu, lu; split1(h, hu, lu);
    h0hi[idx] = (ushort_t)hu; h0lo[idx] = (ushort_t)lu;
    h1hi[idx] = (ushort_t)hu; h1lo[idx] = (ushort_t)lu;
}

// ---------------------------------------------------------------------------
// Attention (512 thr): scores over SRC, softmax, ct; writes ct hi/lo planes.
__global__ __launch_bounds__(512) void k_attn(const float* __restrict__ ctx,
                                              const float* __restrict__ gamma,
                                              ushort_t* __restrict__ cthi,
                                              ushort_t* __restrict__ ctlo) {
    __shared__ float gam[L4][H];
    __shared__ float wsm[L4][SRC];
    const int b = blockIdx.x;
    const int tid = threadIdx.x;
    const int wave = tid >> 6, lane = tid & 63;

    for (int q = tid; q < 1024; q += 512) {
        int l = q >> 8;
        ((float4*)gam[l])[q & 255] =
            ((const float4*)(gamma + (size_t)(l * B + b) * H))[q & 255];
    }
    __syncthreads();

    const float* ctxb = ctx + (size_t)b * SRC * H;
    for (int s8 = 0; s8 < 32; ++s8) {
        int s = wave * 32 + s8;
        const float* cs = ctxb + (size_t)s * H;
        float a0 = 0.f, a1 = 0.f, a2 = 0.f, a3 = 0.f;
#pragma unroll
        for (int j = 0; j < 16; ++j) {
            int h = lane + 64 * j;
            float cv = cs[h];
            a0 += cv * gam[0][h];
            a1 += cv * gam[1][h];
            a2 += cv * gam[2][h];
            a3 += cv * gam[3][h];
        }
#pragma unroll
        for (int off = 32; off >= 1; off >>= 1) {
            a0 += __shfl_xor(a0, off);
            a1 += __shfl_xor(a1, off);
            a2 += __shfl_xor(a2, off);
            a3 += __shfl_xor(a3, off);
        }
        if (lane == 0) {
            wsm[0][s] = a0; wsm[1][s] = a1; wsm[2][s] = a2; wsm[3][s] = a3;
        }
    }
    __syncthreads();

    if (wave < 4) {
        int l = wave;
        float v0 = wsm[l][lane], v1 = wsm[l][lane + 64];
        float v2 = wsm[l][lane + 128], v3 = wsm[l][lane + 192];
        float m = fmaxf(fmaxf(v0, v1), fmaxf(v2, v3));
#pragma unroll
        for (int off = 32; off >= 1; off >>= 1) m = fmaxf(m, __shfl_xor(m, off));
        float e0 = expf(v0 - m), e1 = expf(v1 - m), e2 = expf(v2 - m), e3 = expf(v3 - m);
        float sum = e0 + e1 + e2 + e3;
#pragma unroll
        for (int off = 32; off >= 1; off >>= 1) sum += __shfl_xor(sum, off);
        float inv = 1.f / sum;
        wsm[l][lane] = e0 * inv;
        wsm[l][lane + 64] = e1 * inv;
        wsm[l][lane + 128] = e2 * inv;
        wsm[l][lane + 192] = e3 * inv;
    }
    __syncthreads();

    // ct: each thread one float2 of H for all 4 levels
    float2 acc[L4];
#pragma unroll
    for (int l = 0; l < L4; ++l) acc[l] = make_float2(0.f, 0.f);
    const float2* ctx2 = (const float2*)ctxb;
    for (int s = 0; s < SRC; ++s) {
        float2 cv = ctx2[(size_t)s * (H / 2) + tid];
        float w0 = wsm[0][s], w1 = wsm[1][s], w2 = wsm[2][s], w3 = wsm[3][s];
        acc[0].x += w0 * cv.x; acc[0].y += w0 * cv.y;
        acc[1].x += w1 * cv.x; acc[1].y += w1 * cv.y;
        acc[2].x += w2 * cv.x; acc[2].y += w2 * cv.y;
        acc[3].x += w3 * cv.x; acc[3].y += w3 * cv.y;
    }
#pragma unroll
    for (int l = 0; l < L4; ++l) {
        uint_t hx, lx, hy, ly;
        split1(acc[l].x, hx, lx);
        split1(acc[l].y, hy, ly);
        size_t base = (size_t)(l * B + b) * H + tid * 2;
        *(uint_t*)(cthi + base) = hx | (hy << 16);
        *(uint_t*)(ctlo + base) = lx | (ly << 16);
    }
}

// ---------------------------------------------------------------------------
extern "C" void kernel_launch(void* const* d_in, const int* in_sizes, int n_in,
                              void* d_out, int out_size, void* d_ws, size_t ws_size,
                              hipStream_t stream) {
    const int*   inputs     = (const int*)d_in[0];
    const int*   input_lens = (const int*)d_in[1];
    const float* contexts   = (const float*)d_in[2];
    const float* emb_W      = (const float*)d_in[3];
    const float* W_ih0      = (const float*)d_in[4];
    const float* W_hh0      = (const float*)d_in[5];
    const float* b_ih0      = (const float*)d_in[6];
    const float* b_hh0      = (const float*)d_in[7];
    const float* W_ih1      = (const float*)d_in[8];
    const float* W_hh1      = (const float*)d_in[9];
    const float* b_ih1      = (const float*)d_in[10];
    const float* b_hh1      = (const float*)d_in[11];
    const float* att_in_W   = (const float*)d_in[12];
    const float* att_in_b   = (const float*)d_in[13];
    const float* att_out_W  = (const float*)d_in[14];
    const float* att_out_b  = (const float*)d_in[15];
    const float* isl_in_W   = (const float*)d_in[16];
    const float* isl_in_b   = (const float*)d_in[17];
    const float* isl_out_W  = (const float*)d_in[18];
    const float* isl_out_b  = (const float*)d_in[19];

    float* out = (float*)d_out;

    // workspace carve (256B-aligned)
    char* p = (char*)d_ws;
    auto alloc = [&](size_t bytes) { char* r = p; p += (bytes + 255) & ~(size_t)255; return r; };
    ushort_t* xs_hi = (ushort_t*)alloc((size_t)T * R * E * 2);
    ushort_t* xs_lo = (ushort_t*)alloc((size_t)T * R * E * 2);
    ushort_t* h0hi[2], *h0lo[2], *h1hi[2], *h1lo[2];
    for (int i = 0; i < 2; ++i) {
        h0hi[i] = (ushort_t*)alloc((size_t)R * H * 2);
        h0lo[i] = (ushort_t*)alloc((size_t)R * H * 2);
        h1hi[i] = (ushort_t*)alloc((size_t)R * H * 2);
        h1lo[i] = (ushort_t*)alloc((size_t)R * H * 2);
    }
    ushort_t* cthi  = (ushort_t*)alloc((size_t)R * H * 2);
    ushort_t* ctlo  = (ushort_t*)alloc((size_t)R * H * 2);
    ushort_t* pehi  = (ushort_t*)alloc((size_t)R * E * 2);
    ushort_t* pelo  = (ushort_t*)alloc((size_t)R * E * 2);
    ushort_t* cmhi  = (ushort_t*)alloc((size_t)B * H * 2);
    ushort_t* cmlo  = (ushort_t*)alloc((size_t)B * H * 2);
    float* h0f = (float*)alloc((size_t)R * H * 4);
    float* h1f = (float*)alloc((size_t)R * H * 4);
    float* c0f = (float*)alloc((size_t)R * H * 4);
    float* c1f = (float*)alloc((size_t)R * H * 4);
    float* gam = (float*)alloc((size_t)R * H * 4);

    // ---- setup ----
    k_embed<<<L4 * T * B, 128, 0, stream>>>(inputs, emb_W, xs_hi, xs_lo);
    k_pe<<<R, 128, 0, stream>>>(inputs, input_lens, emb_W, pehi, pelo);
    k_cm<<<B, 256, 0, stream>>>(contexts, cmhi, cmlo);

    // h0 = tanh([pe|cm] @ isl_in_W^T + b); c0 = tanh([cm|pe] @ isl_out_W^T + b)
    k_fgemm<<<dim3(16, 4), 512, 0, stream>>>(pehi, pelo, 512, cmhi, cmlo, 1024,
                                             isl_in_W, 1536, isl_in_W + 512, 1536,
                                             isl_in_b, nullptr, 0, 64, 0,
                                             h0f, 64LL * H, (long long)H, 1,
                                             nullptr, nullptr, nullptr, nullptr);
    k_fgemm<<<dim3(16, 4), 512, 0, stream>>>(pehi, pelo, 512, cmhi, cmlo, 1024,
                                             isl_out_W + 1024, 1536, isl_out_W, 1536,
                                             isl_out_b, nullptr, 0, 64, 0,
                                             c0f, 64LL * H, (long long)H, 1,
                                             nullptr, nullptr, nullptr, nullptr);
    k_init_split<<<R * H / 256, 256, 0, stream>>>(h0f, c0f, h1f, c1f,
                                                  h0hi[0], h0lo[0], h1hi[0], h1lo[0]);

    // ---- recurrent loop ----
    int cur = 0;
    for (int t = 0; t < T; ++t) {
        int nxt = cur ^ 1;
        const ushort_t* xh = xs_hi + (size_t)t * R * E;
        const ushort_t* xl = xs_lo + (size_t)t * R * E;
        // layer0 gates + LSTM: reads h0[cur], writes h0[nxt]
        k_fgemm<<<dim3(64, 4), 512, 0, stream>>>(xh, xl, 512,
                                                 h0hi[cur], h0lo[cur], 1024,
                                                 W_ih0, 512, W_hh0, 1024,
                                                 b_ih0, b_hh0, 1, 0, 1,
                                                 nullptr, 0, 0, 0,
                                                 c0f, h0f, h0hi[nxt], h0lo[nxt]);
        // layer1 gates + LSTM: reads h0[nxt], h1[cur]; writes h1[nxt]
        k_fgemm<<<dim3(64, 4), 512, 0, stream>>>(h0hi[nxt], h0lo[nxt], 1024,
                                                 h1hi[cur], h1lo[cur], 1024,
                                                 W_ih1, 1024, W_hh1, 1024,
                                                 b_ih1, b_hh1, 1, 0, 1,
                                                 nullptr, 0, 0, 0,
                                                 c1f, h1f, h1hi[nxt], h1lo[nxt]);
        // gamma = h2 @ att_in_W^T + b
        k_fgemm<<<dim3(16, 4), 512, 0, stream>>>(h1hi[nxt], h1lo[nxt], 1024,
                                                 nullptr, nullptr, 0,
                                                 att_in_W, 1024, nullptr, 0,
                                                 att_in_b, nullptr, 0, 0, 0,
                                                 gam, 64LL * H, (long long)H, 0,
                                                 nullptr, nullptr, nullptr, nullptr);
        // attention
        k_attn<<<B, 512, 0, stream>>>(contexts, gam, cthi, ctlo);
        // out = tanh([ct | h2] @ att_out_W^T + b) scattered into outs[l,t,b,:]
        k_fgemm<<<dim3(16, 4), 512, 0, stream>>>(cthi, ctlo, 1024,
                                                 h1hi[nxt], h1lo[nxt], 1024,
                                                 att_out_W, 2048, att_out_W + 1024, 2048,
                                                 att_out_b, nullptr, 0, 0, 0,
                                                 out + (size_t)t * B * H,
                                                 (long long)T * B * H, (long long)H, 1,
                                                 nullptr, nullptr, nullptr, nullptr);
        cur = nxt;
    }

    // ---- finals ----
    size_t OUTS = (size_t)L4 * T * B * H;
    size_t seg = (size_t)B * H;
    hipMemcpyAsync(out + OUTS,           h0f + 192 * H, seg * 4, hipMemcpyDeviceToDevice, stream);
    hipMemcpyAsync(out + OUTS + seg,     h1f + 192 * H, seg * 4, hipMemcpyDeviceToDevice, stream);
    hipMemcpyAsync(out + OUTS + 2 * seg, c0f + 192 * H, seg * 4, hipMemcpyDeviceToDevice, stream);
    hipMemcpyAsync(out + OUTS + 3 * seg, c1f + 192 * H, seg * 4, hipMemcpyDeviceToDevice, stream);
}

// Round 5
// 3773.395 us; speedup vs baseline: 4.5787x; 1.0956x over previous
//
#include <hip/hip_runtime.h>
#include <math.h>

#define E 512
#define H 1024
#define B 64
#define S 32
#define SRC 256
#define L4 4      // NLEV-1 levels actually processed
#define T 31      // S-1 timesteps
#define R 256     // L4*B rows (effective batch)

typedef unsigned int uint_t;
typedef unsigned short ushort_t;
typedef float f32x4_v __attribute__((ext_vector_type(4)));
typedef short bf16x8_v __attribute__((ext_vector_type(8)));

// ---------------------------------------------------------------------------
// split f32 -> bf16 hi (truncate) + bf16 lo (truncated remainder)
__device__ __forceinline__ void split1(float x, uint_t& h, uint_t& l) {
    uint_t u = __float_as_uint(x);
    h = u >> 16;
    float hf = __uint_as_float(u & 0xFFFF0000u);
    l = __float_as_uint(x - hf) >> 16;
}

__device__ __forceinline__ void split_quad(float4 v, uint2& hi, uint2& lo) {
    uint_t h0, h1, h2, h3, l0, l1, l2, l3;
    split1(v.x, h0, l0); split1(v.y, h1, l1);
    split1(v.z, h2, l2); split1(v.w, h3, l3);
    hi.x = h0 | (h1 << 16); hi.y = h2 | (h3 << 16);
    lo.x = l0 | (l1 << 16); lo.y = l2 | (l3 << 16);
}

__device__ __forceinline__ void gl_lds16(const void* g, void* l) {
    __builtin_amdgcn_global_load_lds(
        (const __attribute__((address_space(1))) void*)g,
        (__attribute__((address_space(3))) void*)l, 16, 0, 0);
}

// ---------------------------------------------------------------------------
// Embeddings -> bf16 hi/lo planes: xs[t*R + l*B+b][e]
__global__ __launch_bounds__(128) void k_embed(const int* __restrict__ inputs,
                                               const float* __restrict__ embW,
                                               ushort_t* __restrict__ xhi,
                                               ushort_t* __restrict__ xlo) {
    int blk = blockIdx.x;              // l*T*B + t*B + b
    int b = blk % B;
    int t = (blk / B) % T;
    int l = blk / (B * T);
    int tok = inputs[(l + 1) * B * S + b * S + t];
    const float4* src = (const float4*)(embW + (long long)tok * E);
    float4 v = src[threadIdx.x];
    uint2 hi, lo; split_quad(v, hi, lo);
    size_t base = ((size_t)t * R + (size_t)l * B + b) * E + threadIdx.x * 4;
    *(uint2*)(xhi + base) = hi;
    *(uint2*)(xlo + base) = lo;
}

// ---------------------------------------------------------------------------
// pe mean -> bf16 hi/lo planes
__global__ __launch_bounds__(128) void k_pe(const int* __restrict__ inputs,
                                            const int* __restrict__ lens,
                                            const float* __restrict__ embW,
                                            ushort_t* __restrict__ phi,
                                            ushort_t* __restrict__ plo) {
    int r = blockIdx.x;
    int l = r >> 6, b = r & 63;
    int plen = lens[l * B + b];
    int send = plen - 1;
    if (send > S) send = S;
    const int* toks = inputs + l * B * S + b * S;
    float4 acc = {0.f, 0.f, 0.f, 0.f};
    for (int s = 1; s < send; ++s) {
        int tok = toks[s];
        float4 v = ((const float4*)(embW + (long long)tok * E))[threadIdx.x];
        acc.x += v.x; acc.y += v.y; acc.z += v.z; acc.w += v.w;
    }
    const float inv = 1.f / 32.f;
    acc.x *= inv; acc.y *= inv; acc.z *= inv; acc.w *= inv;
    uint2 hi, lo; split_quad(acc, hi, lo);
    size_t base = (size_t)r * E + threadIdx.x * 4;
    *(uint2*)(phi + base) = hi;
    *(uint2*)(plo + base) = lo;
}

// ---------------------------------------------------------------------------
// cm mean -> bf16 hi/lo planes
__global__ __launch_bounds__(256) void k_cm(const float* __restrict__ ctx,
                                            ushort_t* __restrict__ chi,
                                            ushort_t* __restrict__ clo) {
    int b = blockIdx.x;
    int j = threadIdx.x;
    const float4* c4 = (const float4*)(ctx + (size_t)b * SRC * H);
    float4 acc = {0.f, 0.f, 0.f, 0.f};
    for (int s = 0; s < SRC; ++s) {
        float4 v = c4[(size_t)s * (H / 4) + j];
        acc.x += v.x; acc.y += v.y; acc.z += v.z; acc.w += v.w;
    }
    const float inv = 1.f / (float)SRC;
    acc.x *= inv; acc.y *= inv; acc.z *= inv; acc.w *= inv;
    uint2 hi, lo; split_quad(acc, hi, lo);
    size_t base = (size_t)b * H + j * 4;
    *(uint2*)(chi + base) = hi;
    *(uint2*)(clo + base) = lo;
}

// ---------------------------------------------------------------------------
// One-time weight preprocessing: concat two K-slices per row, optional
// gate-interleave (rowmap=1: dst row n' takes src row (n'&3)*H + (n'>>2)),
// split f32 -> bf16 hi/lo planes. dst row-major, ld = Ka+Kb.
__global__ __launch_bounds__(256) void k_wsplit(
    const float* __restrict__ src1, int ld1, int o1, int Ka,
    const float* __restrict__ src2, int ld2, int o2, int Kb,
    int rowmap, ushort_t* __restrict__ dhi, ushort_t* __restrict__ dlo) {
    int n = blockIdx.x;
    int KT = Ka + Kb;
    long long r = rowmap ? ((long long)(n & 3) * H + (n >> 2)) : (long long)n;
    for (int k4 = threadIdx.x; k4 < (KT >> 2); k4 += 256) {
        int k = k4 << 2;
        float4 v = (k < Ka) ? *(const float4*)(src1 + r * ld1 + o1 + k)
                            : *(const float4*)(src2 + r * ld2 + o2 + (k - Ka));
        uint2 hi, lo; split_quad(v, hi, lo);
        size_t base = (size_t)n * KT + k;
        *(uint2*)(dhi + base) = hi;
        *(uint2*)(dlo + base) = lo;
    }
}

// ---------------------------------------------------------------------------
// Fully-async split-bf16 MFMA GEMM. 512 threads = 2 k-split groups x 4 waves.
// A = concat([A1(K1) | A2(K2)]) pre-split bf16 hi/lo planes.
// B = pre-split plane pair, row n' = blockIdx.x*64 + j, ld = K1+K2 (concat).
// Both staged via global_load_lds w=16 with both-sides XOR swizzle (rule 21),
// double-buffered; counted s_waitcnt vmcnt(8) (never 0 mid-loop) + raw
// s_barrier so next-tile loads stay in flight across the barrier (T3/T4).
// mode 0: C = act(g + bias1), rows scattered by strideL/strideB.
// mode 1: fused LSTM pointwise (cols gate-interleaved: n' = nh*4+q).
__global__ __launch_bounds__(512) void k_g2(
    const ushort_t* __restrict__ Ah1, const ushort_t* __restrict__ Al1, int K1,
    const ushort_t* __restrict__ Ah2, const ushort_t* __restrict__ Al2, int K2,
    int a2mod,
    const ushort_t* __restrict__ Bh, const ushort_t* __restrict__ Bl,
    const float* __restrict__ bias1, const float* __restrict__ bias2,
    int mode, float* __restrict__ C, long long strideL, long long strideB, int act,
    float* __restrict__ cbuf, float* __restrict__ hf,
    ushort_t* __restrict__ hhi, ushort_t* __restrict__ hlo) {
    // per group (64KB): A[2][16KB] @ 0, B[2][16KB] @ 32KB. group1 region doubles
    // as the f32 reduction tile after the K-loop.
    __shared__ __align__(16) unsigned char lds[131072];
    const int tid = threadIdx.x;
    const int gi = tid >> 8;           // k-split group 0/1
    const int lane = tid & 63;
    const int gwv = (tid >> 6) & 3;    // wave within group
    const int wm = gwv & 1, wn = gwv >> 1;
    const int m0 = blockIdx.y * 64;
    const int colbase = blockIdx.x * 64;
    const int KT = K1 + K2;
    const int NTg = KT >> 7;           // tiles per group
    const int n1steps = K1 >> 6;
    unsigned char* Gbase = lds + (gi << 16);

    f32x4_v zero = {0.f, 0.f, 0.f, 0.f};
    f32x4_v acc[2][2] = {{zero, zero}, {zero, zero}};

    const int xorc = ((lane & 7) * 16) ^ ((lane >> 3) << 4);
    const int rsub = lane >> 3;

    auto stage = [&](int t, int buf) {
        unsigned char* dstA = Gbase + buf * 16384;
        unsigned char* dstB = Gbase + 32768 + buf * 16384;
        // A tile (hi+lo, 16KB)
        {
            const ushort_t *Ph, *Pl; int lda, k0, mod;
            if (t < n1steps) { Ph = Ah1; Pl = Al1; lda = K1; k0 = t << 6; mod = 0; }
            else { Ph = Ah2; Pl = Al2; lda = K2; k0 = (t - n1steps) << 6; mod = a2mod; }
#pragma unroll
            for (int cc = 0; cc < 4; ++cc) {
                int c = gwv * 4 + cc;          // 16 chunks of 1KB
                int p = c >> 3, s = c & 7;
                int rr = m0 + 8 * s + rsub;
                if (mod) rr &= (mod - 1);
                const ushort_t* plane = p ? Pl : Ph;
                gl_lds16((const unsigned char*)(plane + (size_t)rr * lda + k0) + xorc,
                         dstA + p * 8192 + s * 1024);
            }
        }
        // B tile (hi+lo, 16KB) — concat K, single row stride KT
        {
            int k0 = t << 6;
#pragma unroll
            for (int cc = 0; cc < 4; ++cc) {
                int c = gwv * 4 + cc;
                int p = c >> 3, s = c & 7;
                int rr = colbase + 8 * s + rsub;
                const ushort_t* plane = p ? Bl : Bh;
                gl_lds16((const unsigned char*)(plane + (size_t)rr * KT + k0) + xorc,
                         dstB + p * 8192 + s * 1024);
            }
        }
    };
    auto compute = [&](int buf) {
        const unsigned char* Ab = Gbase + buf * 16384;
        const unsigned char* Bb = Gbase + 32768 + buf * 16384;
#pragma unroll
        for (int kf = 0; kf < 2; ++kf) {
            int colA = (kf * 64 + ((lane >> 4) * 16)) ^ ((lane & 7) << 4);
            bf16x8_v ah[2], al[2], bh[2], bl[2];
#pragma unroll
            for (int i = 0; i < 2; ++i) {
                int rowm = (wm * 2 + i) * 16 + (lane & 15);
                ah[i] = *(const bf16x8_v*)(Ab + rowm * 128 + colA);
                al[i] = *(const bf16x8_v*)(Ab + 8192 + rowm * 128 + colA);
                int rj = (wn * 2 + i) * 16 + (lane & 15);
                bh[i] = *(const bf16x8_v*)(Bb + rj * 128 + colA);
                bl[i] = *(const bf16x8_v*)(Bb + 8192 + rj * 128 + colA);
            }
            __builtin_amdgcn_s_setprio(1);
#pragma unroll
            for (int i = 0; i < 2; ++i)
#pragma unroll
                for (int j = 0; j < 2; ++j) {
                    acc[i][j] = __builtin_amdgcn_mfma_f32_16x16x32_bf16(al[i], bh[j], acc[i][j], 0, 0, 0);
                    acc[i][j] = __builtin_amdgcn_mfma_f32_16x16x32_bf16(ah[i], bl[j], acc[i][j], 0, 0, 0);
                    acc[i][j] = __builtin_amdgcn_mfma_f32_16x16x32_bf16(ah[i], bh[j], acc[i][j], 0, 0, 0);
                }
            __builtin_amdgcn_s_setprio(0);
        }
    };

    // --- pipelined K-loop: counted vmcnt keeps prefetch alive over barriers -
    const int tbase = gi * NTg;
    stage(tbase, 0);
    int cur = 0;
    for (int tt = 0; tt < NTg; ++tt) {
        if (tt + 1 < NTg) {
            stage(tbase + tt + 1, cur ^ 1);                 // 8 loads in flight
            asm volatile("s_waitcnt vmcnt(8)" ::: "memory"); // tile tt landed
        } else {
            asm volatile("s_waitcnt vmcnt(0)" ::: "memory");
        }
        __builtin_amdgcn_s_barrier();
        __builtin_amdgcn_sched_barrier(0);
        compute(cur);
        __builtin_amdgcn_sched_barrier(0);
        __builtin_amdgcn_s_barrier();
        cur ^= 1;
    }

    // --- cross-group reduction + epilogue (gtile in group-1 region) --------
    float* gtile = (float*)(lds + 65536);
    const int l16 = lane & 15, g4 = (lane >> 4) * 4;
    if (gi == 1) {
#pragma unroll
        for (int i = 0; i < 2; ++i)
#pragma unroll
            for (int jj = 0; jj < 2; ++jj)
#pragma unroll
                for (int r = 0; r < 4; ++r)
                    gtile[(wm * 32 + i * 16 + g4 + r) * 68 + wn * 32 + jj * 16 + l16] = acc[i][jj][r];
    }
    __syncthreads();
    if (gi == 0) {
#pragma unroll
        for (int i = 0; i < 2; ++i)
#pragma unroll
            for (int jj = 0; jj < 2; ++jj)
#pragma unroll
                for (int r = 0; r < 4; ++r)
                    acc[i][jj][r] += gtile[(wm * 32 + i * 16 + g4 + r) * 68 + wn * 32 + jj * 16 + l16];
        if (mode == 0) {
#pragma unroll
            for (int i = 0; i < 2; ++i) {
#pragma unroll
                for (int r = 0; r < 4; ++r) {
                    int m = m0 + wm * 32 + i * 16 + g4 + r;
                    long long rowoff = (long long)(m >> 6) * strideL + (long long)(m & 63) * strideB;
#pragma unroll
                    for (int jj = 0; jj < 2; ++jj) {
                        int n = colbase + wn * 32 + jj * 16 + l16;
                        float v = acc[i][jj][r] + bias1[n];
                        if (bias2) v += bias2[n];
                        if (act) v = tanhf(v);
                        C[rowoff + n] = v;
                    }
                }
            }
        } else {
#pragma unroll
            for (int i = 0; i < 2; ++i)
#pragma unroll
                for (int jj = 0; jj < 2; ++jj)
#pragma unroll
                    for (int r = 0; r < 4; ++r)
                        gtile[(wm * 32 + i * 16 + g4 + r) * 68 + wn * 32 + jj * 16 + l16] = acc[i][jj][r];
        }
    }
    if (mode == 1) {
        __syncthreads();
        // LSTM pointwise on 64 rows x 16 h-cols; col j = hc*4 + q (interleave)
        int m = tid >> 3;
        int hcb = (tid & 7) * 2;
        int nh0 = blockIdx.x * 16;
#pragma unroll
        for (int e = 0; e < 2; ++e) {
            int hc = hcb + e;
            float gv[4];
#pragma unroll
            for (int q = 0; q < 4; ++q) {
                int bidx = q * H + nh0 + hc;
                gv[q] = gtile[m * 68 + hc * 4 + q] + bias1[bidx] + bias2[bidx];
            }
            size_t idx = (size_t)(m0 + m) * H + nh0 + hc;
            float cp = cbuf[idx];
            float si = 1.f / (1.f + __expf(-gv[0]));
            float sf = 1.f / (1.f + __expf(-gv[1]));
            float so = 1.f / (1.f + __expf(-gv[3]));
            float c = sf * cp + si * tanhf(gv[2]);
            float hn = so * tanhf(c);
            cbuf[idx] = c;
            hf[idx] = hn;
            uint_t hu, lu; split1(hn, hu, lu);
            hhi[idx] = (ushort_t)hu;
            hlo[idx] = (ushort_t)lu;
        }
    }
}

// ---------------------------------------------------------------------------
// Init: emit bf16 planes for h0/h1 (set 0) and copy h/c to layer-1 buffers.
__global__ __launch_bounds__(256) void k_init_split(const float* __restrict__ h0f,
                                                    const float* __restrict__ c0f,
                                                    float* __restrict__ h1f,
                                                    float* __restrict__ c1f,
                                                    ushort_t* __restrict__ h0hi,
                                                    ushort_t* __restrict__ h0lo,
                                                    ushort_t* __restrict__ h1hi,
                                                    ushort_t* __restrict__ h1lo) {
    int idx = blockIdx.x * 256 + threadIdx.x;
    float h = h0f[idx], c = c0f[idx];
    h1f[idx] = h; c1f[idx] = c;
    uint_t hu, lu; split1(h, hu, lu);
    h0hi[idx] = (ushort_t)hu; h0lo[idx] = (ushort_t)lu;
    h1hi[idx] = (ushort_t)hu; h1lo[idx] = (ushort_t)lu;
}

// ---------------------------------------------------------------------------
// Attention (512 thr): scores over SRC, softmax, ct; writes ct hi/lo planes.
__global__ __launch_bounds__(512) void k_attn(const float* __restrict__ ctx,
                                              const float* __restrict__ gamma,
                                              ushort_t* __restrict__ cthi,
                                              ushort_t* __restrict__ ctlo) {
    __shared__ float gam[L4][H];
    __shared__ float wsm[L4][SRC];
    const int b = blockIdx.x;
    const int tid = threadIdx.x;
    const int wave = tid >> 6, lane = tid & 63;

    for (int q = tid; q < 1024; q += 512) {
        int l = q >> 8;
        ((float4*)gam[l])[q & 255] =
            ((const float4*)(gamma + (size_t)(l * B + b) * H))[q & 255];
    }
    __syncthreads();

    const float* ctxb = ctx + (size_t)b * SRC * H;
    for (int s8 = 0; s8 < 32; ++s8) {
        int s = wave * 32 + s8;
        const float* cs = ctxb + (size_t)s * H;
        float a0 = 0.f, a1 = 0.f, a2 = 0.f, a3 = 0.f;
#pragma unroll
        for (int j = 0; j < 16; ++j) {
            int h = lane + 64 * j;
            float cv = cs[h];
            a0 += cv * gam[0][h];
            a1 += cv * gam[1][h];
            a2 += cv * gam[2][h];
            a3 += cv * gam[3][h];
        }
#pragma unroll
        for (int off = 32; off >= 1; off >>= 1) {
            a0 += __shfl_xor(a0, off);
            a1 += __shfl_xor(a1, off);
            a2 += __shfl_xor(a2, off);
            a3 += __shfl_xor(a3, off);
        }
        if (lane == 0) {
            wsm[0][s] = a0; wsm[1][s] = a1; wsm[2][s] = a2; wsm[3][s] = a3;
        }
    }
    __syncthreads();

    if (wave < 4) {
        int l = wave;
        float v0 = wsm[l][lane], v1 = wsm[l][lane + 64];
        float v2 = wsm[l][lane + 128], v3 = wsm[l][lane + 192];
        float m = fmaxf(fmaxf(v0, v1), fmaxf(v2, v3));
#pragma unroll
        for (int off = 32; off >= 1; off >>= 1) m = fmaxf(m, __shfl_xor(m, off));
        float e0 = expf(v0 - m), e1 = expf(v1 - m), e2 = expf(v2 - m), e3 = expf(v3 - m);
        float sum = e0 + e1 + e2 + e3;
#pragma unroll
        for (int off = 32; off >= 1; off >>= 1) sum += __shfl_xor(sum, off);
        float inv = 1.f / sum;
        wsm[l][lane] = e0 * inv;
        wsm[l][lane + 64] = e1 * inv;
        wsm[l][lane + 128] = e2 * inv;
        wsm[l][lane + 192] = e3 * inv;
    }
    __syncthreads();

    float2 acc[L4];
#pragma unroll
    for (int l = 0; l < L4; ++l) acc[l] = make_float2(0.f, 0.f);
    const float2* ctx2 = (const float2*)ctxb;
    for (int s = 0; s < SRC; ++s) {
        float2 cv = ctx2[(size_t)s * (H / 2) + tid];
        float w0 = wsm[0][s], w1 = wsm[1][s], w2 = wsm[2][s], w3 = wsm[3][s];
        acc[0].x += w0 * cv.x; acc[0].y += w0 * cv.y;
        acc[1].x += w1 * cv.x; acc[1].y += w1 * cv.y;
        acc[2].x += w2 * cv.x; acc[2].y += w2 * cv.y;
        acc[3].x += w3 * cv.x; acc[3].y += w3 * cv.y;
    }
#pragma unroll
    for (int l = 0; l < L4; ++l) {
        uint_t hx, lx, hy, ly;
        split1(acc[l].x, hx, lx);
        split1(acc[l].y, hy, ly);
        size_t base = (size_t)(l * B + b) * H + tid * 2;
        *(uint_t*)(cthi + base) = hx | (hy << 16);
        *(uint_t*)(ctlo + base) = lx | (ly << 16);
    }
}

// ---------------------------------------------------------------------------
extern "C" void kernel_launch(void* const* d_in, const int* in_sizes, int n_in,
                              void* d_out, int out_size, void* d_ws, size_t ws_size,
                              hipStream_t stream) {
    const int*   inputs     = (const int*)d_in[0];
    const int*   input_lens = (const int*)d_in[1];
    const float* contexts   = (const float*)d_in[2];
    const float* emb_W      = (const float*)d_in[3];
    const float* W_ih0      = (const float*)d_in[4];
    const float* W_hh0      = (const float*)d_in[5];
    const float* b_ih0      = (const float*)d_in[6];
    const float* b_hh0      = (const float*)d_in[7];
    const float* W_ih1      = (const float*)d_in[8];
    const float* W_hh1      = (const float*)d_in[9];
    const float* b_ih1      = (const float*)d_in[10];
    const float* b_hh1      = (const float*)d_in[11];
    const float* att_in_W   = (const float*)d_in[12];
    const float* att_in_b   = (const float*)d_in[13];
    const float* att_out_W  = (const float*)d_in[14];
    const float* att_out_b  = (const float*)d_in[15];
    const float* isl_in_W   = (const float*)d_in[16];
    const float* isl_in_b   = (const float*)d_in[17];
    const float* isl_out_W  = (const float*)d_in[18];
    const float* isl_out_b  = (const float*)d_in[19];

    float* out = (float*)d_out;

    // workspace carve (256B-aligned)
    char* p = (char*)d_ws;
    auto alloc = [&](size_t bytes) { char* r = p; p += (bytes + 255) & ~(size_t)255; return r; };
    ushort_t* xs_hi = (ushort_t*)alloc((size_t)T * R * E * 2);
    ushort_t* xs_lo = (ushort_t*)alloc((size_t)T * R * E * 2);
    ushort_t* h0hi[2], *h0lo[2], *h1hi[2], *h1lo[2];
    for (int i = 0; i < 2; ++i) {
        h0hi[i] = (ushort_t*)alloc((size_t)R * H * 2);
        h0lo[i] = (ushort_t*)alloc((size_t)R * H * 2);
        h1hi[i] = (ushort_t*)alloc((size_t)R * H * 2);
        h1lo[i] = (ushort_t*)alloc((size_t)R * H * 2);
    }
    ushort_t* cthi = (ushort_t*)alloc((size_t)R * H * 2);
    ushort_t* ctlo = (ushort_t*)alloc((size_t)R * H * 2);
    ushort_t* pehi = (ushort_t*)alloc((size_t)R * E * 2);
    ushort_t* pelo = (ushort_t*)alloc((size_t)R * E * 2);
    ushort_t* cmhi = (ushort_t*)alloc((size_t)B * H * 2);
    ushort_t* cmlo = (ushort_t*)alloc((size_t)B * H * 2);
    // pre-split weight planes
    ushort_t* wg0h = (ushort_t*)alloc((size_t)4096 * 1536 * 2);
    ushort_t* wg0l = (ushort_t*)alloc((size_t)4096 * 1536 * 2);
    ushort_t* wg1h = (ushort_t*)alloc((size_t)4096 * 2048 * 2);
    ushort_t* wg1l = (ushort_t*)alloc((size_t)4096 * 2048 * 2);
    ushort_t* wgmh = (ushort_t*)alloc((size_t)1024 * 1024 * 2);
    ushort_t* wgml = (ushort_t*)alloc((size_t)1024 * 1024 * 2);
    ushort_t* woth = (ushort_t*)alloc((size_t)1024 * 2048 * 2);
    ushort_t* wotl = (ushort_t*)alloc((size_t)1024 * 2048 * 2);
    ushort_t* wiih = (ushort_t*)alloc((size_t)1024 * 1536 * 2);
    ushort_t* wiil = (ushort_t*)alloc((size_t)1024 * 1536 * 2);
    ushort_t* wioh = (ushort_t*)alloc((size_t)1024 * 1536 * 2);
    ushort_t* wiol = (ushort_t*)alloc((size_t)1024 * 1536 * 2);
    float* h0f = (float*)alloc((size_t)R * H * 4);
    float* h1f = (float*)alloc((size_t)R * H * 4);
    float* c0f = (float*)alloc((size_t)R * H * 4);
    float* c1f = (float*)alloc((size_t)R * H * 4);
    float* gam = (float*)alloc((size_t)R * H * 4);

    // ---- setup: embeddings, means, weight plane splits ----
    k_embed<<<L4 * T * B, 128, 0, stream>>>(inputs, emb_W, xs_hi, xs_lo);
    k_pe<<<R, 128, 0, stream>>>(inputs, input_lens, emb_W, pehi, pelo);
    k_cm<<<B, 256, 0, stream>>>(contexts, cmhi, cmlo);
    k_wsplit<<<4096, 256, 0, stream>>>(W_ih0, 512, 0, 512, W_hh0, 1024, 0, 1024, 1, wg0h, wg0l);
    k_wsplit<<<4096, 256, 0, stream>>>(W_ih1, 1024, 0, 1024, W_hh1, 1024, 0, 1024, 1, wg1h, wg1l);
    k_wsplit<<<1024, 256, 0, stream>>>(att_in_W, 1024, 0, 1024, nullptr, 0, 0, 0, 0, wgmh, wgml);
    k_wsplit<<<1024, 256, 0, stream>>>(att_out_W, 2048, 0, 2048, nullptr, 0, 0, 0, 0, woth, wotl);
    k_wsplit<<<1024, 256, 0, stream>>>(isl_in_W, 1536, 0, 1536, nullptr, 0, 0, 0, 0, wiih, wiil);
    k_wsplit<<<1024, 256, 0, stream>>>(isl_out_W, 1536, 1024, 512, isl_out_W, 1536, 0, 1024, 0, wioh, wiol);

    // h0 = tanh([pe|cm] @ isl_in'^T + b); c0 = tanh([pe|cm] @ isl_out'^T + b)
    k_g2<<<dim3(16, 4), 512, 0, stream>>>(pehi, pelo, 512, cmhi, cmlo, 1024, 64,
                                          wiih, wiil, isl_in_b, nullptr, 0,
                                          h0f, 64LL * H, (long long)H, 1,
                                          nullptr, nullptr, nullptr, nullptr);
    k_g2<<<dim3(16, 4), 512, 0, stream>>>(pehi, pelo, 512, cmhi, cmlo, 1024, 64,
                                          wioh, wiol, isl_out_b, nullptr, 0,
                                          c0f, 64LL * H, (long long)H, 1,
                                          nullptr, nullptr, nullptr, nullptr);
    k_init_split<<<R * H / 256, 256, 0, stream>>>(h0f, c0f, h1f, c1f,
                                                  h0hi[0], h0lo[0], h1hi[0], h1lo[0]);

    // ---- recurrent loop ----
    int cur = 0;
    for (int t = 0; t < T; ++t) {
        int nxt = cur ^ 1;
        const ushort_t* xh = xs_hi + (size_t)t * R * E;
        const ushort_t* xl = xs_lo + (size_t)t * R * E;
        // layer0 gates + LSTM: reads h0[cur], writes h0[nxt]
        k_g2<<<dim3(64, 4), 512, 0, stream>>>(xh, xl, 512,
                                              h0hi[cur], h0lo[cur], 1024, 0,
                                              wg0h, wg0l, b_ih0, b_hh0, 1,
                                              nullptr, 0, 0, 0,
                                              c0f, h0f, h0hi[nxt], h0lo[nxt]);
        // layer1 gates + LSTM: reads h0[nxt], h1[cur]; writes h1[nxt]
        k_g2<<<dim3(64, 4), 512, 0, stream>>>(h0hi[nxt], h0lo[nxt], 1024,
                                              h1hi[cur], h1lo[cur], 1024, 0,
                                              wg1h, wg1l, b_ih1, b_hh1, 1,
                                              nullptr, 0, 0, 0,
                                              c1f, h1f, h1hi[nxt], h1lo[nxt]);
        // gamma = h2 @ att_in_W^T + b
        k_g2<<<dim3(16, 4), 512, 0, stream>>>(h1hi[nxt], h1lo[nxt], 1024,
                                              nullptr, nullptr, 0, 0,
                                              wgmh, wgml, att_in_b, nullptr, 0,
                                              gam, 64LL * H, (long long)H, 0,
                                              nullptr, nullptr, nullptr, nullptr);
        // attention
        k_attn<<<B, 512, 0, stream>>>(contexts, gam, cthi, ctlo);
        // out = tanh([ct | h2] @ att_out_W^T + b) scattered into outs[l,t,b,:]
        k_g2<<<dim3(16, 4), 512, 0, stream>>>(cthi, ctlo, 1024,
                                              h1hi[nxt], h1lo[nxt], 1024, 0,
                                              woth, wotl, att_out_b, nullptr, 0,
                                              out + (size_t)t * B * H,
                                              (long long)T * B * H, (long long)H, 1,
                                              nullptr, nullptr, nullptr, nullptr);
        cur = nxt;
    }

    // ---- finals ----
    size_t OUTS = (size_t)L4 * T * B * H;
    size_t seg = (size_t)B * H;
    hipMemcpyAsync(out + OUTS,           h0f + 192 * H, seg * 4, hipMemcpyDeviceToDevice, stream);
    hipMemcpyAsync(out + OUTS + seg,     h1f + 192 * H, seg * 4, hipMemcpyDeviceToDevice, stream);
    hipMemcpyAsync(out + OUTS + 2 * seg, c0f + 192 * H, seg * 4, hipMemcpyDeviceToDevice, stream);
    hipMemcpyAsync(out + OUTS + 3 * seg, c1f + 192 * H, seg * 4, hipMemcpyDeviceToDevice, stream);
}

// Round 7
// 3308.101 us; speedup vs baseline: 5.2227x; 1.1407x over previous
//
#include <hip/hip_runtime.h>
#include <math.h>

#define E 512
#define H 1024
#define B 64
#define S 32
#define SRC 256
#define L4 4      // NLEV-1 levels actually processed
#define T 31      // S-1 timesteps
#define R 256     // L4*B rows (effective batch)

typedef unsigned int uint_t;
typedef unsigned short ushort_t;
typedef float f32x4_v __attribute__((ext_vector_type(4)));
typedef short bf16x8_v __attribute__((ext_vector_type(8)));

// ---------------------------------------------------------------------------
// split f32 -> bf16 hi (truncate) + bf16 lo (truncated remainder)
__device__ __forceinline__ void split1(float x, uint_t& h, uint_t& l) {
    uint_t u = __float_as_uint(x);
    h = u >> 16;
    float hf = __uint_as_float(u & 0xFFFF0000u);
    l = __float_as_uint(x - hf) >> 16;
}

__device__ __forceinline__ void split_quad(float4 v, uint2& hi, uint2& lo) {
    uint_t h0, h1, h2, h3, l0, l1, l2, l3;
    split1(v.x, h0, l0); split1(v.y, h1, l1);
    split1(v.z, h2, l2); split1(v.w, h3, l3);
    hi.x = h0 | (h1 << 16); hi.y = h2 | (h3 << 16);
    lo.x = l0 | (l1 << 16); lo.y = l2 | (l3 << 16);
}

__device__ __forceinline__ void gl_lds16(const void* g, void* l) {
    __builtin_amdgcn_global_load_lds(
        (const __attribute__((address_space(1))) void*)g,
        (__attribute__((address_space(3))) void*)l, 16, 0, 0);
}

// ---------------------------------------------------------------------------
// Embeddings -> bf16 hi/lo planes: xs[t*R + l*B+b][e]
__global__ __launch_bounds__(128) void k_embed(const int* __restrict__ inputs,
                                               const float* __restrict__ embW,
                                               ushort_t* __restrict__ xhi,
                                               ushort_t* __restrict__ xlo) {
    int blk = blockIdx.x;              // l*T*B + t*B + b
    int b = blk % B;
    int t = (blk / B) % T;
    int l = blk / (B * T);
    int tok = inputs[(l + 1) * B * S + b * S + t];
    const float4* src = (const float4*)(embW + (long long)tok * E);
    float4 v = src[threadIdx.x];
    uint2 hi, lo; split_quad(v, hi, lo);
    size_t base = ((size_t)t * R + (size_t)l * B + b) * E + threadIdx.x * 4;
    *(uint2*)(xhi + base) = hi;
    *(uint2*)(xlo + base) = lo;
}

// ---------------------------------------------------------------------------
__global__ __launch_bounds__(128) void k_pe(const int* __restrict__ inputs,
                                            const int* __restrict__ lens,
                                            const float* __restrict__ embW,
                                            ushort_t* __restrict__ phi,
                                            ushort_t* __restrict__ plo) {
    int r = blockIdx.x;
    int l = r >> 6, b = r & 63;
    int plen = lens[l * B + b];
    int send = plen - 1;
    if (send > S) send = S;
    const int* toks = inputs + l * B * S + b * S;
    float4 acc = {0.f, 0.f, 0.f, 0.f};
    for (int s = 1; s < send; ++s) {
        int tok = toks[s];
        float4 v = ((const float4*)(embW + (long long)tok * E))[threadIdx.x];
        acc.x += v.x; acc.y += v.y; acc.z += v.z; acc.w += v.w;
    }
    const float inv = 1.f / 32.f;
    acc.x *= inv; acc.y *= inv; acc.z *= inv; acc.w *= inv;
    uint2 hi, lo; split_quad(acc, hi, lo);
    size_t base = (size_t)r * E + threadIdx.x * 4;
    *(uint2*)(phi + base) = hi;
    *(uint2*)(plo + base) = lo;
}

// ---------------------------------------------------------------------------
__global__ __launch_bounds__(256) void k_cm(const float* __restrict__ ctx,
                                            ushort_t* __restrict__ chi,
                                            ushort_t* __restrict__ clo) {
    int b = blockIdx.x;
    int j = threadIdx.x;
    const float4* c4 = (const float4*)(ctx + (size_t)b * SRC * H);
    float4 acc = {0.f, 0.f, 0.f, 0.f};
    for (int s = 0; s < SRC; ++s) {
        float4 v = c4[(size_t)s * (H / 4) + j];
        acc.x += v.x; acc.y += v.y; acc.z += v.z; acc.w += v.w;
    }
    const float inv = 1.f / (float)SRC;
    acc.x *= inv; acc.y *= inv; acc.z *= inv; acc.w *= inv;
    uint2 hi, lo; split_quad(acc, hi, lo);
    size_t base = (size_t)b * H + j * 4;
    *(uint2*)(chi + base) = hi;
    *(uint2*)(clo + base) = lo;
}

// ---------------------------------------------------------------------------
// One-time weight/activations preprocessing: concat two K-slices per row,
// optional gate-interleave (rowmap=1: dst row n' <- src row (n'&3)*H + (n'>>2)),
// split f32 -> bf16 hi/lo planes. dst row-major, ld = Ka+Kb.
__global__ __launch_bounds__(256) void k_wsplit(
    const float* __restrict__ src1, int ld1, int o1, int Ka,
    const float* __restrict__ src2, int ld2, int o2, int Kb,
    int rowmap, ushort_t* __restrict__ dhi, ushort_t* __restrict__ dlo) {
    int n = blockIdx.x;
    int KT = Ka + Kb;
    long long r = rowmap ? ((long long)(n & 3) * H + (n >> 2)) : (long long)n;
    for (int k4 = threadIdx.x; k4 < (KT >> 2); k4 += 256) {
        int k = k4 << 2;
        float4 v = (k < Ka) ? *(const float4*)(src1 + r * ld1 + o1 + k)
                            : *(const float4*)(src2 + r * ld2 + o2 + (k - Ka));
        uint2 hi, lo; split_quad(v, hi, lo);
        size_t base = (size_t)n * KT + k;
        *(uint2*)(dhi + base) = hi;
        *(uint2*)(dlo + base) = lo;
    }
}

// ---------------------------------------------------------------------------
// TRANSPOSING splitter: dst row n, col k = src[k*ld + n] (dst = src^T planes).
// One-time setup op; scalar reads are acceptable.
__global__ __launch_bounds__(256) void k_wsplitT(
    const float* __restrict__ src, int ld, int K,
    ushort_t* __restrict__ dhi, ushort_t* __restrict__ dlo) {
    int n = blockIdx.x;
    for (int k4 = threadIdx.x; k4 < (K >> 2); k4 += 256) {
        int k = k4 << 2;
        float4 v;
        v.x = src[(size_t)(k + 0) * ld + n];
        v.y = src[(size_t)(k + 1) * ld + n];
        v.z = src[(size_t)(k + 2) * ld + n];
        v.w = src[(size_t)(k + 3) * ld + n];
        uint2 hi, lo; split_quad(v, hi, lo);
        size_t base = (size_t)n * K + k;
        *(uint2*)(dhi + base) = hi;
        *(uint2*)(dlo + base) = lo;
    }
}

// ---------------------------------------------------------------------------
// Fully-async split-bf16 MFMA GEMM. 512 threads = 2 k-split groups x 4 waves.
// A = concat([A1(K1) | A2(K2)]) pre-split bf16 hi/lo planes.
// B = pre-split plane pair, row n' = blockIdx.x*64 + j, ld = K1+K2 (concat).
// Both staged via global_load_lds w=16 with both-sides XOR swizzle (rule 21),
// double-buffered; counted s_waitcnt vmcnt(8) + raw s_barrier (T3/T4).
// mode 0: C = act(g + bias1? + bias2?), rows scattered by strideL/strideB.
// mode 1: fused LSTM pointwise (cols gate-interleaved: n' = nh*4+q).
__global__ __launch_bounds__(512) void k_g2(
    const ushort_t* __restrict__ Ah1, const ushort_t* __restrict__ Al1, int K1,
    const ushort_t* __restrict__ Ah2, const ushort_t* __restrict__ Al2, int K2,
    int a2mod,
    const ushort_t* __restrict__ Bh, const ushort_t* __restrict__ Bl,
    const float* __restrict__ bias1, const float* __restrict__ bias2,
    int mode, float* __restrict__ C, long long strideL, long long strideB, int act,
    float* __restrict__ cbuf, float* __restrict__ hf,
    ushort_t* __restrict__ hhi, ushort_t* __restrict__ hlo) {
    __shared__ __align__(16) unsigned char lds[131072];
    const int tid = threadIdx.x;
    const int gi = tid >> 8;           // k-split group 0/1
    const int lane = tid & 63;
    const int gwv = (tid >> 6) & 3;    // wave within group
    const int wm = gwv & 1, wn = gwv >> 1;
    const int m0 = blockIdx.y * 64;
    const int colbase = blockIdx.x * 64;
    const int KT = K1 + K2;
    const int NTg = KT >> 7;           // tiles per group
    const int n1steps = K1 >> 6;
    unsigned char* Gbase = lds + (gi << 16);

    f32x4_v zero = {0.f, 0.f, 0.f, 0.f};
    f32x4_v acc[2][2] = {{zero, zero}, {zero, zero}};

    const int xorc = ((lane & 7) * 16) ^ ((lane >> 3) << 4);
    const int rsub = lane >> 3;

    auto stage = [&](int t, int buf) {
        unsigned char* dstA = Gbase + buf * 16384;
        unsigned char* dstB = Gbase + 32768 + buf * 16384;
        {
            const ushort_t *Ph, *Pl; int lda, k0, mod;
            if (t < n1steps) { Ph = Ah1; Pl = Al1; lda = K1; k0 = t << 6; mod = 0; }
            else { Ph = Ah2; Pl = Al2; lda = K2; k0 = (t - n1steps) << 6; mod = a2mod; }
#pragma unroll
            for (int cc = 0; cc < 4; ++cc) {
                int c = gwv * 4 + cc;
                int p = c >> 3, s = c & 7;
                int rr = m0 + 8 * s + rsub;
                if (mod) rr &= (mod - 1);
                const ushort_t* plane = p ? Pl : Ph;
                gl_lds16((const unsigned char*)(plane + (size_t)rr * lda + k0) + xorc,
                         dstA + p * 8192 + s * 1024);
            }
        }
        {
            int k0 = t << 6;
#pragma unroll
            for (int cc = 0; cc < 4; ++cc) {
                int c = gwv * 4 + cc;
                int p = c >> 3, s = c & 7;
                int rr = colbase + 8 * s + rsub;
                const ushort_t* plane = p ? Bl : Bh;
                gl_lds16((const unsigned char*)(plane + (size_t)rr * KT + k0) + xorc,
                         dstB + p * 8192 + s * 1024);
            }
        }
    };
    auto compute = [&](int buf) {
        const unsigned char* Ab = Gbase + buf * 16384;
        const unsigned char* Bb = Gbase + 32768 + buf * 16384;
#pragma unroll
        for (int kf = 0; kf < 2; ++kf) {
            int colA = (kf * 64 + ((lane >> 4) * 16)) ^ ((lane & 7) << 4);
            bf16x8_v ah[2], al[2], bh[2], bl[2];
#pragma unroll
            for (int i = 0; i < 2; ++i) {
                int rowm = (wm * 2 + i) * 16 + (lane & 15);
                ah[i] = *(const bf16x8_v*)(Ab + rowm * 128 + colA);
                al[i] = *(const bf16x8_v*)(Ab + 8192 + rowm * 128 + colA);
                int rj = (wn * 2 + i) * 16 + (lane & 15);
                bh[i] = *(const bf16x8_v*)(Bb + rj * 128 + colA);
                bl[i] = *(const bf16x8_v*)(Bb + 8192 + rj * 128 + colA);
            }
            __builtin_amdgcn_s_setprio(1);
#pragma unroll
            for (int i = 0; i < 2; ++i)
#pragma unroll
                for (int j = 0; j < 2; ++j) {
                    acc[i][j] = __builtin_amdgcn_mfma_f32_16x16x32_bf16(al[i], bh[j], acc[i][j], 0, 0, 0);
                    acc[i][j] = __builtin_amdgcn_mfma_f32_16x16x32_bf16(ah[i], bl[j], acc[i][j], 0, 0, 0);
                    acc[i][j] = __builtin_amdgcn_mfma_f32_16x16x32_bf16(ah[i], bh[j], acc[i][j], 0, 0, 0);
                }
            __builtin_amdgcn_s_setprio(0);
        }
    };

    const int tbase = gi * NTg;
    stage(tbase, 0);
    int cur = 0;
    for (int tt = 0; tt < NTg; ++tt) {
        if (tt + 1 < NTg) {
            stage(tbase + tt + 1, cur ^ 1);
            asm volatile("s_waitcnt vmcnt(8)" ::: "memory");
        } else {
            asm volatile("s_waitcnt vmcnt(0)" ::: "memory");
        }
        __builtin_amdgcn_s_barrier();
        __builtin_amdgcn_sched_barrier(0);
        compute(cur);
        __builtin_amdgcn_sched_barrier(0);
        __builtin_amdgcn_s_barrier();
        cur ^= 1;
    }

    // --- cross-group reduction + epilogue ---------------------------------
    float* gtile = (float*)(lds + 65536);
    const int l16 = lane & 15, g4 = (lane >> 4) * 4;
    if (gi == 1) {
#pragma unroll
        for (int i = 0; i < 2; ++i)
#pragma unroll
            for (int jj = 0; jj < 2; ++jj)
#pragma unroll
                for (int r = 0; r < 4; ++r)
                    gtile[(wm * 32 + i * 16 + g4 + r) * 68 + wn * 32 + jj * 16 + l16] = acc[i][jj][r];
    }
    __syncthreads();
    if (gi == 0) {
#pragma unroll
        for (int i = 0; i < 2; ++i)
#pragma unroll
            for (int jj = 0; jj < 2; ++jj)
#pragma unroll
                for (int r = 0; r < 4; ++r)
                    acc[i][jj][r] += gtile[(wm * 32 + i * 16 + g4 + r) * 68 + wn * 32 + jj * 16 + l16];
        if (mode == 0) {
#pragma unroll
            for (int i = 0; i < 2; ++i) {
#pragma unroll
                for (int r = 0; r < 4; ++r) {
                    int m = m0 + wm * 32 + i * 16 + g4 + r;
                    long long rowoff = (long long)(m >> 6) * strideL + (long long)(m & 63) * strideB;
#pragma unroll
                    for (int jj = 0; jj < 2; ++jj) {
                        int n = colbase + wn * 32 + jj * 16 + l16;
                        float v = acc[i][jj][r];
                        if (bias1) v += bias1[n];
                        if (bias2) v += bias2[n];
                        if (act) v = tanhf(v);
                        C[rowoff + n] = v;
                    }
                }
            }
        } else {
#pragma unroll
            for (int i = 0; i < 2; ++i)
#pragma unroll
                for (int jj = 0; jj < 2; ++jj)
#pragma unroll
                    for (int r = 0; r < 4; ++r)
                        gtile[(wm * 32 + i * 16 + g4 + r) * 68 + wn * 32 + jj * 16 + l16] = acc[i][jj][r];
        }
    }
    if (mode == 1) {
        __syncthreads();
        int m = tid >> 3;
        int hcb = (tid & 7) * 2;
        int nh0 = blockIdx.x * 16;
#pragma unroll
        for (int e = 0; e < 2; ++e) {
            int hc = hcb + e;
            float gv[4];
#pragma unroll
            for (int q = 0; q < 4; ++q) {
                int bidx = q * H + nh0 + hc;
                gv[q] = gtile[m * 68 + hc * 4 + q] + bias1[bidx] + bias2[bidx];
            }
            size_t idx = (size_t)(m0 + m) * H + nh0 + hc;
            float cp = cbuf[idx];
            float si = 1.f / (1.f + __expf(-gv[0]));
            float sf = 1.f / (1.f + __expf(-gv[1]));
            float so = 1.f / (1.f + __expf(-gv[3]));
            float c = sf * cp + si * tanhf(gv[2]);
            float hn = so * tanhf(c);
            cbuf[idx] = c;
            hf[idx] = hn;
            uint_t hu, lu; split1(hn, hu, lu);
            hhi[idx] = (ushort_t)hu;
            hlo[idx] = (ushort_t)lu;
        }
    }
}

// ---------------------------------------------------------------------------
__global__ __launch_bounds__(256) void k_init_split(const float* __restrict__ h0f,
                                                    const float* __restrict__ c0f,
                                                    float* __restrict__ h1f,
                                                    float* __restrict__ c1f,
                                                    ushort_t* __restrict__ h0hi,
                                                    ushort_t* __restrict__ h0lo,
                                                    ushort_t* __restrict__ h1hi,
                                                    ushort_t* __restrict__ h1lo) {
    int idx = blockIdx.x * 256 + threadIdx.x;
    float h = h0f[idx], c = c0f[idx];
    h1f[idx] = h; c1f[idx] = c;
    uint_t hu, lu; split1(h, hu, lu);
    h0hi[idx] = (ushort_t)hu; h0lo[idx] = (ushort_t)lu;
    h1hi[idx] = (ushort_t)hu; h1lo[idx] = (ushort_t)lu;
}

// ---------------------------------------------------------------------------
// cb[b][s] = dot(ctx[b,s,:], att_in_b)   (once, setup)
__global__ __launch_bounds__(256) void k_cb(const float* __restrict__ ctx,
                                            const float* __restrict__ bvec,
                                            float* __restrict__ cb) {
    int b = blockIdx.x, ch = blockIdx.y;
    int wave = threadIdx.x >> 6, lane = threadIdx.x & 63;
    for (int i = 0; i < 16; ++i) {
        int s = ch * 64 + wave * 16 + i;
        const float* cs = ctx + ((size_t)b * SRC + s) * H;
        float a = 0.f;
#pragma unroll
        for (int j = 0; j < 4; ++j) {
            float4 cv = *(const float4*)(cs + lane * 4 + j * 256);
            float4 bv = *(const float4*)(bvec + lane * 4 + j * 256);
            a += cv.x * bv.x + cv.y * bv.y + cv.z * bv.z + cv.w * bv.w;
        }
#pragma unroll
        for (int off = 32; off >= 1; off >>= 1) a += __shfl_xor(a, off);
        if (lane == 0) cb[b * SRC + s] = a;
    }
}

// ---------------------------------------------------------------------------
// scores[l*B+b][s] = ctxW[b,s,:] . h1[l*B+b,:] + cb[b,s]
// grid (B, 4 s-chunks), 512 thr: wave w handles 8 s-values of its chunk.
__global__ __launch_bounds__(512) void k_score(const float* __restrict__ ctxW,
                                               const float* __restrict__ cb,
                                               const float* __restrict__ h1f,
                                               float* __restrict__ scores) {
    __shared__ float gam[L4][H];
    const int b = blockIdx.x, ch = blockIdx.y;
    const int tid = threadIdx.x;
    const int wave = tid >> 6, lane = tid & 63;

    for (int q = tid; q < 1024; q += 512) {
        int l = q >> 8;
        ((float4*)gam[l])[q & 255] =
            ((const float4*)(h1f + (size_t)(l * B + b) * H))[q & 255];
    }
    __syncthreads();

    for (int i = 0; i < 8; ++i) {
        int s = ch * 64 + wave * 8 + i;
        const float* cs = ctxW + ((size_t)b * SRC + s) * H;
        float a0 = 0.f, a1 = 0.f, a2 = 0.f, a3 = 0.f;
#pragma unroll
        for (int j = 0; j < 4; ++j) {
            float4 cv = *(const float4*)(cs + lane * 4 + j * 256);
            const float* g0 = &gam[0][lane * 4 + j * 256];
            const float* g1 = &gam[1][lane * 4 + j * 256];
            const float* g2 = &gam[2][lane * 4 + j * 256];
            const float* g3 = &gam[3][lane * 4 + j * 256];
            a0 += cv.x * g0[0] + cv.y * g0[1] + cv.z * g0[2] + cv.w * g0[3];
            a1 += cv.x * g1[0] + cv.y * g1[1] + cv.z * g1[2] + cv.w * g1[3];
            a2 += cv.x * g2[0] + cv.y * g2[1] + cv.z * g2[2] + cv.w * g2[3];
            a3 += cv.x * g3[0] + cv.y * g3[1] + cv.z * g3[2] + cv.w * g3[3];
        }
#pragma unroll
        for (int off = 32; off >= 1; off >>= 1) {
            a0 += __shfl_xor(a0, off);
            a1 += __shfl_xor(a1, off);
            a2 += __shfl_xor(a2, off);
            a3 += __shfl_xor(a3, off);
        }
        if (lane == 0) {
            float c = cb[b * SRC + s];
            scores[(size_t)(0 * B + b) * SRC + s] = a0 + c;
            scores[(size_t)(1 * B + b) * SRC + s] = a1 + c;
            scores[(size_t)(2 * B + b) * SRC + s] = a2 + c;
            scores[(size_t)(3 * B + b) * SRC + s] = a3 + c;
        }
    }
}

// ---------------------------------------------------------------------------
// Softmax (redundant per h-chunk, cheap) + ct accumulation over ctx.
// grid (B, 4 h-chunks of 256), 512 thr: thread = (level l = tid>>7, colpair).
// Writes ct bf16 hi/lo planes.
__global__ __launch_bounds__(512) void k_attnred(const float* __restrict__ ctx,
                                                 const float* __restrict__ scores,
                                                 ushort_t* __restrict__ cthi,
                                                 ushort_t* __restrict__ ctlo) {
    __shared__ float wsm[L4][SRC];
    const int b = blockIdx.x, hc = blockIdx.y;
    const int tid = threadIdx.x;
    const int wave = tid >> 6, lane = tid & 63;

    if (wave < 4) {
        int l = wave;
        const float* sr = scores + (size_t)(l * B + b) * SRC;
        float v0 = sr[lane], v1 = sr[lane + 64], v2 = sr[lane + 128], v3 = sr[lane + 192];
        float m = fmaxf(fmaxf(v0, v1), fmaxf(v2, v3));
#pragma unroll
        for (int off = 32; off >= 1; off >>= 1) m = fmaxf(m, __shfl_xor(m, off));
        float e0 = expf(v0 - m), e1 = expf(v1 - m), e2 = expf(v2 - m), e3 = expf(v3 - m);
        float sum = e0 + e1 + e2 + e3;
#pragma unroll
        for (int off = 32; off >= 1; off >>= 1) sum += __shfl_xor(sum, off);
        float inv = 1.f / sum;
        wsm[l][lane] = e0 * inv;
        wsm[l][lane + 64] = e1 * inv;
        wsm[l][lane + 128] = e2 * inv;
        wsm[l][lane + 192] = e3 * inv;
    }
    __syncthreads();

    const int l = tid >> 7;
    const int cp = tid & 127;
    const float* base = ctx + (size_t)b * SRC * H + hc * 256 + cp * 2;
    float ax = 0.f, ay = 0.f;
    for (int s = 0; s < SRC; s += 4) {
        float w0 = wsm[l][s], w1 = wsm[l][s + 1], w2 = wsm[l][s + 2], w3 = wsm[l][s + 3];
        float2 c0 = *(const float2*)(base + (size_t)s * H);
        float2 c1 = *(const float2*)(base + (size_t)(s + 1) * H);
        float2 c2 = *(const float2*)(base + (size_t)(s + 2) * H);
        float2 c3 = *(const float2*)(base + (size_t)(s + 3) * H);
        ax += w0 * c0.x + w1 * c1.x + w2 * c2.x + w3 * c3.x;
        ay += w0 * c0.y + w1 * c1.y + w2 * c2.y + w3 * c3.y;
    }
    uint_t hx, lx, hy, ly;
    split1(ax, hx, lx);
    split1(ay, hy, ly);
    size_t obase = (size_t)(l * B + b) * H + hc * 256 + cp * 2;
    *(uint_t*)(cthi + obase) = hx | (hy << 16);
    *(uint_t*)(ctlo + obase) = lx | (ly << 16);
}

// ---------------------------------------------------------------------------
extern "C" void kernel_launch(void* const* d_in, const int* in_sizes, int n_in,
                              void* d_out, int out_size, void* d_ws, size_t ws_size,
                              hipStream_t stream) {
    const int*   inputs     = (const int*)d_in[0];
    const int*   input_lens = (const int*)d_in[1];
    const float* contexts   = (const float*)d_in[2];
    const float* emb_W      = (const float*)d_in[3];
    const float* W_ih0      = (const float*)d_in[4];
    const float* W_hh0      = (const float*)d_in[5];
    const float* b_ih0      = (const float*)d_in[6];
    const float* b_hh0      = (const float*)d_in[7];
    const float* W_ih1      = (const float*)d_in[8];
    const float* W_hh1      = (const float*)d_in[9];
    const float* b_ih1      = (const float*)d_in[10];
    const float* b_hh1      = (const float*)d_in[11];
    const float* att_in_W   = (const float*)d_in[12];
    const float* att_in_b   = (const float*)d_in[13];
    const float* att_out_W  = (const float*)d_in[14];
    const float* att_out_b  = (const float*)d_in[15];
    const float* isl_in_W   = (const float*)d_in[16];
    const float* isl_in_b   = (const float*)d_in[17];
    const float* isl_out_W  = (const float*)d_in[18];
    const float* isl_out_b  = (const float*)d_in[19];

    float* out = (float*)d_out;

    // workspace carve (256B-aligned)
    char* p = (char*)d_ws;
    auto alloc = [&](size_t bytes) { char* r = p; p += (bytes + 255) & ~(size_t)255; return r; };
    ushort_t* xs_hi = (ushort_t*)alloc((size_t)T * R * E * 2);
    ushort_t* xs_lo = (ushort_t*)alloc((size_t)T * R * E * 2);
    ushort_t* h0hi[2], *h0lo[2], *h1hi[2], *h1lo[2];
    for (int i = 0; i < 2; ++i) {
        h0hi[i] = (ushort_t*)alloc((size_t)R * H * 2);
        h0lo[i] = (ushort_t*)alloc((size_t)R * H * 2);
        h1hi[i] = (ushort_t*)alloc((size_t)R * H * 2);
        h1lo[i] = (ushort_t*)alloc((size_t)R * H * 2);
    }
    ushort_t* cthi = (ushort_t*)alloc((size_t)R * H * 2);
    ushort_t* ctlo = (ushort_t*)alloc((size_t)R * H * 2);
    ushort_t* pehi = (ushort_t*)alloc((size_t)R * E * 2);
    ushort_t* pelo = (ushort_t*)alloc((size_t)R * E * 2);
    ushort_t* cmhi = (ushort_t*)alloc((size_t)B * H * 2);
    ushort_t* cmlo = (ushort_t*)alloc((size_t)B * H * 2);
    // pre-split weight planes
    ushort_t* wg0h = (ushort_t*)alloc((size_t)4096 * 1536 * 2);
    ushort_t* wg0l = (ushort_t*)alloc((size_t)4096 * 1536 * 2);
    ushort_t* wg1h = (ushort_t*)alloc((size_t)4096 * 2048 * 2);
    ushort_t* wg1l = (ushort_t*)alloc((size_t)4096 * 2048 * 2);
    ushort_t* wgTh = (ushort_t*)alloc((size_t)1024 * 1024 * 2);   // att_in_W^T planes
    ushort_t* wgTl = (ushort_t*)alloc((size_t)1024 * 1024 * 2);
    ushort_t* woth = (ushort_t*)alloc((size_t)1024 * 2048 * 2);
    ushort_t* wotl = (ushort_t*)alloc((size_t)1024 * 2048 * 2);
    ushort_t* wiih = (ushort_t*)alloc((size_t)1024 * 1536 * 2);
    ushort_t* wiil = (ushort_t*)alloc((size_t)1024 * 1536 * 2);
    ushort_t* wioh = (ushort_t*)alloc((size_t)1024 * 1536 * 2);
    ushort_t* wiol = (ushort_t*)alloc((size_t)1024 * 1536 * 2);
    // ctx planes (setup only) + ctxW + cb + scores
    ushort_t* cxh = (ushort_t*)alloc((size_t)B * SRC * H * 2);
    ushort_t* cxl = (ushort_t*)alloc((size_t)B * SRC * H * 2);
    float* ctxW   = (float*)alloc((size_t)B * SRC * H * 4);
    float* cbv    = (float*)alloc((size_t)B * SRC * 4);
    float* scores = (float*)alloc((size_t)R * SRC * 4);
    float* h0f = (float*)alloc((size_t)R * H * 4);
    float* h1f = (float*)alloc((size_t)R * H * 4);
    float* c0f = (float*)alloc((size_t)R * H * 4);
    float* c1f = (float*)alloc((size_t)R * H * 4);

    // ---- setup ----
    k_embed<<<L4 * T * B, 128, 0, stream>>>(inputs, emb_W, xs_hi, xs_lo);
    k_pe<<<R, 128, 0, stream>>>(inputs, input_lens, emb_W, pehi, pelo);
    k_cm<<<B, 256, 0, stream>>>(contexts, cmhi, cmlo);
    k_wsplit<<<4096, 256, 0, stream>>>(W_ih0, 512, 0, 512, W_hh0, 1024, 0, 1024, 1, wg0h, wg0l);
    k_wsplit<<<4096, 256, 0, stream>>>(W_ih1, 1024, 0, 1024, W_hh1, 1024, 0, 1024, 1, wg1h, wg1l);
    k_wsplitT<<<1024, 256, 0, stream>>>(att_in_W, 1024, 1024, wgTh, wgTl);   // att_in_W^T
    k_wsplit<<<1024, 256, 0, stream>>>(att_out_W, 2048, 0, 2048, nullptr, 0, 0, 0, 0, woth, wotl);
    k_wsplit<<<1024, 256, 0, stream>>>(isl_in_W, 1536, 0, 1536, nullptr, 0, 0, 0, 0, wiih, wiil);
    k_wsplit<<<1024, 256, 0, stream>>>(isl_out_W, 1536, 1024, 512, isl_out_W, 1536, 0, 1024, 0, wioh, wiol);
    k_wsplit<<<B * SRC, 256, 0, stream>>>(contexts, 1024, 0, 1024, nullptr, 0, 0, 0, 0, cxh, cxl);

    // init projections
    k_g2<<<dim3(16, 4), 512, 0, stream>>>(pehi, pelo, 512, cmhi, cmlo, 1024, 64,
                                          wiih, wiil, isl_in_b, nullptr, 0,
                                          h0f, 64LL * H, (long long)H, 1,
                                          nullptr, nullptr, nullptr, nullptr);
    k_g2<<<dim3(16, 4), 512, 0, stream>>>(pehi, pelo, 512, cmhi, cmlo, 1024, 64,
                                          wioh, wiol, isl_out_b, nullptr, 0,
                                          c0f, 64LL * H, (long long)H, 1,
                                          nullptr, nullptr, nullptr, nullptr);
    k_init_split<<<R * H / 256, 256, 0, stream>>>(h0f, c0f, h1f, c1f,
                                                  h0hi[0], h0lo[0], h1hi[0], h1lo[0]);

    // ctxW = contexts @ att_in_W  (16384 x 1024, K=1024) via W^T planes,
    // plus cb = ctx . att_in_b
    k_g2<<<dim3(16, 256), 512, 0, stream>>>(cxh, cxl, 1024,
                                            nullptr, nullptr, 0, 0,
                                            wgTh, wgTl, nullptr, nullptr, 0,
                                            ctxW, 64LL * H, (long long)H, 0,
                                            nullptr, nullptr, nullptr, nullptr);
    k_cb<<<dim3(B, 4), 256, 0, stream>>>(contexts, att_in_b, cbv);

    // ---- recurrent loop ----
    int cur = 0;
    for (int t = 0; t < T; ++t) {
        int nxt = cur ^ 1;
        const ushort_t* xh = xs_hi + (size_t)t * R * E;
        const ushort_t* xl = xs_lo + (size_t)t * R * E;
        // layer0 gates + LSTM
        k_g2<<<dim3(64, 4), 512, 0, stream>>>(xh, xl, 512,
                                              h0hi[cur], h0lo[cur], 1024, 0,
                                              wg0h, wg0l, b_ih0, b_hh0, 1,
                                              nullptr, 0, 0, 0,
                                              c0f, h0f, h0hi[nxt], h0lo[nxt]);
        // layer1 gates + LSTM
        k_g2<<<dim3(64, 4), 512, 0, stream>>>(h0hi[nxt], h0lo[nxt], 1024,
                                              h1hi[cur], h1lo[cur], 1024, 0,
                                              wg1h, wg1l, b_ih1, b_hh1, 1,
                                              nullptr, 0, 0, 0,
                                              c1f, h1f, h1hi[nxt], h1lo[nxt]);
        // attention scores (gamma folded into precomputed ctxW)
        k_score<<<dim3(B, 4), 512, 0, stream>>>(ctxW, cbv, h1f, scores);
        // softmax + ct accumulation
        k_attnred<<<dim3(B, 4), 512, 0, stream>>>(contexts, scores, cthi, ctlo);
        // out = tanh([ct | h2] @ att_out_W^T + b) scattered into outs[l,t,b,:]
        k_g2<<<dim3(16, 4), 512, 0, stream>>>(cthi, ctlo, 1024,
                                              h1hi[nxt], h1lo[nxt], 1024, 0,
                                              woth, wotl, att_out_b, nullptr, 0,
                                              out + (size_t)t * B * H,
                                              (long long)T * B * H, (long long)H, 1,
                                              nullptr, nullptr, nullptr, nullptr);
        cur = nxt;
    }

    // ---- finals ----
    size_t OUTS = (size_t)L4 * T * B * H;
    size_t seg = (size_t)B * H;
    hipMemcpyAsync(out + OUTS,           h0f + 192 * H, seg * 4, hipMemcpyDeviceToDevice, stream);
    hipMemcpyAsync(out + OUTS + seg,     h1f + 192 * H, seg * 4, hipMemcpyDeviceToDevice, stream);
    hipMemcpyAsync(out + OUTS + 2 * seg, c0f + 192 * H, seg * 4, hipMemcpyDeviceToDevice, stream);
    hipMemcpyAsync(out + OUTS + 3 * seg, c1f + 192 * H, seg * 4, hipMemcpyDeviceToDevice, stream);
}

// Round 8
// 2036.108 us; speedup vs baseline: 8.4855x; 1.6247x over previous
//
#include <hip/hip_runtime.h>
#include <math.h>

#define E 512
#define H 1024
#define B 64
#define S 32
#define SRC 256
#define L4 4      // NLEV-1 levels actually processed
#define T 31      // S-1 timesteps
#define R 256     // L4*B rows (effective batch)

typedef unsigned int uint_t;
typedef unsigned short ushort_t;
typedef float f32x4_v __attribute__((ext_vector_type(4)));
typedef short bf16x8_v __attribute__((ext_vector_type(8)));

// ---------------------------------------------------------------------------
// split f32 -> bf16 hi (truncate) + bf16 lo (truncated remainder)
__device__ __forceinline__ void split1(float x, uint_t& h, uint_t& l) {
    uint_t u = __float_as_uint(x);
    h = u >> 16;
    float hf = __uint_as_float(u & 0xFFFF0000u);
    l = __float_as_uint(x - hf) >> 16;
}

__device__ __forceinline__ void split_quad(float4 v, uint2& hi, uint2& lo) {
    uint_t h0, h1, h2, h3, l0, l1, l2, l3;
    split1(v.x, h0, l0); split1(v.y, h1, l1);
    split1(v.z, h2, l2); split1(v.w, h3, l3);
    hi.x = h0 | (h1 << 16); hi.y = h2 | (h3 << 16);
    lo.x = l0 | (l1 << 16); lo.y = l2 | (l3 << 16);
}

__device__ __forceinline__ void gl_lds16(const void* g, void* l) {
    __builtin_amdgcn_global_load_lds(
        (const __attribute__((address_space(1))) void*)g,
        (__attribute__((address_space(3))) void*)l, 16, 0, 0);
}

// ---------------------------------------------------------------------------
// Embeddings -> bf16 hi/lo planes: xs[t*R + l*B+b][e]
__global__ __launch_bounds__(128) void k_embed(const int* __restrict__ inputs,
                                               const float* __restrict__ embW,
                                               ushort_t* __restrict__ xhi,
                                               ushort_t* __restrict__ xlo) {
    int blk = blockIdx.x;              // l*T*B + t*B + b
    int b = blk % B;
    int t = (blk / B) % T;
    int l = blk / (B * T);
    int tok = inputs[(l + 1) * B * S + b * S + t];
    const float4* src = (const float4*)(embW + (long long)tok * E);
    float4 v = src[threadIdx.x];
    uint2 hi, lo; split_quad(v, hi, lo);
    size_t base = ((size_t)t * R + (size_t)l * B + b) * E + threadIdx.x * 4;
    *(uint2*)(xhi + base) = hi;
    *(uint2*)(xlo + base) = lo;
}

// ---------------------------------------------------------------------------
__global__ __launch_bounds__(128) void k_pe(const int* __restrict__ inputs,
                                            const int* __restrict__ lens,
                                            const float* __restrict__ embW,
                                            ushort_t* __restrict__ phi,
                                            ushort_t* __restrict__ plo) {
    int r = blockIdx.x;
    int l = r >> 6, b = r & 63;
    int plen = lens[l * B + b];
    int send = plen - 1;
    if (send > S) send = S;
    const int* toks = inputs + l * B * S + b * S;
    float4 acc = {0.f, 0.f, 0.f, 0.f};
    for (int s = 1; s < send; ++s) {
        int tok = toks[s];
        float4 v = ((const float4*)(embW + (long long)tok * E))[threadIdx.x];
        acc.x += v.x; acc.y += v.y; acc.z += v.z; acc.w += v.w;
    }
    const float inv = 1.f / 32.f;
    acc.x *= inv; acc.y *= inv; acc.z *= inv; acc.w *= inv;
    uint2 hi, lo; split_quad(acc, hi, lo);
    size_t base = (size_t)r * E + threadIdx.x * 4;
    *(uint2*)(phi + base) = hi;
    *(uint2*)(plo + base) = lo;
}

// ---------------------------------------------------------------------------
__global__ __launch_bounds__(256) void k_cm(const float* __restrict__ ctx,
                                            ushort_t* __restrict__ chi,
                                            ushort_t* __restrict__ clo) {
    int b = blockIdx.x;
    int j = threadIdx.x;
    const float4* c4 = (const float4*)(ctx + (size_t)b * SRC * H);
    float4 acc = {0.f, 0.f, 0.f, 0.f};
    for (int s = 0; s < SRC; ++s) {
        float4 v = c4[(size_t)s * (H / 4) + j];
        acc.x += v.x; acc.y += v.y; acc.z += v.z; acc.w += v.w;
    }
    const float inv = 1.f / (float)SRC;
    acc.x *= inv; acc.y *= inv; acc.z *= inv; acc.w *= inv;
    uint2 hi, lo; split_quad(acc, hi, lo);
    size_t base = (size_t)b * H + j * 4;
    *(uint2*)(chi + base) = hi;
    *(uint2*)(clo + base) = lo;
}

// ---------------------------------------------------------------------------
// One-time preprocessing: concat two K-slices per row, optional gate
// interleave (rowmap=1: dst row n' <- src row (n'&3)*H + (n'>>2)), split
// f32 -> bf16 hi/lo planes. dst row-major, ld = Ka+Kb.
__global__ __launch_bounds__(256) void k_wsplit(
    const float* __restrict__ src1, int ld1, int o1, int Ka,
    const float* __restrict__ src2, int ld2, int o2, int Kb,
    int rowmap, ushort_t* __restrict__ dhi, ushort_t* __restrict__ dlo) {
    int n = blockIdx.x;
    int KT = Ka + Kb;
    long long r = rowmap ? ((long long)(n & 3) * H + (n >> 2)) : (long long)n;
    for (int k4 = threadIdx.x; k4 < (KT >> 2); k4 += 256) {
        int k = k4 << 2;
        float4 v = (k < Ka) ? *(const float4*)(src1 + r * ld1 + o1 + k)
                            : *(const float4*)(src2 + r * ld2 + o2 + (k - Ka));
        uint2 hi, lo; split_quad(v, hi, lo);
        size_t base = (size_t)n * KT + k;
        *(uint2*)(dhi + base) = hi;
        *(uint2*)(dlo + base) = lo;
    }
}

// ---------------------------------------------------------------------------
// TRANSPOSING splitter: dst row n, col k = src[k*ld + n].
__global__ __launch_bounds__(256) void k_wsplitT(
    const float* __restrict__ src, int ld, int K,
    ushort_t* __restrict__ dhi, ushort_t* __restrict__ dlo) {
    int n = blockIdx.x;
    for (int k4 = threadIdx.x; k4 < (K >> 2); k4 += 256) {
        int k = k4 << 2;
        float4 v;
        v.x = src[(size_t)(k + 0) * ld + n];
        v.y = src[(size_t)(k + 1) * ld + n];
        v.z = src[(size_t)(k + 2) * ld + n];
        v.w = src[(size_t)(k + 3) * ld + n];
        uint2 hi, lo; split_quad(v, hi, lo);
        size_t base = (size_t)n * K + k;
        *(uint2*)(dhi + base) = hi;
        *(uint2*)(dlo + base) = lo;
    }
}

// ---------------------------------------------------------------------------
// Split-bf16 MFMA GEMM, 512 thr = 2 k-split groups x 4 waves. Tile 64x64.
// A = concat([A1|A2]) planes; B = plane pair row-major ld=K1+K2.
// Row scatter: rowoff = (m>>8)*strideT + ((m>>6)&3)*strideL + (m&63)*strideB.
// swapxy: 0 -> (x=col, y=m); 1 -> (x=m, y=col)  [XCD L2 locality control]
// mode 0: C=act(g+biases) f32.  mode 1: fused LSTM.  mode 2: bf16 plane out.
__global__ __launch_bounds__(512) void k_g2(
    const ushort_t* __restrict__ Ah1, const ushort_t* __restrict__ Al1, int K1,
    const ushort_t* __restrict__ Ah2, const ushort_t* __restrict__ Al2, int K2,
    int a2mod,
    const ushort_t* __restrict__ Bh, const ushort_t* __restrict__ Bl,
    const float* __restrict__ bias1, const float* __restrict__ bias2,
    int mode, float* __restrict__ C,
    long long strideT, long long strideL, long long strideB, int act, int swapxy,
    float* __restrict__ cbuf, float* __restrict__ hf,
    ushort_t* __restrict__ hhi, ushort_t* __restrict__ hlo) {
    __shared__ __align__(16) unsigned char lds[131072];
    const int tid = threadIdx.x;
    const int gi = tid >> 8;
    const int lane = tid & 63;
    const int gwv = (tid >> 6) & 3;
    const int wm = gwv & 1, wn = gwv >> 1;
    const int cblk = swapxy ? blockIdx.y : blockIdx.x;
    const int mblk = swapxy ? blockIdx.x : blockIdx.y;
    const int m0 = mblk * 64;
    const int colbase = cblk * 64;
    const int KT = K1 + K2;
    const int NTg = KT >> 7;
    const int n1steps = K1 >> 6;
    unsigned char* Gbase = lds + (gi << 16);

    f32x4_v zero = {0.f, 0.f, 0.f, 0.f};
    f32x4_v acc[2][2] = {{zero, zero}, {zero, zero}};

    const int xorc = ((lane & 7) * 16) ^ ((lane >> 3) << 4);
    const int rsub = lane >> 3;

    auto stage = [&](int t, int buf) {
        unsigned char* dstA = Gbase + buf * 16384;
        unsigned char* dstB = Gbase + 32768 + buf * 16384;
        {
            const ushort_t *Ph, *Pl; int lda, k0, mod;
            if (t < n1steps) { Ph = Ah1; Pl = Al1; lda = K1; k0 = t << 6; mod = 0; }
            else { Ph = Ah2; Pl = Al2; lda = K2; k0 = (t - n1steps) << 6; mod = a2mod; }
#pragma unroll
            for (int cc = 0; cc < 4; ++cc) {
                int c = gwv * 4 + cc;
                int p = c >> 3, s = c & 7;
                int rr = m0 + 8 * s + rsub;
                if (mod) rr &= (mod - 1);
                const ushort_t* plane = p ? Pl : Ph;
                gl_lds16((const unsigned char*)(plane + (size_t)rr * lda + k0) + xorc,
                         dstA + p * 8192 + s * 1024);
            }
        }
        {
            int k0 = t << 6;
#pragma unroll
            for (int cc = 0; cc < 4; ++cc) {
                int c = gwv * 4 + cc;
                int p = c >> 3, s = c & 7;
                int rr = colbase + 8 * s + rsub;
                const ushort_t* plane = p ? Bl : Bh;
                gl_lds16((const unsigned char*)(plane + (size_t)rr * KT + k0) + xorc,
                         dstB + p * 8192 + s * 1024);
            }
        }
    };
    auto compute = [&](int buf) {
        const unsigned char* Ab = Gbase + buf * 16384;
        const unsigned char* Bb = Gbase + 32768 + buf * 16384;
#pragma unroll
        for (int kf = 0; kf < 2; ++kf) {
            int colA = (kf * 64 + ((lane >> 4) * 16)) ^ ((lane & 7) << 4);
            bf16x8_v ah[2], al[2], bh[2], bl[2];
#pragma unroll
            for (int i = 0; i < 2; ++i) {
                int rowm = (wm * 2 + i) * 16 + (lane & 15);
                ah[i] = *(const bf16x8_v*)(Ab + rowm * 128 + colA);
                al[i] = *(const bf16x8_v*)(Ab + 8192 + rowm * 128 + colA);
                int rj = (wn * 2 + i) * 16 + (lane & 15);
                bh[i] = *(const bf16x8_v*)(Bb + rj * 128 + colA);
                bl[i] = *(const bf16x8_v*)(Bb + 8192 + rj * 128 + colA);
            }
            __builtin_amdgcn_s_setprio(1);
#pragma unroll
            for (int i = 0; i < 2; ++i)
#pragma unroll
                for (int j = 0; j < 2; ++j) {
                    acc[i][j] = __builtin_amdgcn_mfma_f32_16x16x32_bf16(al[i], bh[j], acc[i][j], 0, 0, 0);
                    acc[i][j] = __builtin_amdgcn_mfma_f32_16x16x32_bf16(ah[i], bl[j], acc[i][j], 0, 0, 0);
                    acc[i][j] = __builtin_amdgcn_mfma_f32_16x16x32_bf16(ah[i], bh[j], acc[i][j], 0, 0, 0);
                }
            __builtin_amdgcn_s_setprio(0);
        }
    };

    const int tbase = gi * NTg;
    stage(tbase, 0);
    int cur = 0;
    for (int tt = 0; tt < NTg; ++tt) {
        if (tt + 1 < NTg) {
            stage(tbase + tt + 1, cur ^ 1);
            asm volatile("s_waitcnt vmcnt(8)" ::: "memory");
        } else {
            asm volatile("s_waitcnt vmcnt(0)" ::: "memory");
        }
        __builtin_amdgcn_s_barrier();
        __builtin_amdgcn_sched_barrier(0);
        compute(cur);
        __builtin_amdgcn_sched_barrier(0);
        __builtin_amdgcn_s_barrier();
        cur ^= 1;
    }

    // --- cross-group reduction + epilogue ---------------------------------
    float* gtile = (float*)(lds + 65536);
    const int l16 = lane & 15, g4 = (lane >> 4) * 4;
    if (gi == 1) {
#pragma unroll
        for (int i = 0; i < 2; ++i)
#pragma unroll
            for (int jj = 0; jj < 2; ++jj)
#pragma unroll
                for (int r = 0; r < 4; ++r)
                    gtile[(wm * 32 + i * 16 + g4 + r) * 68 + wn * 32 + jj * 16 + l16] = acc[i][jj][r];
    }
    __syncthreads();
    if (gi == 0) {
#pragma unroll
        for (int i = 0; i < 2; ++i)
#pragma unroll
            for (int jj = 0; jj < 2; ++jj)
#pragma unroll
                for (int r = 0; r < 4; ++r)
                    acc[i][jj][r] += gtile[(wm * 32 + i * 16 + g4 + r) * 68 + wn * 32 + jj * 16 + l16];
        if (mode == 0 || mode == 2) {
#pragma unroll
            for (int i = 0; i < 2; ++i) {
#pragma unroll
                for (int r = 0; r < 4; ++r) {
                    int m = m0 + wm * 32 + i * 16 + g4 + r;
                    long long rowoff = (long long)(m >> 8) * strideT
                                     + (long long)((m >> 6) & 3) * strideL
                                     + (long long)(m & 63) * strideB;
#pragma unroll
                    for (int jj = 0; jj < 2; ++jj) {
                        int n = colbase + wn * 32 + jj * 16 + l16;
                        float v = acc[i][jj][r];
                        if (mode == 0) {
                            if (bias1) v += bias1[n];
                            if (bias2) v += bias2[n];
                            if (act) v = tanhf(v);
                            C[rowoff + n] = v;
                        } else {
                            uint_t hu, lu; split1(v, hu, lu);
                            hhi[rowoff + n] = (ushort_t)hu;
                            hlo[rowoff + n] = (ushort_t)lu;
                        }
                    }
                }
            }
        } else {
#pragma unroll
            for (int i = 0; i < 2; ++i)
#pragma unroll
                for (int jj = 0; jj < 2; ++jj)
#pragma unroll
                    for (int r = 0; r < 4; ++r)
                        gtile[(wm * 32 + i * 16 + g4 + r) * 68 + wn * 32 + jj * 16 + l16] = acc[i][jj][r];
        }
    }
    if (mode == 1) {
        __syncthreads();
        int m = tid >> 3;
        int hcb = (tid & 7) * 2;
        int nh0 = cblk * 16;
#pragma unroll
        for (int e = 0; e < 2; ++e) {
            int hc = hcb + e;
            float gv[4];
#pragma unroll
            for (int q = 0; q < 4; ++q) {
                int bidx = q * H + nh0 + hc;
                gv[q] = gtile[m * 68 + hc * 4 + q] + bias1[bidx] + bias2[bidx];
            }
            size_t idx = (size_t)(m0 + m) * H + nh0 + hc;
            float cp = cbuf[idx];
            float si = 1.f / (1.f + __expf(-gv[0]));
            float sf = 1.f / (1.f + __expf(-gv[1]));
            float so = 1.f / (1.f + __expf(-gv[3]));
            float c = sf * cp + si * tanhf(gv[2]);
            float hn = so * tanhf(c);
            cbuf[idx] = c;
            hf[idx] = hn;
            uint_t hu, lu; split1(hn, hu, lu);
            hhi[idx] = (ushort_t)hu;
            hlo[idx] = (ushort_t)lu;
        }
    }
}

// ---------------------------------------------------------------------------
// Batched score MFMA: per b, scores[t*R + l*64 + b][s] =
//   split-bf16( h1[t,l,b,:] . ctxW[b,s,:] ). grid (4 colblk, 2 mblk, B).
__global__ __launch_bounds__(512) void k_smfma(
    const ushort_t* __restrict__ h1h, const ushort_t* __restrict__ h1l,
    const ushort_t* __restrict__ cwh, const ushort_t* __restrict__ cwl,
    float* __restrict__ scores) {
    __shared__ __align__(16) unsigned char lds[131072];
    const int tid = threadIdx.x;
    const int gi = tid >> 8;
    const int lane = tid & 63;
    const int gwv = (tid >> 6) & 3;
    const int wm = gwv & 1, wn = gwv >> 1;
    const int b = blockIdx.z;
    const int m0 = blockIdx.y * 64;        // 2 m-blocks (128 rows, 124 valid)
    const int colbase = blockIdx.x * 64;   // 4 col-blocks = s
    const int KT = 1024;
    const int NTg = KT >> 7;               // 8 per group
    unsigned char* Gbase = lds + (gi << 16);

    f32x4_v zero = {0.f, 0.f, 0.f, 0.f};
    f32x4_v acc[2][2] = {{zero, zero}, {zero, zero}};
    const int xorc = ((lane & 7) * 16) ^ ((lane >> 3) << 4);
    const int rsub = lane >> 3;

    auto stage = [&](int t, int buf) {
        unsigned char* dstA = Gbase + buf * 16384;
        unsigned char* dstB = Gbase + 32768 + buf * 16384;
        int k0 = t << 6;
#pragma unroll
        for (int cc = 0; cc < 4; ++cc) {
            int c = gwv * 4 + cc;
            int p = c >> 3, s = c & 7;
            int rr = m0 + 8 * s + rsub;          // 0..127
            int tt = rr >> 2; if (tt > 30) tt = 30;
            size_t row = (size_t)tt * R + (rr & 3) * 64 + b;
            const ushort_t* plane = p ? h1l : h1h;
            gl_lds16((const unsigned char*)(plane + row * H + k0) + xorc,
                     dstA + p * 8192 + s * 1024);
        }
#pragma unroll
        for (int cc = 0; cc < 4; ++cc) {
            int c = gwv * 4 + cc;
            int p = c >> 3, s = c & 7;
            int rr = colbase + 8 * s + rsub;     // s index 0..255
            const ushort_t* plane = p ? cwl : cwh;
            gl_lds16((const unsigned char*)(plane + ((size_t)b * SRC + rr) * H + k0) + xorc,
                     dstB + p * 8192 + s * 1024);
        }
    };
    auto compute = [&](int buf) {
        const unsigned char* Ab = Gbase + buf * 16384;
        const unsigned char* Bb = Gbase + 32768 + buf * 16384;
#pragma unroll
        for (int kf = 0; kf < 2; ++kf) {
            int colA = (kf * 64 + ((lane >> 4) * 16)) ^ ((lane & 7) << 4);
            bf16x8_v ah[2], al[2], bh[2], bl[2];
#pragma unroll
            for (int i = 0; i < 2; ++i) {
                int rowm = (wm * 2 + i) * 16 + (lane & 15);
                ah[i] = *(const bf16x8_v*)(Ab + rowm * 128 + colA);
                al[i] = *(const bf16x8_v*)(Ab + 8192 + rowm * 128 + colA);
                int rj = (wn * 2 + i) * 16 + (lane & 15);
                bh[i] = *(const bf16x8_v*)(Bb + rj * 128 + colA);
                bl[i] = *(const bf16x8_v*)(Bb + 8192 + rj * 128 + colA);
            }
            __builtin_amdgcn_s_setprio(1);
#pragma unroll
            for (int i = 0; i < 2; ++i)
#pragma unroll
                for (int j = 0; j < 2; ++j) {
                    acc[i][j] = __builtin_amdgcn_mfma_f32_16x16x32_bf16(al[i], bh[j], acc[i][j], 0, 0, 0);
                    acc[i][j] = __builtin_amdgcn_mfma_f32_16x16x32_bf16(ah[i], bl[j], acc[i][j], 0, 0, 0);
                    acc[i][j] = __builtin_amdgcn_mfma_f32_16x16x32_bf16(ah[i], bh[j], acc[i][j], 0, 0, 0);
                }
            __builtin_amdgcn_s_setprio(0);
        }
    };

    const int tbase = gi * NTg;
    stage(tbase, 0);
    int cur = 0;
    for (int tt = 0; tt < NTg; ++tt) {
        if (tt + 1 < NTg) {
            stage(tbase + tt + 1, cur ^ 1);
            asm volatile("s_waitcnt vmcnt(8)" ::: "memory");
        } else {
            asm volatile("s_waitcnt vmcnt(0)" ::: "memory");
        }
        __builtin_amdgcn_s_barrier();
        __builtin_amdgcn_sched_barrier(0);
        compute(cur);
        __builtin_amdgcn_sched_barrier(0);
        __builtin_amdgcn_s_barrier();
        cur ^= 1;
    }

    float* gtile = (float*)(lds + 65536);
    const int l16 = lane & 15, g4 = (lane >> 4) * 4;
    if (gi == 1) {
#pragma unroll
        for (int i = 0; i < 2; ++i)
#pragma unroll
            for (int jj = 0; jj < 2; ++jj)
#pragma unroll
                for (int r = 0; r < 4; ++r)
                    gtile[(wm * 32 + i * 16 + g4 + r) * 68 + wn * 32 + jj * 16 + l16] = acc[i][jj][r];
    }
    __syncthreads();
    if (gi == 0) {
#pragma unroll
        for (int i = 0; i < 2; ++i) {
#pragma unroll
            for (int jj = 0; jj < 2; ++jj) {
#pragma unroll
                for (int r = 0; r < 4; ++r) {
                    float v = acc[i][jj][r] +
                        gtile[(wm * 32 + i * 16 + g4 + r) * 68 + wn * 32 + jj * 16 + l16];
                    int m = m0 + wm * 32 + i * 16 + g4 + r;
                    int t = m >> 2;
                    if (t < 31) {
                        size_t row = (size_t)t * R + (m & 3) * 64 + b;
                        int n = colbase + wn * 32 + jj * 16 + l16;
                        scores[row * SRC + n] = v;
                    }
                }
            }
        }
    }
}

// ---------------------------------------------------------------------------
// Softmax over s with cb bias add. grid (T, B), 256 thr (wave = level).
__global__ __launch_bounds__(256) void k_smax(const float* __restrict__ scores,
                                              const float* __restrict__ cb,
                                              float* __restrict__ w) {
    int t = blockIdx.x, b = blockIdx.y;
    int l = threadIdx.x >> 6, lane = threadIdx.x & 63;
    size_t row = (size_t)t * R + l * 64 + b;
    const float* sr = scores + row * SRC;
    const float* cbb = cb + b * SRC;
    float v0 = sr[lane] + cbb[lane];
    float v1 = sr[lane + 64] + cbb[lane + 64];
    float v2 = sr[lane + 128] + cbb[lane + 128];
    float v3 = sr[lane + 192] + cbb[lane + 192];
    float m = fmaxf(fmaxf(v0, v1), fmaxf(v2, v3));
#pragma unroll
    for (int off = 32; off >= 1; off >>= 1) m = fmaxf(m, __shfl_xor(m, off));
    float e0 = expf(v0 - m), e1 = expf(v1 - m), e2 = expf(v2 - m), e3 = expf(v3 - m);
    float sum = e0 + e1 + e2 + e3;
#pragma unroll
    for (int off = 32; off >= 1; off >>= 1) sum += __shfl_xor(sum, off);
    float inv = 1.f / sum;
    float* wr = w + row * SRC;
    wr[lane] = e0 * inv;
    wr[lane + 64] = e1 * inv;
    wr[lane + 128] = e2 * inv;
    wr[lane + 192] = e3 * inv;
}

// ---------------------------------------------------------------------------
// Batched ct: ct[t,l,b,:] = sum_s w[t,l,b,s] * ctx[b,s,:]. grid (B, 4 tchunk),
// 512 thr (thread = h-pair). Writes ct bf16 hi/lo planes.
__global__ __launch_bounds__(512) void k_ct_all(const float* __restrict__ ctx,
                                                const float* __restrict__ w,
                                                ushort_t* __restrict__ cthi,
                                                ushort_t* __restrict__ ctlo) {
    __shared__ float ws[32][260];
    const int b = blockIdx.x, tc = blockIdx.y;
    const int tid = threadIdx.x;
    for (int q = tid; q < 32 * 64; q += 512) {
        int r = q >> 6, c4 = q & 63;
        int t = tc * 8 + (r >> 2);
        float4 v = {0.f, 0.f, 0.f, 0.f};
        if (t < 31)
            v = *(const float4*)(w + ((size_t)t * R + (r & 3) * 64 + b) * SRC + c4 * 4);
        *(float4*)&ws[r][c4 * 4] = v;
    }
    __syncthreads();

    float2 acc[32];
#pragma unroll
    for (int r = 0; r < 32; ++r) acc[r] = make_float2(0.f, 0.f);
    const float2* base = (const float2*)(ctx + (size_t)b * SRC * H) + tid;
    for (int s = 0; s < SRC; s += 4) {
        float2 c0 = base[(size_t)s * (H / 2)];
        float2 c1 = base[(size_t)(s + 1) * (H / 2)];
        float2 c2 = base[(size_t)(s + 2) * (H / 2)];
        float2 c3 = base[(size_t)(s + 3) * (H / 2)];
#pragma unroll
        for (int r = 0; r < 32; ++r) {
            float4 wv = *(const float4*)&ws[r][s];
            acc[r].x += wv.x * c0.x + wv.y * c1.x + wv.z * c2.x + wv.w * c3.x;
            acc[r].y += wv.x * c0.y + wv.y * c1.y + wv.z * c2.y + wv.w * c3.y;
        }
    }
#pragma unroll
    for (int r = 0; r < 32; ++r) {
        int t = tc * 8 + (r >> 2);
        if (t < 31) {
            size_t obase = ((size_t)t * R + (r & 3) * 64 + b) * H + tid * 2;
            uint_t hx, lx, hy, ly;
            split1(acc[r].x, hx, lx);
            split1(acc[r].y, hy, ly);
            *(uint_t*)(cthi + obase) = hx | (hy << 16);
            *(uint_t*)(ctlo + obase) = lx | (ly << 16);
        }
    }
}

// ---------------------------------------------------------------------------
__global__ __launch_bounds__(256) void k_init_split(const float* __restrict__ h0f,
                                                    const float* __restrict__ c0f,
                                                    float* __restrict__ h1f,
                                                    float* __restrict__ c1f,
                                                    ushort_t* __restrict__ h0hi,
                                                    ushort_t* __restrict__ h0lo,
                                                    ushort_t* __restrict__ h1hi,
                                                    ushort_t* __restrict__ h1lo) {
    int idx = blockIdx.x * 256 + threadIdx.x;
    float h = h0f[idx], c = c0f[idx];
    h1f[idx] = h; c1f[idx] = c;
    uint_t hu, lu; split1(h, hu, lu);
    h0hi[idx] = (ushort_t)hu; h0lo[idx] = (ushort_t)lu;
    h1hi[idx] = (ushort_t)hu; h1lo[idx] = (ushort_t)lu;
}

// ---------------------------------------------------------------------------
// cb[b][s] = dot(ctx[b,s,:], att_in_b)
__global__ __launch_bounds__(256) void k_cb(const float* __restrict__ ctx,
                                            const float* __restrict__ bvec,
                                            float* __restrict__ cb) {
    int b = blockIdx.x, ch = blockIdx.y;
    int wave = threadIdx.x >> 6, lane = threadIdx.x & 63;
    for (int i = 0; i < 16; ++i) {
        int s = ch * 64 + wave * 16 + i;
        const float* cs = ctx + ((size_t)b * SRC + s) * H;
        float a = 0.f;
#pragma unroll
        for (int j = 0; j < 4; ++j) {
            float4 cv = *(const float4*)(cs + lane * 4 + j * 256);
            float4 bv = *(const float4*)(bvec + lane * 4 + j * 256);
            a += cv.x * bv.x + cv.y * bv.y + cv.z * bv.z + cv.w * bv.w;
        }
#pragma unroll
        for (int off = 32; off >= 1; off >>= 1) a += __shfl_xor(a, off);
        if (lane == 0) cb[b * SRC + s] = a;
    }
}

// ---------------------------------------------------------------------------
extern "C" void kernel_launch(void* const* d_in, const int* in_sizes, int n_in,
                              void* d_out, int out_size, void* d_ws, size_t ws_size,
                              hipStream_t stream) {
    const int*   inputs     = (const int*)d_in[0];
    const int*   input_lens = (const int*)d_in[1];
    const float* contexts   = (const float*)d_in[2];
    const float* emb_W      = (const float*)d_in[3];
    const float* W_ih0      = (const float*)d_in[4];
    const float* W_hh0      = (const float*)d_in[5];
    const float* b_ih0      = (const float*)d_in[6];
    const float* b_hh0      = (const float*)d_in[7];
    const float* W_ih1      = (const float*)d_in[8];
    const float* W_hh1      = (const float*)d_in[9];
    const float* b_ih1      = (const float*)d_in[10];
    const float* b_hh1      = (const float*)d_in[11];
    const float* att_in_W   = (const float*)d_in[12];
    const float* att_in_b   = (const float*)d_in[13];
    const float* att_out_W  = (const float*)d_in[14];
    const float* att_out_b  = (const float*)d_in[15];
    const float* isl_in_W   = (const float*)d_in[16];
    const float* isl_in_b   = (const float*)d_in[17];
    const float* isl_out_W  = (const float*)d_in[18];
    const float* isl_out_b  = (const float*)d_in[19];

    float* out = (float*)d_out;

    // workspace carve (256B-aligned)
    char* p = (char*)d_ws;
    auto alloc = [&](size_t bytes) { char* r = p; p += (bytes + 255) & ~(size_t)255; return r; };
    ushort_t* xs_hi = (ushort_t*)alloc((size_t)T * R * E * 2);
    ushort_t* xs_lo = (ushort_t*)alloc((size_t)T * R * E * 2);
    ushort_t* h0hi[2], *h0lo[2];
    for (int i = 0; i < 2; ++i) {
        h0hi[i] = (ushort_t*)alloc((size_t)R * H * 2);
        h0lo[i] = (ushort_t*)alloc((size_t)R * H * 2);
    }
    ushort_t* h1ihi = (ushort_t*)alloc((size_t)R * H * 2);   // init h1 planes
    ushort_t* h1ilo = (ushort_t*)alloc((size_t)R * H * 2);
    ushort_t* h1hall = (ushort_t*)alloc((size_t)T * R * H * 2);  // per-t h1 planes
    ushort_t* h1lall = (ushort_t*)alloc((size_t)T * R * H * 2);
    ushort_t* pehi = (ushort_t*)alloc((size_t)R * E * 2);
    ushort_t* pelo = (ushort_t*)alloc((size_t)R * E * 2);
    ushort_t* cmhi = (ushort_t*)alloc((size_t)B * H * 2);
    ushort_t* cmlo = (ushort_t*)alloc((size_t)B * H * 2);
    // pre-split weight planes
    ushort_t* wg0h = (ushort_t*)alloc((size_t)4096 * 1536 * 2);
    ushort_t* wg0l = (ushort_t*)alloc((size_t)4096 * 1536 * 2);
    ushort_t* wg1h = (ushort_t*)alloc((size_t)4096 * 2048 * 2);
    ushort_t* wg1l = (ushort_t*)alloc((size_t)4096 * 2048 * 2);
    ushort_t* wgTh = (ushort_t*)alloc((size_t)1024 * 1024 * 2);
    ushort_t* wgTl = (ushort_t*)alloc((size_t)1024 * 1024 * 2);
    ushort_t* woth = (ushort_t*)alloc((size_t)1024 * 2048 * 2);
    ushort_t* wotl = (ushort_t*)alloc((size_t)1024 * 2048 * 2);
    ushort_t* wiih = (ushort_t*)alloc((size_t)1024 * 1536 * 2);
    ushort_t* wiil = (ushort_t*)alloc((size_t)1024 * 1536 * 2);
    ushort_t* wioh = (ushort_t*)alloc((size_t)1024 * 1536 * 2);
    ushort_t* wiol = (ushort_t*)alloc((size_t)1024 * 1536 * 2);
    // ctx source planes (dead after ctxW GEMM) — region reused for post buffers
    ushort_t* cxh = (ushort_t*)alloc((size_t)B * SRC * H * 2);
    ushort_t* cxl = (ushort_t*)alloc((size_t)B * SRC * H * 2);
    // ctxW bf16 planes
    ushort_t* cwh = (ushort_t*)alloc((size_t)B * SRC * H * 2);
    ushort_t* cwl = (ushort_t*)alloc((size_t)B * SRC * H * 2);
    float* cbv = (float*)alloc((size_t)B * SRC * 4);
    float* h0f = (float*)alloc((size_t)R * H * 4);
    float* h1f = (float*)alloc((size_t)R * H * 4);
    float* c0f = (float*)alloc((size_t)R * H * 4);
    float* c1f = (float*)alloc((size_t)R * H * 4);
    // post buffers aliased into the dead cx region (57MB <= 67MB)
    {
        char* q = (char*)cxh;
        scoresq: ;
    }
    float* scores = (float*)cxh;                                   // 8.1 MB
    float* wbuf   = scores + (size_t)T * R * SRC;                  // 8.1 MB
    ushort_t* cthi = (ushort_t*)(wbuf + (size_t)T * R * SRC);      // 16.3 MB
    ushort_t* ctlo = cthi + (size_t)T * R * H;                     // 16.3 MB

    // ---- setup ----
    k_embed<<<L4 * T * B, 128, 0, stream>>>(inputs, emb_W, xs_hi, xs_lo);
    k_pe<<<R, 128, 0, stream>>>(inputs, input_lens, emb_W, pehi, pelo);
    k_cm<<<B, 256, 0, stream>>>(contexts, cmhi, cmlo);
    k_wsplit<<<4096, 256, 0, stream>>>(W_ih0, 512, 0, 512, W_hh0, 1024, 0, 1024, 1, wg0h, wg0l);
    k_wsplit<<<4096, 256, 0, stream>>>(W_ih1, 1024, 0, 1024, W_hh1, 1024, 0, 1024, 1, wg1h, wg1l);
    k_wsplitT<<<1024, 256, 0, stream>>>(att_in_W, 1024, 1024, wgTh, wgTl);
    k_wsplit<<<1024, 256, 0, stream>>>(att_out_W, 2048, 0, 2048, nullptr, 0, 0, 0, 0, woth, wotl);
    k_wsplit<<<1024, 256, 0, stream>>>(isl_in_W, 1536, 0, 1536, nullptr, 0, 0, 0, 0, wiih, wiil);
    k_wsplit<<<1024, 256, 0, stream>>>(isl_out_W, 1536, 1024, 512, isl_out_W, 1536, 0, 1024, 0, wioh, wiol);
    k_wsplit<<<B * SRC, 256, 0, stream>>>(contexts, 1024, 0, 1024, nullptr, 0, 0, 0, 0, cxh, cxl);

    // init projections
    k_g2<<<dim3(16, 4), 512, 0, stream>>>(pehi, pelo, 512, cmhi, cmlo, 1024, 64,
                                          wiih, wiil, isl_in_b, nullptr, 0,
                                          h0f, 0, 64LL * H, (long long)H, 1, 0,
                                          nullptr, nullptr, nullptr, nullptr);
    k_g2<<<dim3(16, 4), 512, 0, stream>>>(pehi, pelo, 512, cmhi, cmlo, 1024, 64,
                                          wioh, wiol, isl_out_b, nullptr, 0,
                                          c0f, 0, 64LL * H, (long long)H, 1, 0,
                                          nullptr, nullptr, nullptr, nullptr);
    k_init_split<<<R * H / 256, 256, 0, stream>>>(h0f, c0f, h1f, c1f,
                                                  h0hi[0], h0lo[0], h1ihi, h1ilo);

    // ctxW = contexts @ att_in_W -> bf16 planes (mode 2), m-fastest dispatch
    k_g2<<<dim3(256, 16), 512, 0, stream>>>(cxh, cxl, 1024,
                                            nullptr, nullptr, 0, 0,
                                            wgTh, wgTl, nullptr, nullptr, 2,
                                            nullptr, (long long)SRC * H, 64LL * H, (long long)H, 0, 1,
                                            nullptr, nullptr, cwh, cwl);
    k_cb<<<dim3(B, 4), 256, 0, stream>>>(contexts, att_in_b, cbv);

    // ---- recurrence: 2 launches/step ----
    int cur = 0;
    for (int t = 0; t < T; ++t) {
        int nxt = cur ^ 1;
        const ushort_t* xh = xs_hi + (size_t)t * R * E;
        const ushort_t* xl = xs_lo + (size_t)t * R * E;
        const ushort_t* ph1h = t ? h1hall + (size_t)(t - 1) * R * H : h1ihi;
        const ushort_t* ph1l = t ? h1lall + (size_t)(t - 1) * R * H : h1ilo;
        // layer0 gates + LSTM: reads h0[cur], writes h0[nxt]
        k_g2<<<dim3(64, 4), 512, 0, stream>>>(xh, xl, 512,
                                              h0hi[cur], h0lo[cur], 1024, 0,
                                              wg0h, wg0l, b_ih0, b_hh0, 1,
                                              nullptr, 0, 0, 0, 0, 0,
                                              c0f, h0f, h0hi[nxt], h0lo[nxt]);
        // layer1 gates + LSTM: reads h0[nxt], h1(t-1); writes per-t h1 planes
        k_g2<<<dim3(64, 4), 512, 0, stream>>>(h0hi[nxt], h0lo[nxt], 1024,
                                              ph1h, ph1l, 1024, 0,
                                              wg1h, wg1l, b_ih1, b_hh1, 1,
                                              nullptr, 0, 0, 0, 0, 0,
                                              c1f, h1f,
                                              h1hall + (size_t)t * R * H,
                                              h1lall + (size_t)t * R * H);
        cur = nxt;
    }

    // ---- batched attention + output over all t ----
    k_smfma<<<dim3(4, 2, B), 512, 0, stream>>>(h1hall, h1lall, cwh, cwl, scores);
    k_smax<<<dim3(T, B), 256, 0, stream>>>(scores, cbv, wbuf);
    k_ct_all<<<dim3(B, 4), 512, 0, stream>>>(contexts, wbuf, cthi, ctlo);
    // out[t,l,b,:] = tanh([ct|h1] @ att_out_W^T + b), M = 7936 rows
    k_g2<<<dim3(124, 16), 512, 0, stream>>>(cthi, ctlo, 1024,
                                            h1hall, h1lall, 1024, 0,
                                            woth, wotl, att_out_b, nullptr, 0,
                                            out, (long long)B * H,
                                            (long long)T * B * H, (long long)H, 1, 1,
                                            nullptr, nullptr, nullptr, nullptr);

    // ---- finals ----
    size_t OUTS = (size_t)L4 * T * B * H;
    size_t seg = (size_t)B * H;
    hipMemcpyAsync(out + OUTS,           h0f + 192 * H, seg * 4, hipMemcpyDeviceToDevice, stream);
    hipMemcpyAsync(out + OUTS + seg,     h1f + 192 * H, seg * 4, hipMemcpyDeviceToDevice, stream);
    hipMemcpyAsync(out + OUTS + 2 * seg, c0f + 192 * H, seg * 4, hipMemcpyDeviceToDevice, stream);
    hipMemcpyAsync(out + OUTS + 3 * seg, c1f + 192 * H, seg * 4, hipMemcpyDeviceToDevice, stream);
}

// Round 9
// 1681.195 us; speedup vs baseline: 10.2768x; 1.2111x over previous
//
#include <hip/hip_runtime.h>
#include <math.h>

#define E 512
#define H 1024
#define B 64
#define S 32
#define SRC 256
#define L4 4      // NLEV-1 levels actually processed
#define T 31      // S-1 timesteps
#define R 256     // L4*B rows (effective batch)

typedef unsigned int uint_t;
typedef unsigned short ushort_t;
typedef float f32x4_v __attribute__((ext_vector_type(4)));
typedef short bf16x8_v __attribute__((ext_vector_type(8)));

// ---------------------------------------------------------------------------
__device__ __forceinline__ void split1(float x, uint_t& h, uint_t& l) {
    uint_t u = __float_as_uint(x);
    h = u >> 16;
    float hf = __uint_as_float(u & 0xFFFF0000u);
    l = __float_as_uint(x - hf) >> 16;
}

__device__ __forceinline__ void split_quad(float4 v, uint2& hi, uint2& lo) {
    uint_t h0, h1, h2, h3, l0, l1, l2, l3;
    split1(v.x, h0, l0); split1(v.y, h1, l1);
    split1(v.z, h2, l2); split1(v.w, h3, l3);
    hi.x = h0 | (h1 << 16); hi.y = h2 | (h3 << 16);
    lo.x = l0 | (l1 << 16); lo.y = l2 | (l3 << 16);
}

__device__ __forceinline__ void gl_lds16(const void* g, void* l) {
    __builtin_amdgcn_global_load_lds(
        (const __attribute__((address_space(1))) void*)g,
        (__attribute__((address_space(3))) void*)l, 16, 0, 0);
}

// ---------------------------------------------------------------------------
__global__ __launch_bounds__(128) void k_embed(const int* __restrict__ inputs,
                                               const float* __restrict__ embW,
                                               ushort_t* __restrict__ xhi,
                                               ushort_t* __restrict__ xlo) {
    int blk = blockIdx.x;              // l*T*B + t*B + b
    int b = blk % B;
    int t = (blk / B) % T;
    int l = blk / (B * T);
    int tok = inputs[(l + 1) * B * S + b * S + t];
    const float4* src = (const float4*)(embW + (long long)tok * E);
    float4 v = src[threadIdx.x];
    uint2 hi, lo; split_quad(v, hi, lo);
    size_t base = ((size_t)t * R + (size_t)l * B + b) * E + threadIdx.x * 4;
    *(uint2*)(xhi + base) = hi;
    *(uint2*)(xlo + base) = lo;
}

// ---------------------------------------------------------------------------
__global__ __launch_bounds__(128) void k_pe(const int* __restrict__ inputs,
                                            const int* __restrict__ lens,
                                            const float* __restrict__ embW,
                                            ushort_t* __restrict__ phi,
                                            ushort_t* __restrict__ plo) {
    int r = blockIdx.x;
    int l = r >> 6, b = r & 63;
    int plen = lens[l * B + b];
    int send = plen - 1;
    if (send > S) send = S;
    const int* toks = inputs + l * B * S + b * S;
    float4 acc = {0.f, 0.f, 0.f, 0.f};
    for (int s = 1; s < send; ++s) {
        int tok = toks[s];
        float4 v = ((const float4*)(embW + (long long)tok * E))[threadIdx.x];
        acc.x += v.x; acc.y += v.y; acc.z += v.z; acc.w += v.w;
    }
    const float inv = 1.f / 32.f;
    acc.x *= inv; acc.y *= inv; acc.z *= inv; acc.w *= inv;
    uint2 hi, lo; split_quad(acc, hi, lo);
    size_t base = (size_t)r * E + threadIdx.x * 4;
    *(uint2*)(phi + base) = hi;
    *(uint2*)(plo + base) = lo;
}

// ---------------------------------------------------------------------------
__global__ __launch_bounds__(256) void k_cm(const float* __restrict__ ctx,
                                            ushort_t* __restrict__ chi,
                                            ushort_t* __restrict__ clo) {
    int b = blockIdx.x;
    int j = threadIdx.x;
    const float4* c4 = (const float4*)(ctx + (size_t)b * SRC * H);
    float4 acc = {0.f, 0.f, 0.f, 0.f};
    for (int s = 0; s < SRC; ++s) {
        float4 v = c4[(size_t)s * (H / 4) + j];
        acc.x += v.x; acc.y += v.y; acc.z += v.z; acc.w += v.w;
    }
    const float inv = 1.f / (float)SRC;
    acc.x *= inv; acc.y *= inv; acc.z *= inv; acc.w *= inv;
    uint2 hi, lo; split_quad(acc, hi, lo);
    size_t base = (size_t)b * H + j * 4;
    *(uint2*)(chi + base) = hi;
    *(uint2*)(clo + base) = lo;
}

// ---------------------------------------------------------------------------
__global__ __launch_bounds__(256) void k_wsplit(
    const float* __restrict__ src1, int ld1, int o1, int Ka,
    const float* __restrict__ src2, int ld2, int o2, int Kb,
    int rowmap, ushort_t* __restrict__ dhi, ushort_t* __restrict__ dlo) {
    int n = blockIdx.x;
    int KT = Ka + Kb;
    long long r = rowmap ? ((long long)(n & 3) * H + (n >> 2)) : (long long)n;
    for (int k4 = threadIdx.x; k4 < (KT >> 2); k4 += 256) {
        int k = k4 << 2;
        float4 v = (k < Ka) ? *(const float4*)(src1 + r * ld1 + o1 + k)
                            : *(const float4*)(src2 + r * ld2 + o2 + (k - Ka));
        uint2 hi, lo; split_quad(v, hi, lo);
        size_t base = (size_t)n * KT + k;
        *(uint2*)(dhi + base) = hi;
        *(uint2*)(dlo + base) = lo;
    }
}

// ---------------------------------------------------------------------------
__global__ __launch_bounds__(256) void k_wsplitT(
    const float* __restrict__ src, int ld, int K,
    ushort_t* __restrict__ dhi, ushort_t* __restrict__ dlo) {
    int n = blockIdx.x;
    for (int k4 = threadIdx.x; k4 < (K >> 2); k4 += 256) {
        int k = k4 << 2;
        float4 v;
        v.x = src[(size_t)(k + 0) * ld + n];
        v.y = src[(size_t)(k + 1) * ld + n];
        v.z = src[(size_t)(k + 2) * ld + n];
        v.w = src[(size_t)(k + 3) * ld + n];
        uint2 hi, lo; split_quad(v, hi, lo);
        size_t base = (size_t)n * K + k;
        *(uint2*)(dhi + base) = hi;
        *(uint2*)(dlo + base) = lo;
    }
}

// ---------------------------------------------------------------------------
// 256-thr split-bf16 MFMA GEMM (4 waves, tile 64x64, BK=64, A+B dbuf, 64KB
// LDS -> 2 blocks/CU). A = concat([A1|A2]) planes; B planes ld=K1+K2.
// mode 0: C=act(acc+biases) f32, scattered rows; mode 2: bf16 plane out.
__global__ __launch_bounds__(256) void k_g2(
    const ushort_t* __restrict__ Ah1, const ushort_t* __restrict__ Al1, int K1,
    const ushort_t* __restrict__ Ah2, const ushort_t* __restrict__ Al2, int K2,
    int a2mod,
    const ushort_t* __restrict__ Bh, const ushort_t* __restrict__ Bl,
    const float* __restrict__ bias1, const float* __restrict__ bias2,
    int mode, float* __restrict__ C,
    long long strideT, long long strideL, long long strideB, int act, int swapxy,
    ushort_t* __restrict__ ohi, ushort_t* __restrict__ olo) {
    __shared__ __align__(16) unsigned char lds[65536];
    const int tid = threadIdx.x;
    const int lane = tid & 63;
    const int wv = tid >> 6;
    const int wm = wv & 1, wn = wv >> 1;
    const int cblk = swapxy ? blockIdx.y : blockIdx.x;
    const int mblk = swapxy ? blockIdx.x : blockIdx.y;
    const int m0 = mblk * 64;
    const int colbase = cblk * 64;
    const int KT = K1 + K2;
    const int NT = KT >> 6;
    const int n1steps = K1 >> 6;

    f32x4_v zero = {0.f, 0.f, 0.f, 0.f};
    f32x4_v acc[2][2] = {{zero, zero}, {zero, zero}};
    const int xorc = ((lane & 7) * 16) ^ ((lane >> 3) << 4);
    const int rsub = lane >> 3;

    auto stage = [&](int t, int buf) {
        unsigned char* dstA = lds + buf * 16384;
        unsigned char* dstB = lds + 32768 + buf * 16384;
        {
            const ushort_t *Ph, *Pl; int lda, k0, mod;
            if (t < n1steps) { Ph = Ah1; Pl = Al1; lda = K1; k0 = t << 6; mod = 0; }
            else { Ph = Ah2; Pl = Al2; lda = K2; k0 = (t - n1steps) << 6; mod = a2mod; }
#pragma unroll
            for (int cc = 0; cc < 4; ++cc) {
                int c = wv * 4 + cc;
                int p = c >> 3, s = c & 7;
                int rr = m0 + 8 * s + rsub;
                if (mod) rr &= (mod - 1);
                const ushort_t* plane = p ? Pl : Ph;
                gl_lds16((const unsigned char*)(plane + (size_t)rr * lda + k0) + xorc,
                         dstA + p * 8192 + s * 1024);
            }
        }
        {
            int k0 = t << 6;
#pragma unroll
            for (int cc = 0; cc < 4; ++cc) {
                int c = wv * 4 + cc;
                int p = c >> 3, s = c & 7;
                int rr = colbase + 8 * s + rsub;
                const ushort_t* plane = p ? Bl : Bh;
                gl_lds16((const unsigned char*)(plane + (size_t)rr * KT + k0) + xorc,
                         dstB + p * 8192 + s * 1024);
            }
        }
    };
    auto compute = [&](int buf) {
        const unsigned char* Ab = lds + buf * 16384;
        const unsigned char* Bb = lds + 32768 + buf * 16384;
#pragma unroll
        for (int kf = 0; kf < 2; ++kf) {
            int colA = (kf * 64 + ((lane >> 4) * 16)) ^ ((lane & 7) << 4);
            bf16x8_v ah[2], al[2], bh[2], bl[2];
#pragma unroll
            for (int i = 0; i < 2; ++i) {
                int rowm = (wm * 2 + i) * 16 + (lane & 15);
                ah[i] = *(const bf16x8_v*)(Ab + rowm * 128 + colA);
                al[i] = *(const bf16x8_v*)(Ab + 8192 + rowm * 128 + colA);
                int rj = (wn * 2 + i) * 16 + (lane & 15);
                bh[i] = *(const bf16x8_v*)(Bb + rj * 128 + colA);
                bl[i] = *(const bf16x8_v*)(Bb + 8192 + rj * 128 + colA);
            }
            __builtin_amdgcn_s_setprio(1);
#pragma unroll
            for (int i = 0; i < 2; ++i)
#pragma unroll
                for (int j = 0; j < 2; ++j) {
                    acc[i][j] = __builtin_amdgcn_mfma_f32_16x16x32_bf16(al[i], bh[j], acc[i][j], 0, 0, 0);
                    acc[i][j] = __builtin_amdgcn_mfma_f32_16x16x32_bf16(ah[i], bl[j], acc[i][j], 0, 0, 0);
                    acc[i][j] = __builtin_amdgcn_mfma_f32_16x16x32_bf16(ah[i], bh[j], acc[i][j], 0, 0, 0);
                }
            __builtin_amdgcn_s_setprio(0);
        }
    };

    stage(0, 0);
    int cur = 0;
    for (int tt = 0; tt < NT; ++tt) {
        if (tt + 1 < NT) {
            stage(tt + 1, cur ^ 1);
            asm volatile("s_waitcnt vmcnt(8)" ::: "memory");
        } else {
            asm volatile("s_waitcnt vmcnt(0)" ::: "memory");
        }
        __builtin_amdgcn_s_barrier();
        __builtin_amdgcn_sched_barrier(0);
        compute(cur);
        __builtin_amdgcn_sched_barrier(0);
        __builtin_amdgcn_s_barrier();
        cur ^= 1;
    }

    const int l16 = lane & 15, g4 = (lane >> 4) * 4;
#pragma unroll
    for (int i = 0; i < 2; ++i) {
#pragma unroll
        for (int r = 0; r < 4; ++r) {
            int m = m0 + wm * 32 + i * 16 + g4 + r;
            long long rowoff = (long long)(m >> 8) * strideT
                             + (long long)((m >> 6) & 3) * strideL
                             + (long long)(m & 63) * strideB;
#pragma unroll
            for (int jj = 0; jj < 2; ++jj) {
                int n = colbase + wn * 32 + jj * 16 + l16;
                float v = acc[i][jj][r];
                if (mode == 0) {
                    if (bias1) v += bias1[n];
                    if (bias2) v += bias2[n];
                    if (act) v = tanhf(v);
                    C[rowoff + n] = v;
                } else {
                    uint_t hu, lu; split1(v, hu, lu);
                    ohi[rowoff + n] = (ushort_t)hu;
                    olo[rowoff + n] = (ushort_t)lu;
                }
            }
        }
    }
}

// ---------------------------------------------------------------------------
// Dual-job gate GEMM + fused LSTM. grid (64, 4*njobs): y<4 -> j0, y>=4 -> j1.
// Cols gate-interleaved (n' = nh*4+q); 256 thr, 64KB LDS -> 2 blocks/CU.
struct GateJob {
    const ushort_t *Ah1, *Al1, *Ah2, *Al2, *Bh, *Bl;
    const float *bias1, *bias2;
    float *cbuf, *hf;
    ushort_t *hhi, *hlo;
    int K1, K2;
};

__global__ __launch_bounds__(256) void k_gatepair(GateJob j0, GateJob j1) {
    __shared__ __align__(16) unsigned char lds[65536];
    const bool sec = blockIdx.y >= 4;
    const ushort_t* Ah1 = sec ? j1.Ah1 : j0.Ah1;
    const ushort_t* Al1 = sec ? j1.Al1 : j0.Al1;
    const ushort_t* Ah2 = sec ? j1.Ah2 : j0.Ah2;
    const ushort_t* Al2 = sec ? j1.Al2 : j0.Al2;
    const ushort_t* Bh  = sec ? j1.Bh  : j0.Bh;
    const ushort_t* Bl  = sec ? j1.Bl  : j0.Bl;
    const float* bias1  = sec ? j1.bias1 : j0.bias1;
    const float* bias2  = sec ? j1.bias2 : j0.bias2;
    float* cbuf         = sec ? j1.cbuf : j0.cbuf;
    float* hf           = sec ? j1.hf   : j0.hf;
    ushort_t* hhi       = sec ? j1.hhi  : j0.hhi;
    ushort_t* hlo       = sec ? j1.hlo  : j0.hlo;
    const int K1        = sec ? j1.K1   : j0.K1;
    const int K2        = sec ? j1.K2   : j0.K2;

    const int tid = threadIdx.x;
    const int lane = tid & 63;
    const int wv = tid >> 6;
    const int wm = wv & 1, wn = wv >> 1;
    const int mblk = blockIdx.y & 3;
    const int cblk = blockIdx.x;
    const int m0 = mblk * 64;
    const int colbase = cblk * 64;
    const int KT = K1 + K2;
    const int NT = KT >> 6;
    const int n1steps = K1 >> 6;

    f32x4_v zero = {0.f, 0.f, 0.f, 0.f};
    f32x4_v acc[2][2] = {{zero, zero}, {zero, zero}};
    const int xorc = ((lane & 7) * 16) ^ ((lane >> 3) << 4);
    const int rsub = lane >> 3;

    auto stage = [&](int t, int buf) {
        unsigned char* dstA = lds + buf * 16384;
        unsigned char* dstB = lds + 32768 + buf * 16384;
        {
            const ushort_t *Ph, *Pl; int lda, k0;
            if (t < n1steps) { Ph = Ah1; Pl = Al1; lda = K1; k0 = t << 6; }
            else { Ph = Ah2; Pl = Al2; lda = K2; k0 = (t - n1steps) << 6; }
#pragma unroll
            for (int cc = 0; cc < 4; ++cc) {
                int c = wv * 4 + cc;
                int p = c >> 3, s = c & 7;
                int rr = m0 + 8 * s + rsub;
                const ushort_t* plane = p ? Pl : Ph;
                gl_lds16((const unsigned char*)(plane + (size_t)rr * lda + k0) + xorc,
                         dstA + p * 8192 + s * 1024);
            }
        }
        {
            int k0 = t << 6;
#pragma unroll
            for (int cc = 0; cc < 4; ++cc) {
                int c = wv * 4 + cc;
                int p = c >> 3, s = c & 7;
                int rr = colbase + 8 * s + rsub;
                const ushort_t* plane = p ? Bl : Bh;
                gl_lds16((const unsigned char*)(plane + (size_t)rr * KT + k0) + xorc,
                         dstB + p * 8192 + s * 1024);
            }
        }
    };
    auto compute = [&](int buf) {
        const unsigned char* Ab = lds + buf * 16384;
        const unsigned char* Bb = lds + 32768 + buf * 16384;
#pragma unroll
        for (int kf = 0; kf < 2; ++kf) {
            int colA = (kf * 64 + ((lane >> 4) * 16)) ^ ((lane & 7) << 4);
            bf16x8_v ah[2], al[2], bh[2], bl[2];
#pragma unroll
            for (int i = 0; i < 2; ++i) {
                int rowm = (wm * 2 + i) * 16 + (lane & 15);
                ah[i] = *(const bf16x8_v*)(Ab + rowm * 128 + colA);
                al[i] = *(const bf16x8_v*)(Ab + 8192 + rowm * 128 + colA);
                int rj = (wn * 2 + i) * 16 + (lane & 15);
                bh[i] = *(const bf16x8_v*)(Bb + rj * 128 + colA);
                bl[i] = *(const bf16x8_v*)(Bb + 8192 + rj * 128 + colA);
            }
            __builtin_amdgcn_s_setprio(1);
#pragma unroll
            for (int i = 0; i < 2; ++i)
#pragma unroll
                for (int j = 0; j < 2; ++j) {
                    acc[i][j] = __builtin_amdgcn_mfma_f32_16x16x32_bf16(al[i], bh[j], acc[i][j], 0, 0, 0);
                    acc[i][j] = __builtin_amdgcn_mfma_f32_16x16x32_bf16(ah[i], bl[j], acc[i][j], 0, 0, 0);
                    acc[i][j] = __builtin_amdgcn_mfma_f32_16x16x32_bf16(ah[i], bh[j], acc[i][j], 0, 0, 0);
                }
            __builtin_amdgcn_s_setprio(0);
        }
    };

    stage(0, 0);
    int cur = 0;
    for (int tt = 0; tt < NT; ++tt) {
        if (tt + 1 < NT) {
            stage(tt + 1, cur ^ 1);
            asm volatile("s_waitcnt vmcnt(8)" ::: "memory");
        } else {
            asm volatile("s_waitcnt vmcnt(0)" ::: "memory");
        }
        __builtin_amdgcn_s_barrier();
        __builtin_amdgcn_sched_barrier(0);
        compute(cur);
        __builtin_amdgcn_sched_barrier(0);
        __builtin_amdgcn_s_barrier();
        cur ^= 1;
    }

    // gate tile -> LDS (overlays staging buffers; K-loop fully drained)
    float* gtile = (float*)lds;    // [64][68]
    const int l16 = lane & 15, g4 = (lane >> 4) * 4;
#pragma unroll
    for (int i = 0; i < 2; ++i)
#pragma unroll
        for (int jj = 0; jj < 2; ++jj)
#pragma unroll
            for (int r = 0; r < 4; ++r)
                gtile[(wm * 32 + i * 16 + g4 + r) * 68 + wn * 32 + jj * 16 + l16] = acc[i][jj][r];
    __syncthreads();

    // LSTM pointwise: 256 thr x 4 elems = 64 rows x 16 h-cols
    int m = tid >> 2;
    int hcb = (tid & 3) * 4;
    int nh0 = cblk * 16;
#pragma unroll
    for (int e = 0; e < 4; ++e) {
        int hc = hcb + e;
        float gv[4];
#pragma unroll
        for (int q = 0; q < 4; ++q) {
            int bidx = q * H + nh0 + hc;
            gv[q] = gtile[m * 68 + hc * 4 + q] + bias1[bidx] + bias2[bidx];
        }
        size_t idx = (size_t)(m0 + m) * H + nh0 + hc;
        float cp = cbuf[idx];
        float si = 1.f / (1.f + __expf(-gv[0]));
        float sf = 1.f / (1.f + __expf(-gv[1]));
        float so = 1.f / (1.f + __expf(-gv[3]));
        float c = sf * cp + si * tanhf(gv[2]);
        float hn = so * tanhf(c);
        cbuf[idx] = c;
        hf[idx] = hn;
        uint_t hu, lu; split1(hn, hu, lu);
        hhi[idx] = (ushort_t)hu;
        hlo[idx] = (ushort_t)lu;
    }
}

// ---------------------------------------------------------------------------
// Batched score MFMA (256 thr, 64KB): scores[t*R+l*64+b][s] = h1 . ctxW.
// grid (4 colblk, 2 mblk, B).
__global__ __launch_bounds__(256) void k_smfma(
    const ushort_t* __restrict__ h1h, const ushort_t* __restrict__ h1l,
    const ushort_t* __restrict__ cwh, const ushort_t* __restrict__ cwl,
    float* __restrict__ scores) {
    __shared__ __align__(16) unsigned char lds[65536];
    const int tid = threadIdx.x;
    const int lane = tid & 63;
    const int wv = tid >> 6;
    const int wm = wv & 1, wn = wv >> 1;
    const int b = blockIdx.z;
    const int m0 = blockIdx.y * 64;
    const int colbase = blockIdx.x * 64;
    const int NT = 16;                       // K=1024 / 64

    f32x4_v zero = {0.f, 0.f, 0.f, 0.f};
    f32x4_v acc[2][2] = {{zero, zero}, {zero, zero}};
    const int xorc = ((lane & 7) * 16) ^ ((lane >> 3) << 4);
    const int rsub = lane >> 3;

    auto stage = [&](int t, int buf) {
        unsigned char* dstA = lds + buf * 16384;
        unsigned char* dstB = lds + 32768 + buf * 16384;
        int k0 = t << 6;
#pragma unroll
        for (int cc = 0; cc < 4; ++cc) {
            int c = wv * 4 + cc;
            int p = c >> 3, s = c & 7;
            int rr = m0 + 8 * s + rsub;
            int tt = rr >> 2; if (tt > 30) tt = 30;
            size_t row = (size_t)tt * R + (rr & 3) * 64 + b;
            const ushort_t* plane = p ? h1l : h1h;
            gl_lds16((const unsigned char*)(plane + row * H + k0) + xorc,
                     dstA + p * 8192 + s * 1024);
        }
#pragma unroll
        for (int cc = 0; cc < 4; ++cc) {
            int c = wv * 4 + cc;
            int p = c >> 3, s = c & 7;
            int rr = colbase + 8 * s + rsub;
            const ushort_t* plane = p ? cwl : cwh;
            gl_lds16((const unsigned char*)(plane + ((size_t)b * SRC + rr) * H + k0) + xorc,
                     dstB + p * 8192 + s * 1024);
        }
    };
    auto compute = [&](int buf) {
        const unsigned char* Ab = lds + buf * 16384;
        const unsigned char* Bb = lds + 32768 + buf * 16384;
#pragma unroll
        for (int kf = 0; kf < 2; ++kf) {
            int colA = (kf * 64 + ((lane >> 4) * 16)) ^ ((lane & 7) << 4);
            bf16x8_v ah[2], al[2], bh[2], bl[2];
#pragma unroll
            for (int i = 0; i < 2; ++i) {
                int rowm = (wm * 2 + i) * 16 + (lane & 15);
                ah[i] = *(const bf16x8_v*)(Ab + rowm * 128 + colA);
                al[i] = *(const bf16x8_v*)(Ab + 8192 + rowm * 128 + colA);
                int rj = (wn * 2 + i) * 16 + (lane & 15);
                bh[i] = *(const bf16x8_v*)(Bb + rj * 128 + colA);
                bl[i] = *(const bf16x8_v*)(Bb + 8192 + rj * 128 + colA);
            }
            __builtin_amdgcn_s_setprio(1);
#pragma unroll
            for (int i = 0; i < 2; ++i)
#pragma unroll
                for (int j = 0; j < 2; ++j) {
                    acc[i][j] = __builtin_amdgcn_mfma_f32_16x16x32_bf16(al[i], bh[j], acc[i][j], 0, 0, 0);
                    acc[i][j] = __builtin_amdgcn_mfma_f32_16x16x32_bf16(ah[i], bl[j], acc[i][j], 0, 0, 0);
                    acc[i][j] = __builtin_amdgcn_mfma_f32_16x16x32_bf16(ah[i], bh[j], acc[i][j], 0, 0, 0);
                }
            __builtin_amdgcn_s_setprio(0);
        }
    };

    stage(0, 0);
    int cur = 0;
    for (int tt = 0; tt < NT; ++tt) {
        if (tt + 1 < NT) {
            stage(tt + 1, cur ^ 1);
            asm volatile("s_waitcnt vmcnt(8)" ::: "memory");
        } else {
            asm volatile("s_waitcnt vmcnt(0)" ::: "memory");
        }
        __builtin_amdgcn_s_barrier();
        __builtin_amdgcn_sched_barrier(0);
        compute(cur);
        __builtin_amdgcn_sched_barrier(0);
        __builtin_amdgcn_s_barrier();
        cur ^= 1;
    }

    const int l16 = lane & 15, g4 = (lane >> 4) * 4;
#pragma unroll
    for (int i = 0; i < 2; ++i) {
#pragma unroll
        for (int jj = 0; jj < 2; ++jj) {
#pragma unroll
            for (int r = 0; r < 4; ++r) {
                int m = m0 + wm * 32 + i * 16 + g4 + r;
                int t = m >> 2;
                if (t < 31) {
                    size_t row = (size_t)t * R + (m & 3) * 64 + b;
                    int n = colbase + wn * 32 + jj * 16 + l16;
                    scores[row * SRC + n] = acc[i][jj][r];
                }
            }
        }
    }
}

// ---------------------------------------------------------------------------
__global__ __launch_bounds__(256) void k_smax(const float* __restrict__ scores,
                                              const float* __restrict__ cb,
                                              float* __restrict__ w) {
    int t = blockIdx.x, b = blockIdx.y;
    int l = threadIdx.x >> 6, lane = threadIdx.x & 63;
    size_t row = (size_t)t * R + l * 64 + b;
    const float* sr = scores + row * SRC;
    const float* cbb = cb + b * SRC;
    float v0 = sr[lane] + cbb[lane];
    float v1 = sr[lane + 64] + cbb[lane + 64];
    float v2 = sr[lane + 128] + cbb[lane + 128];
    float v3 = sr[lane + 192] + cbb[lane + 192];
    float m = fmaxf(fmaxf(v0, v1), fmaxf(v2, v3));
#pragma unroll
    for (int off = 32; off >= 1; off >>= 1) m = fmaxf(m, __shfl_xor(m, off));
    float e0 = expf(v0 - m), e1 = expf(v1 - m), e2 = expf(v2 - m), e3 = expf(v3 - m);
    float sum = e0 + e1 + e2 + e3;
#pragma unroll
    for (int off = 32; off >= 1; off >>= 1) sum += __shfl_xor(sum, off);
    float inv = 1.f / sum;
    float* wr = w + row * SRC;
    wr[lane] = e0 * inv;
    wr[lane + 64] = e1 * inv;
    wr[lane + 128] = e2 * inv;
    wr[lane + 192] = e3 * inv;
}

// ---------------------------------------------------------------------------
__global__ __launch_bounds__(512) void k_ct_all(const float* __restrict__ ctx,
                                                const float* __restrict__ w,
                                                ushort_t* __restrict__ cthi,
                                                ushort_t* __restrict__ ctlo) {
    __shared__ float ws[32][260];
    const int b = blockIdx.x, tc = blockIdx.y;
    const int tid = threadIdx.x;
    for (int q = tid; q < 32 * 64; q += 512) {
        int r = q >> 6, c4 = q & 63;
        int t = tc * 8 + (r >> 2);
        float4 v = {0.f, 0.f, 0.f, 0.f};
        if (t < 31)
            v = *(const float4*)(w + ((size_t)t * R + (r & 3) * 64 + b) * SRC + c4 * 4);
        *(float4*)&ws[r][c4 * 4] = v;
    }
    __syncthreads();

    float2 acc[32];
#pragma unroll
    for (int r = 0; r < 32; ++r) acc[r] = make_float2(0.f, 0.f);
    const float2* base = (const float2*)(ctx + (size_t)b * SRC * H) + tid;
    for (int s = 0; s < SRC; s += 4) {
        float2 c0 = base[(size_t)s * (H / 2)];
        float2 c1 = base[(size_t)(s + 1) * (H / 2)];
        float2 c2 = base[(size_t)(s + 2) * (H / 2)];
        float2 c3 = base[(size_t)(s + 3) * (H / 2)];
#pragma unroll
        for (int r = 0; r < 32; ++r) {
            float4 wv = *(const float4*)&ws[r][s];
            acc[r].x += wv.x * c0.x + wv.y * c1.x + wv.z * c2.x + wv.w * c3.x;
            acc[r].y += wv.x * c0.y + wv.y * c1.y + wv.z * c2.y + wv.w * c3.y;
        }
    }
#pragma unroll
    for (int r = 0; r < 32; ++r) {
        int t = tc * 8 + (r >> 2);
        if (t < 31) {
            size_t obase = ((size_t)t * R + (r & 3) * 64 + b) * H + tid * 2;
            uint_t hx, lx, hy, ly;
            split1(acc[r].x, hx, lx);
            split1(acc[r].y, hy, ly);
            *(uint_t*)(cthi + obase) = hx | (hy << 16);
            *(uint_t*)(ctlo + obase) = lx | (ly << 16);
        }
    }
}

// ---------------------------------------------------------------------------
__global__ __launch_bounds__(256) void k_init_split(const float* __restrict__ h0f,
                                                    const float* __restrict__ c0f,
                                                    float* __restrict__ h1f,
                                                    float* __restrict__ c1f,
                                                    ushort_t* __restrict__ h0hi,
                                                    ushort_t* __restrict__ h0lo,
                                                    ushort_t* __restrict__ h1hi,
                                                    ushort_t* __restrict__ h1lo) {
    int idx = blockIdx.x * 256 + threadIdx.x;
    float h = h0f[idx], c = c0f[idx];
    h1f[idx] = h; c1f[idx] = c;
    uint_t hu, lu; split1(h, hu, lu);
    h0hi[idx] = (ushort_t)hu; h0lo[idx] = (ushort_t)lu;
    h1hi[idx] = (ushort_t)hu; h1lo[idx] = (ushort_t)lu;
}

// ---------------------------------------------------------------------------
__global__ __launch_bounds__(256) void k_cb(const float* __restrict__ ctx,
                                            const float* __restrict__ bvec,
                                            float* __restrict__ cb) {
    int b = blockIdx.x, ch = blockIdx.y;
    int wave = threadIdx.x >> 6, lane = threadIdx.x & 63;
    for (int i = 0; i < 16; ++i) {
        int s = ch * 64 + wave * 16 + i;
        const float* cs = ctx + ((size_t)b * SRC + s) * H;
        float a = 0.f;
#pragma unroll
        for (int j = 0; j < 4; ++j) {
            float4 cv = *(const float4*)(cs + lane * 4 + j * 256);
            float4 bv = *(const float4*)(bvec + lane * 4 + j * 256);
            a += cv.x * bv.x + cv.y * bv.y + cv.z * bv.z + cv.w * bv.w;
        }
#pragma unroll
        for (int off = 32; off >= 1; off >>= 1) a += __shfl_xor(a, off);
        if (lane == 0) cb[b * SRC + s] = a;
    }
}

// ---------------------------------------------------------------------------
extern "C" void kernel_launch(void* const* d_in, const int* in_sizes, int n_in,
                              void* d_out, int out_size, void* d_ws, size_t ws_size,
                              hipStream_t stream) {
    const int*   inputs     = (const int*)d_in[0];
    const int*   input_lens = (const int*)d_in[1];
    const float* contexts   = (const float*)d_in[2];
    const float* emb_W      = (const float*)d_in[3];
    const float* W_ih0      = (const float*)d_in[4];
    const float* W_hh0      = (const float*)d_in[5];
    const float* b_ih0      = (const float*)d_in[6];
    const float* b_hh0      = (const float*)d_in[7];
    const float* W_ih1      = (const float*)d_in[8];
    const float* W_hh1      = (const float*)d_in[9];
    const float* b_ih1      = (const float*)d_in[10];
    const float* b_hh1      = (const float*)d_in[11];
    const float* att_in_W   = (const float*)d_in[12];
    const float* att_in_b   = (const float*)d_in[13];
    const float* att_out_W  = (const float*)d_in[14];
    const float* att_out_b  = (const float*)d_in[15];
    const float* isl_in_W   = (const float*)d_in[16];
    const float* isl_in_b   = (const float*)d_in[17];
    const float* isl_out_W  = (const float*)d_in[18];
    const float* isl_out_b  = (const float*)d_in[19];

    float* out = (float*)d_out;

    // workspace carve (256B-aligned)
    char* p = (char*)d_ws;
    auto alloc = [&](size_t bytes) { char* r = p; p += (bytes + 255) & ~(size_t)255; return r; };
    ushort_t* xs_hi = (ushort_t*)alloc((size_t)T * R * E * 2);
    ushort_t* xs_lo = (ushort_t*)alloc((size_t)T * R * E * 2);
    ushort_t* h0hi[2], *h0lo[2];
    for (int i = 0; i < 2; ++i) {
        h0hi[i] = (ushort_t*)alloc((size_t)R * H * 2);
        h0lo[i] = (ushort_t*)alloc((size_t)R * H * 2);
    }
    ushort_t* h1ihi = (ushort_t*)alloc((size_t)R * H * 2);
    ushort_t* h1ilo = (ushort_t*)alloc((size_t)R * H * 2);
    ushort_t* h1hall = (ushort_t*)alloc((size_t)T * R * H * 2);
    ushort_t* h1lall = (ushort_t*)alloc((size_t)T * R * H * 2);
    ushort_t* pehi = (ushort_t*)alloc((size_t)R * E * 2);
    ushort_t* pelo = (ushort_t*)alloc((size_t)R * E * 2);
    ushort_t* cmhi = (ushort_t*)alloc((size_t)B * H * 2);
    ushort_t* cmlo = (ushort_t*)alloc((size_t)B * H * 2);
    ushort_t* wg0h = (ushort_t*)alloc((size_t)4096 * 1536 * 2);
    ushort_t* wg0l = (ushort_t*)alloc((size_t)4096 * 1536 * 2);
    ushort_t* wg1h = (ushort_t*)alloc((size_t)4096 * 2048 * 2);
    ushort_t* wg1l = (ushort_t*)alloc((size_t)4096 * 2048 * 2);
    ushort_t* wgTh = (ushort_t*)alloc((size_t)1024 * 1024 * 2);
    ushort_t* wgTl = (ushort_t*)alloc((size_t)1024 * 1024 * 2);
    ushort_t* woth = (ushort_t*)alloc((size_t)1024 * 2048 * 2);
    ushort_t* wotl = (ushort_t*)alloc((size_t)1024 * 2048 * 2);
    ushort_t* wiih = (ushort_t*)alloc((size_t)1024 * 1536 * 2);
    ushort_t* wiil = (ushort_t*)alloc((size_t)1024 * 1536 * 2);
    ushort_t* wioh = (ushort_t*)alloc((size_t)1024 * 1536 * 2);
    ushort_t* wiol = (ushort_t*)alloc((size_t)1024 * 1536 * 2);
    ushort_t* cxh = (ushort_t*)alloc((size_t)B * SRC * H * 2);
    ushort_t* cxl = (ushort_t*)alloc((size_t)B * SRC * H * 2);
    ushort_t* cwh = (ushort_t*)alloc((size_t)B * SRC * H * 2);
    ushort_t* cwl = (ushort_t*)alloc((size_t)B * SRC * H * 2);
    float* cbv = (float*)alloc((size_t)B * SRC * 4);
    float* h0f = (float*)alloc((size_t)R * H * 4);
    float* h1f = (float*)alloc((size_t)R * H * 4);
    float* c0f = (float*)alloc((size_t)R * H * 4);
    float* c1f = (float*)alloc((size_t)R * H * 4);
    // post buffers aliased into the dead cx region (48.8MB <= 67MB)
    float* scores = (float*)cxh;
    float* wbuf   = scores + (size_t)T * R * SRC;
    ushort_t* cthi = (ushort_t*)(wbuf + (size_t)T * R * SRC);
    ushort_t* ctlo = cthi + (size_t)T * R * H;

    // ---- setup ----
    k_embed<<<L4 * T * B, 128, 0, stream>>>(inputs, emb_W, xs_hi, xs_lo);
    k_pe<<<R, 128, 0, stream>>>(inputs, input_lens, emb_W, pehi, pelo);
    k_cm<<<B, 256, 0, stream>>>(contexts, cmhi, cmlo);
    k_wsplit<<<4096, 256, 0, stream>>>(W_ih0, 512, 0, 512, W_hh0, 1024, 0, 1024, 1, wg0h, wg0l);
    k_wsplit<<<4096, 256, 0, stream>>>(W_ih1, 1024, 0, 1024, W_hh1, 1024, 0, 1024, 1, wg1h, wg1l);
    k_wsplitT<<<1024, 256, 0, stream>>>(att_in_W, 1024, 1024, wgTh, wgTl);
    k_wsplit<<<1024, 256, 0, stream>>>(att_out_W, 2048, 0, 2048, nullptr, 0, 0, 0, 0, woth, wotl);
    k_wsplit<<<1024, 256, 0, stream>>>(isl_in_W, 1536, 0, 1536, nullptr, 0, 0, 0, 0, wiih, wiil);
    k_wsplit<<<1024, 256, 0, stream>>>(isl_out_W, 1536, 1024, 512, isl_out_W, 1536, 0, 1024, 0, wioh, wiol);
    k_wsplit<<<B * SRC, 256, 0, stream>>>(contexts, 1024, 0, 1024, nullptr, 0, 0, 0, 0, cxh, cxl);

    // init projections (mode 0)
    k_g2<<<dim3(16, 4), 256, 0, stream>>>(pehi, pelo, 512, cmhi, cmlo, 1024, 64,
                                          wiih, wiil, isl_in_b, nullptr, 0,
                                          h0f, 0, 64LL * H, (long long)H, 1, 0,
                                          nullptr, nullptr);
    k_g2<<<dim3(16, 4), 256, 0, stream>>>(pehi, pelo, 512, cmhi, cmlo, 1024, 64,
                                          wioh, wiol, isl_out_b, nullptr, 0,
                                          c0f, 0, 64LL * H, (long long)H, 1, 0,
                                          nullptr, nullptr);
    k_init_split<<<R * H / 256, 256, 0, stream>>>(h0f, c0f, h1f, c1f,
                                                  h0hi[0], h0lo[0], h1ihi, h1ilo);

    // ctxW = contexts @ att_in_W -> bf16 planes (mode 2), col-fastest order
    k_g2<<<dim3(16, 256), 256, 0, stream>>>(cxh, cxl, 1024,
                                            nullptr, nullptr, 0, 0,
                                            wgTh, wgTl, nullptr, nullptr, 2,
                                            nullptr, (long long)SRC * H, 64LL * H, (long long)H, 0, 0,
                                            cwh, cwl);
    k_cb<<<dim3(B, 4), 256, 0, stream>>>(contexts, att_in_b, cbv);

    // ---- recurrence: dual-job launches ----
    int cur = 0;
    for (int L = 0; L <= T; ++L) {
        bool has0 = (L < T), has1 = (L > 0);
        GateJob g0 = {}, g1 = {};
        if (has0) {
            g0.Ah1 = xs_hi + (size_t)L * R * E;  g0.Al1 = xs_lo + (size_t)L * R * E;
            g0.Ah2 = h0hi[cur];  g0.Al2 = h0lo[cur];
            g0.Bh = wg0h;  g0.Bl = wg0l;
            g0.bias1 = b_ih0;  g0.bias2 = b_hh0;
            g0.cbuf = c0f;  g0.hf = h0f;
            g0.hhi = h0hi[cur ^ 1];  g0.hlo = h0lo[cur ^ 1];
            g0.K1 = E;  g0.K2 = H;
        }
        if (has1) {
            const ushort_t* ph = (L == 1) ? h1ihi : h1hall + (size_t)(L - 2) * R * H;
            const ushort_t* pl = (L == 1) ? h1ilo : h1lall + (size_t)(L - 2) * R * H;
            g1.Ah1 = h0hi[cur];  g1.Al1 = h0lo[cur];
            g1.Ah2 = ph;  g1.Al2 = pl;
            g1.Bh = wg1h;  g1.Bl = wg1l;
            g1.bias1 = b_ih1;  g1.bias2 = b_hh1;
            g1.cbuf = c1f;  g1.hf = h1f;
            g1.hhi = h1hall + (size_t)(L - 1) * R * H;
            g1.hlo = h1lall + (size_t)(L - 1) * R * H;
            g1.K1 = H;  g1.K2 = H;
        }
        if (has0 && has1)
            k_gatepair<<<dim3(64, 8), 256, 0, stream>>>(g0, g1);
        else if (has0)
            k_gatepair<<<dim3(64, 4), 256, 0, stream>>>(g0, g0);
        else
            k_gatepair<<<dim3(64, 4), 256, 0, stream>>>(g1, g1);
        if (has0) cur ^= 1;
    }

    // ---- batched attention + output over all t ----
    k_smfma<<<dim3(4, 2, B), 256, 0, stream>>>(h1hall, h1lall, cwh, cwl, scores);
    k_smax<<<dim3(T, B), 256, 0, stream>>>(scores, cbv, wbuf);
    k_ct_all<<<dim3(B, 4), 512, 0, stream>>>(contexts, wbuf, cthi, ctlo);
    // out[t,l,b,:] = tanh([ct|h1] @ att_out_W^T + b), col-fastest order
    k_g2<<<dim3(16, 124), 256, 0, stream>>>(cthi, ctlo, 1024,
                                            h1hall, h1lall, 1024, 0,
                                            woth, wotl, att_out_b, nullptr, 0,
                                            out, (long long)B * H,
                                            (long long)T * B * H, (long long)H, 1, 0,
                                            nullptr, nullptr);

    // ---- finals ----
    size_t OUTS = (size_t)L4 * T * B * H;
    size_t seg = (size_t)B * H;
    hipMemcpyAsync(out + OUTS,           h0f + 192 * H, seg * 4, hipMemcpyDeviceToDevice, stream);
    hipMemcpyAsync(out + OUTS + seg,     h1f + 192 * H, seg * 4, hipMemcpyDeviceToDevice, stream);
    hipMemcpyAsync(out + OUTS + 2 * seg, c0f + 192 * H, seg * 4, hipMemcpyDeviceToDevice, stream);
    hipMemcpyAsync(out + OUTS + 3 * seg, c1f + 192 * H, seg * 4, hipMemcpyDeviceToDevice, stream);
}